// Round 15
// baseline (1008.425 us; speedup 1.0000x reference)
//
#include <hip/hip_runtime.h>
#include <hip/hip_bf16.h>
#include <stdint.h>

#define B_ 2
#define T_ 2048
#define H_ 1024
#define M_ 4096
#define DI 2048
#define DS 128
#define CONVD 2304
#define LD2 4480
#define EPS_ 1e-6f

typedef __bf16 bf16x8 __attribute__((ext_vector_type(8)));
typedef float f32x4 __attribute__((ext_vector_type(4)));
typedef uint32_t u32x4 __attribute__((ext_vector_type(4)));

__device__ __forceinline__ unsigned short f2bfu(float f) {
    union { float f; uint32_t u; } a; a.f = f;
    uint32_t r = a.u + 0x7FFFu + ((a.u >> 16) & 1u);
    return (unsigned short)(r >> 16);
}
__device__ __forceinline__ float bfu2f(unsigned short u) {
    union { uint32_t u; float f; } a; a.u = ((uint32_t)u) << 16; return a.f;
}
__device__ __forceinline__ float siluf(float x) { return x / (1.f + expf(-x)); }
__device__ __forceinline__ bf16x8 zero8() { bf16x8 r{}; return r; }

// async global->LDS, 16B per lane; LDS dest is wave-uniform base + lane*16
__device__ __forceinline__ void gl_lds16(const unsigned short* g, unsigned short* l) {
    __builtin_amdgcn_global_load_lds(
        (const __attribute__((address_space(1))) void*)g,
        (__attribute__((address_space(3))) void*)l, 16, 0, 0);
}

// ---------------- RMS over 1024 cols -> bf16 ----------------
__global__ __launch_bounds__(256) void k_rms1024(const float* __restrict__ in, const float* __restrict__ w,
                                                 unsigned short* __restrict__ out) {
    __shared__ float red[4];
    int m = blockIdx.x, tid = threadIdx.x;
    size_t base = (size_t)m * H_ + tid * 4;
    float4 v = *(const float4*)(in + base);
    float ss = v.x * v.x + v.y * v.y + v.z * v.z + v.w * v.w;
#pragma unroll
    for (int off = 32; off; off >>= 1) ss += __shfl_xor(ss, off);
    if ((tid & 63) == 0) red[tid >> 6] = ss;
    __syncthreads();
    float scale = rsqrtf((red[0] + red[1] + red[2] + red[3]) * (1.f / 1024.f) + EPS_);
    float4 wv = *(const float4*)(w + tid * 4);
    ushort4 o;
    o.x = f2bfu(v.x * wv.x * scale); o.y = f2bfu(v.y * wv.y * scale);
    o.z = f2bfu(v.z * wv.z * scale); o.w = f2bfu(v.w * wv.w * scale);
    *(ushort4*)(out + base) = o;
}

// ---------------- transpose fp32 [K,N] -> bf16 [NP,K] ----------------
__global__ __launch_bounds__(256) void k_transpose(const float* __restrict__ src, unsigned short* __restrict__ dst,
                                                   int K, int N, int NP) {
    __shared__ float t[32][33];
    int n0 = blockIdx.x * 32, k0 = blockIdx.y * 32;
    int tx = threadIdx.x & 31, ty = threadIdx.x >> 5;
#pragma unroll
    for (int i = ty; i < 32; i += 8) {
        int k = k0 + i, n = n0 + tx;
        t[i][tx] = (n < N) ? src[(size_t)k * N + n] : 0.f;
    }
    __syncthreads();
#pragma unroll
    for (int i = ty; i < 32; i += 8) {
        int n = n0 + i, k = k0 + tx;
        if (n < NP) dst[(size_t)n * K + k] = f2bfu(t[tx][i]);
    }
}

// ---------------- bf16 MFMA GEMM (global_load_lds staging, XCD-swizzled) ----------------
template <int EPI>
__global__ __launch_bounds__(256) void k_gemm(const unsigned short* __restrict__ A, const unsigned short* __restrict__ Bt,
                                              void* __restrict__ Cout, const float* __restrict__ aux,
                                              int M, int N, int K) {
    __shared__ alignas(16) unsigned short As[128 * 64];
    __shared__ alignas(16) unsigned short Bs[128 * 64];
    const int tid = threadIdx.x;
    int n_t, m_t;
    {
        int nx = gridDim.x;
        int bid = blockIdx.x + blockIdx.y * nx;
        if ((nx & 7) == 0) {
            int chunk = nx >> 3;
            int xcd = bid & 7, j = bid >> 3;
            n_t = xcd * chunk + j % chunk;
            m_t = j / chunk;
        } else { n_t = blockIdx.x; m_t = blockIdx.y; }
    }
    const int m0 = m_t * 128, n0 = n_t * 128;
    const int wave = tid >> 6, lane = tid & 63;
    const int wm = (wave >> 1) * 64, wn = (wave & 1) * 64;
    const int fr = lane & 15, fg = lane >> 4;
    const int srow = wave * 32 + (lane >> 3);   // staging row (+ i*8)
    const int scol = (lane & 7) * 8;            // staging col element

    f32x4 acc[4][4];
#pragma unroll
    for (int m = 0; m < 4; m++)
#pragma unroll
        for (int n = 0; n < 4; n++) acc[m][n] = (f32x4)(0.f);

    const int nk = K >> 6;
    for (int kt = 0; kt < nk; ++kt) {
        __syncthreads();
#pragma unroll
        for (int i = 0; i < 4; i++) {
            int row = srow + i * 8;
            gl_lds16(A + (size_t)(m0 + row) * K + kt * 64 + scol, As + (wave * 32 + i * 8) * 64);
            gl_lds16(Bt + (size_t)(n0 + row) * K + kt * 64 + scol, Bs + (wave * 32 + i * 8) * 64);
        }
        __syncthreads();
#pragma unroll
        for (int ks = 0; ks < 2; ++ks) {
            bf16x8 af[4], bg[4];
#pragma unroll
            for (int m = 0; m < 4; m++)
                af[m] = *(const bf16x8*)(As + (wm + m * 16 + fr) * 64 + ks * 32 + fg * 8);
#pragma unroll
            for (int n = 0; n < 4; n++)
                bg[n] = *(const bf16x8*)(Bs + (wn + n * 16 + fr) * 64 + ks * 32 + fg * 8);
#pragma unroll
            for (int m = 0; m < 4; m++)
#pragma unroll
                for (int n = 0; n < 4; n++)
                    acc[m][n] = __builtin_amdgcn_mfma_f32_16x16x32_bf16(af[m], bg[n], acc[m][n], 0, 0, 0);
        }
    }
#pragma unroll
    for (int m = 0; m < 4; m++) {
#pragma unroll
        for (int r = 0; r < 4; r++) {
            size_t row = (size_t)(m0 + wm + m * 16 + fg * 4 + r);
#pragma unroll
            for (int n = 0; n < 4; n++) {
                size_t idx = row * N + n0 + wn + n * 16 + fr;
                float v = acc[m][n][r];
                if constexpr (EPI == 0) ((float*)Cout)[idx] = v;
                else if constexpr (EPI == 4) ((unsigned short*)Cout)[idx] = f2bfu(0.5f * v * (1.f + erff(v * 0.70710678118f)));
                else ((float*)Cout)[idx] = v + aux[idx];
            }
        }
    }
}

// ---------------- fused projection GEMM (global_load_lds staging, linear mapping 75x32) ------
__global__ __launch_bounds__(256) void k_gemm_fused(const unsigned short* __restrict__ A, const unsigned short* __restrict__ Bt,
                                                    unsigned short* __restrict__ RB, unsigned short* __restrict__ KB,
                                                    unsigned short* __restrict__ VB, unsigned short* __restrict__ GB,
                                                    float* __restrict__ WF, unsigned short* __restrict__ C2B) {
    __shared__ alignas(16) unsigned short As[128 * 64];
    __shared__ alignas(16) unsigned short Bs[128 * 64];
    const int tid = threadIdx.x;
    const int m0 = blockIdx.y * 128, n0 = blockIdx.x * 128;
    const int wave = tid >> 6, lane = tid & 63;
    const int wm = (wave >> 1) * 64, wn = (wave & 1) * 64;
    const int fr = lane & 15, fg = lane >> 4;
    const int srow = wave * 32 + (lane >> 3);
    const int scol = (lane & 7) * 8;
    const int K = 1024;

    f32x4 acc[4][4];
#pragma unroll
    for (int m = 0; m < 4; m++)
#pragma unroll
        for (int n = 0; n < 4; n++) acc[m][n] = (f32x4)(0.f);

    for (int kt = 0; kt < 16; ++kt) {
        __syncthreads();
#pragma unroll
        for (int i = 0; i < 4; i++) {
            int row = srow + i * 8;
            gl_lds16(A + (size_t)(m0 + row) * K + kt * 64 + scol, As + (wave * 32 + i * 8) * 64);
            gl_lds16(Bt + (size_t)(n0 + row) * K + kt * 64 + scol, Bs + (wave * 32 + i * 8) * 64);
        }
        __syncthreads();
#pragma unroll
        for (int ks = 0; ks < 2; ++ks) {
            bf16x8 af[4], bg[4];
#pragma unroll
            for (int m = 0; m < 4; m++)
                af[m] = *(const bf16x8*)(As + (wm + m * 16 + fr) * 64 + ks * 32 + fg * 8);
#pragma unroll
            for (int n = 0; n < 4; n++)
                bg[n] = *(const bf16x8*)(Bs + (wn + n * 16 + fr) * 64 + ks * 32 + fg * 8);
#pragma unroll
            for (int m = 0; m < 4; m++)
#pragma unroll
                for (int n = 0; n < 4; n++)
                    acc[m][n] = __builtin_amdgcn_mfma_f32_16x16x32_bf16(af[m], bg[n], acc[m][n], 0, 0, 0);
        }
    }
    const int seg = n0 >> 10;
#pragma unroll
    for (int m = 0; m < 4; m++) {
#pragma unroll
        for (int r = 0; r < 4; r++) {
            size_t row = (size_t)(m0 + wm + m * 16 + fg * 4 + r);
#pragma unroll
            for (int n = 0; n < 4; n++) {
                int gcol = n0 + wn + n * 16 + fr;
                float v = acc[m][n][r];
                if (n0 < 5120) {
                    size_t idx = row * 1024 + (gcol & 1023);
                    if (seg == 0) RB[idx] = f2bfu(v);
                    else if (seg == 1) KB[idx] = f2bfu(v);
                    else if (seg == 2) VB[idx] = f2bfu(v);
                    else if (seg == 3) GB[idx] = f2bfu(siluf(v));
                    else WF[idx] = expf(-expf(v));
                } else {
                    C2B[row * 4480 + (gcol - 5120)] = f2bfu(v);
                }
            }
        }
    }
}

// ---------------- RWKV chunk prep ----------------
__global__ __launch_bounds__(256) void k_rwkv_prep(unsigned short* __restrict__ RB, unsigned short* __restrict__ KB,
                                                   const float* __restrict__ WF, const float* __restrict__ u,
                                                   unsigned short* __restrict__ KDt, unsigned short* __restrict__ QLb,
                                                   float* __restrict__ DDb) {
    __shared__ float red[16][257];
    __shared__ float red2[16][17];
    const int c = blockIdx.x, bh = blockIdx.y;
    const int b = bh >> 2, h = bh & 3;
    const int k = threadIdx.x;
    const size_t m0 = (size_t)b * T_ + c * 16;
    const int hk = h * 256 + k;
    const float uv = u[hk];
    float Q = 1.f;
    float kd[16];
#pragma unroll
    for (int s = 0; s < 16; s++) {
        size_t off = (m0 + s) * H_ + hk;
        float r = bfu2f(RB[off]);
        float kv = bfu2f(KB[off]);
        float w = WF[off];
        RB[off] = f2bfu(r * Q);
        Q = fmaxf(Q * w, 1e-35f);
        float kdv = kv / Q;
        kd[s] = kdv;
        KB[off] = f2bfu(kdv);
        red[s][k] = r * uv * kv;
    }
    QLb[((size_t)(b * 128 + c)) * 1024 + hk] = f2bfu(Q);
    size_t kt0 = (((size_t)(b * 128 + c)) * 1024 + hk) * 16;
#pragma unroll
    for (int s = 0; s < 16; s++) KDt[kt0 + s] = f2bfu(kd[s]);
    __syncthreads();
    {
        int s = threadIdx.x >> 4, part = threadIdx.x & 15;
        float ps = 0.f;
#pragma unroll
        for (int j = 0; j < 16; j++) ps += red[s][part * 16 + j];
        red2[s][part] = ps;
    }
    __syncthreads();
    if (threadIdx.x < 32) {
        int s = threadIdx.x & 15, half = threadIdx.x >> 4;
        float d = 0.f;
#pragma unroll
        for (int j = 0; j < 8; j++) d += red2[s][half * 8 + j];
        DDb[(((size_t)bh * 128 + c) * 2 + half) * 16 + s] = d;
    }
}

// ---------------- RWKV carry ----------------
__global__ __launch_bounds__(256) void k_rwkv_carry(const unsigned short* __restrict__ KD, const unsigned short* __restrict__ VB,
                                                    const unsigned short* __restrict__ QLb, unsigned short* __restrict__ Scc) {
    __shared__ unsigned short kds[16][256];
    __shared__ float lv[16][4];
    const int vg = blockIdx.x, bh = blockIdx.y;
    const int b = bh >> 2, h = bh & 3;
    const int k = threadIdx.x;
    const int hk = h * 256 + k;
    const size_t baseM = (size_t)b * T_;
    float s0 = 0.f, s1 = 0.f, s2 = 0.f, s3 = 0.f;
    for (int c = 0; c < 128; ++c) {
        size_t m0 = baseM + c * 16;
        if ((c & 7) == 0 && c > 0) {
            int cc = c >> 3;
            size_t sb = ((size_t)(bh * 16 + cc) * 256 + vg * 4) * 256 + k;
            Scc[sb] = f2bfu(s0); Scc[sb + 256] = f2bfu(s1);
            Scc[sb + 512] = f2bfu(s2); Scc[sb + 768] = f2bfu(s3);
        }
        __syncthreads();
#pragma unroll
        for (int it = 0; it < 2; ++it) {
            int i = threadIdx.x + it * 256;
            int row = i >> 5, col8 = (i & 31) * 8;
            *(u32x4*)&kds[row][col8] = *(const u32x4*)(KD + (m0 + row) * H_ + h * 256 + col8);
        }
        if (threadIdx.x < 64) {
            int t = threadIdx.x >> 2, j = threadIdx.x & 3;
            lv[t][j] = bfu2f(VB[(m0 + t) * H_ + h * 256 + vg * 4 + j]);
        }
        __syncthreads();
        float a0 = 0.f, a1 = 0.f, a2 = 0.f, a3 = 0.f;
#pragma unroll
        for (int t = 0; t < 16; t++) {
            float kdv = bfu2f(kds[t][k]);
            a0 = fmaf(kdv, lv[t][0], a0);
            a1 = fmaf(kdv, lv[t][1], a1);
            a2 = fmaf(kdv, lv[t][2], a2);
            a3 = fmaf(kdv, lv[t][3], a3);
        }
        float ql = bfu2f(QLb[((size_t)(b * 128 + c)) * 1024 + hk]);
        s0 = (s0 + a0) * ql; s1 = (s1 + a1) * ql;
        s2 = (s2 + a2) * ql; s3 = (s3 + a3) * ql;
    }
}

// ---------------- RWKV chunked output (MFMA) ----------------
__global__ __launch_bounds__(256) void k_rwkv_out(const unsigned short* __restrict__ RT, const unsigned short* __restrict__ KD,
                                                  const unsigned short* __restrict__ KDt, const unsigned short* __restrict__ VB,
                                                  const unsigned short* __restrict__ QLb, const float* __restrict__ DDb,
                                                  const unsigned short* __restrict__ Scc,
                                                  float* __restrict__ P0, float* __restrict__ P1) {
    __shared__ unsigned short Sb[64][136];
    __shared__ unsigned short VT[64][24];
    __shared__ unsigned short Ab[16][24];
    __shared__ float dls[16];
    const int tid = threadIdx.x;
    const int vt = blockIdx.x, cc = blockIdx.y;
    const int bh = blockIdx.z >> 1, kh = blockIdx.z & 1;
    const int b = bh >> 2, h = bh & 3;
    const int wave = tid >> 6, lane = tid & 63;
    const int l16 = lane & 15, lq = lane >> 4;
    const int wv0 = wave * 16;
    const int hk0 = h * 256 + kh * 128;
    const int hv = h * 256 + vt * 64;
    const int aoff = (lq < 2) ? lq * 8 : 0;
    float* __restrict__ OP = kh ? P1 : P0;
    f32x4 sreg[8];
    if (cc == 0) {
#pragma unroll
        for (int kt = 0; kt < 8; kt++) sreg[kt] = (f32x4)(0.f);
        for (int i = tid; i < 64 * 136 / 8; i += 256) ((u32x4*)Sb)[i] = (u32x4)(0u);
    } else {
        size_t sbase = ((size_t)(bh * 16 + cc) * 256 + vt * 64);
        for (int i = tid; i < 1024; i += 256) {
            int v = i >> 4, k8 = (i & 15) * 8;
            *(u32x4*)&Sb[v][k8] = *(const u32x4*)(Scc + (sbase + v) * 256 + kh * 128 + k8);
        }
#pragma unroll
        for (int kt = 0; kt < 8; kt++) {
            ushort4 w4 = *(const ushort4*)(Scc + (sbase + wv0 + l16) * 256 + kh * 128 + kt * 16 + lq * 4);
            sreg[kt][0] = bfu2f(w4.x); sreg[kt][1] = bfu2f(w4.y);
            sreg[kt][2] = bfu2f(w4.z); sreg[kt][3] = bfu2f(w4.w);
        }
    }
    __syncthreads();

    for (int fc = 0; fc < 8; ++fc) {
        const int c = cc * 8 + fc;
        const size_t m0 = (size_t)b * T_ + c * 16;
        const size_t bc = (size_t)(b * 128 + c);
        if (fc > 0) __syncthreads();
        {
            int st = tid >> 4, v4 = (tid & 15) * 4;
            ushort4 v4v = *(const ushort4*)(VB + (m0 + st) * H_ + hv + v4);
            VT[v4 + 0][st] = v4v.x; VT[v4 + 1][st] = v4v.y;
            VT[v4 + 2][st] = v4v.z; VT[v4 + 3][st] = v4v.w;
            if (tid < 16) dls[tid] = DDb[(((size_t)bh * 128 + c) * 2 + kh) * 16 + tid];
        }
        __syncthreads();
        const size_t rowA = (m0 + l16) * H_ + hk0;
        bf16x8 rtf[4];
#pragma unroll
        for (int ks = 0; ks < 4; ks++) rtf[ks] = *(const bf16x8*)(RT + rowA + ks * 32 + lq * 8);
        f32x4 Aacc = (f32x4)(0.f);
#pragma unroll
        for (int ks = 0; ks < 4; ks++) {
            bf16x8 kdf = *(const bf16x8*)(KD + rowA + ks * 32 + lq * 8);
            Aacc = __builtin_amdgcn_mfma_f32_16x16x32_bf16(rtf[ks], kdf, Aacc, 0, 0, 0);
        }
        f32x4 oacc = (f32x4)(0.f);
#pragma unroll
        for (int ks = 0; ks < 4; ks++) {
            bf16x8 sbf = *(const bf16x8*)(&Sb[wv0 + l16][ks * 32 + lq * 8]);
            oacc = __builtin_amdgcn_mfma_f32_16x16x32_bf16(rtf[ks], sbf, oacc, 0, 0, 0);
        }
#pragma unroll
        for (int r = 0; r < 4; r++) {
            int t = lq * 4 + r, s = l16;
            float av = (s < t) ? Aacc[r] : ((s == t) ? dls[t] : 0.f);
            Ab[t][s] = f2bfu(av);
        }
        bf16x8 abf_t = *(const bf16x8*)(&Ab[l16][aoff]);
        bf16x8 vtf_t = *(const bf16x8*)(&VT[wv0 + l16][aoff]);
        bf16x8 abf = (lq < 2) ? abf_t : zero8();
        bf16x8 vtf = (lq < 2) ? vtf_t : zero8();
        oacc = __builtin_amdgcn_mfma_f32_16x16x32_bf16(abf, vtf, oacc, 0, 0, 0);
#pragma unroll
        for (int r = 0; r < 4; r++)
            OP[(m0 + lq * 4 + r) * H_ + hv + wv0 + l16] = oacc[r];
#pragma unroll
        for (int kt = 0; kt < 8; kt++) {
            const unsigned short* kp = KDt + (((bc * 1024) + hk0 + kt * 16 + l16) << 4) + aoff;
            bf16x8 kdtf_t = *(const bf16x8*)kp;
            bf16x8 kdtf = (lq < 2) ? kdtf_t : zero8();
            sreg[kt] = __builtin_amdgcn_mfma_f32_16x16x32_bf16(kdtf, vtf, sreg[kt], 0, 0, 0);
            ushort4 q4 = *(const ushort4*)(QLb + bc * 1024 + hk0 + kt * 16 + lq * 4);
            sreg[kt][0] *= bfu2f(q4.x); sreg[kt][1] *= bfu2f(q4.y);
            sreg[kt][2] *= bfu2f(q4.z); sreg[kt][3] *= bfu2f(q4.w);
            ushort4 pk;
            pk.x = f2bfu(sreg[kt][0]); pk.y = f2bfu(sreg[kt][1]);
            pk.z = f2bfu(sreg[kt][2]); pk.w = f2bfu(sreg[kt][3]);
            *(ushort4*)(&Sb[wv0 + l16][kt * 16 + lq * 4]) = pk;
        }
    }
}

// ---------------- RWKV post ----------------
__global__ __launch_bounds__(256) void k_rwkv_post(const float* __restrict__ P0, const float* __restrict__ P1,
                                                   const float* __restrict__ gn_w, unsigned short* __restrict__ g_io) {
    int m = blockIdx.x, tid = threadIdx.x;
    int wave = tid >> 6, lane = tid & 63;
    size_t base = (size_t)m * H_ + wave * 256 + lane * 4;
    int col = wave * 256 + lane * 4;
    float4 a = *(const float4*)(P0 + base);
    float4 b4 = *(const float4*)(P1 + base);
    float4 v; v.x = a.x + b4.x; v.y = a.y + b4.y; v.z = a.z + b4.z; v.w = a.w + b4.w;
    float ss = v.x * v.x + v.y * v.y + v.z * v.z + v.w * v.w;
#pragma unroll
    for (int off = 32; off; off >>= 1) ss += __shfl_xor(ss, off);
    float scale = rsqrtf(ss * (1.f / 256.f) + EPS_);
    float4 gn = *(const float4*)(gn_w + col);
    ushort4 gb4 = *(const ushort4*)(g_io + base);
    ushort4 out;
    out.x = f2bfu(v.x * scale * gn.x * bfu2f(gb4.x));
    out.y = f2bfu(v.y * scale * gn.y * bfu2f(gb4.y));
    out.z = f2bfu(v.z * scale * gn.z * bfu2f(gb4.z));
    out.w = f2bfu(v.w * scale * gn.w * bfu2f(gb4.w));
    *(ushort4*)(g_io + base) = out;
}

// ---------------- conv ----------------
__global__ __launch_bounds__(256) void k_conv(const unsigned short* __restrict__ C2B, const float* __restrict__ conv_w,
                                              const float* __restrict__ conv_b, unsigned short* __restrict__ XB,
                                              float* __restrict__ BCF) {
    int m = blockIdx.y;
    int c = blockIdx.x * 256 + threadIdx.x;
    int b = m >> 11, t = m & 2047;
    float acc = conv_b[c];
#pragma unroll
    for (int i = 0; i < 4; i++) {
        int tt = t - 3 + i;
        if (tt >= 0) acc = fmaf(bfu2f(C2B[((size_t)(b * T_ + tt)) * LD2 + DI + c]), conv_w[c * 4 + i], acc);
    }
    float r = siluf(acc);
    if (c < DI) XB[(size_t)m * DI + c] = f2bfu(r);
    else BCF[(size_t)m * 256 + (c - DI)] = r;
}

// ---------------- Mamba chunk prep ----------------
__global__ __launch_bounds__(256) void k_mprep(const unsigned short* __restrict__ C2B,
                                               const float* __restrict__ dt_bias, const float* __restrict__ A_log,
                                               float* __restrict__ DT, float* __restrict__ CD,
                                               float* __restrict__ WS, float* __restrict__ WSC,
                                               float* __restrict__ QJ, float* __restrict__ QLf,
                                               float* __restrict__ QC) {
    __shared__ float sums[128], offs[128], ce[16];
    const int bh = blockIdx.x;
    const int b = bh >> 5, h = bh & 31;
    const int c = threadIdx.x;
    const float A = -expf(A_log[h]);
    const float dtb = dt_bias[h];
    float dloc[16], cdl[16];
    if (c < 128) {
        float acc = 0.f;
#pragma unroll
        for (int s = 0; s < 16; s++) {
            size_t m = (size_t)b * T_ + c * 16 + s;
            float draw = bfu2f(C2B[m * LD2 + 4352 + h]) + dtb;
            float dt = draw > 20.f ? draw : log1pf(expf(draw));
            acc += dt;
            dloc[s] = dt; cdl[s] = acc;
        }
        sums[c] = acc;
    }
    __syncthreads();
    if (threadIdx.x == 0) {
        float run = 0.f;
        for (int i = 0; i < 128; i++) { offs[i] = run; run += sums[i]; }
    }
    __syncthreads();
    if (threadIdx.x < 16) {
        int last = threadIdx.x * 8 + 7;
        ce[threadIdx.x] = offs[last] + sums[last];
    }
    __syncthreads();
    if (c < 128) {
        float off = offs[c];
        float cd15 = off + cdl[15];
        float ceC = ce[c >> 3];
        QLf[bh * 128 + c] = expf(fminf(A * cdl[15], 0.f));
        size_t base = (size_t)bh * 2048 + c * 16;
#pragma unroll
        for (int s = 0; s < 16; s++) {
            float cdg = off + cdl[s];
            DT[base + s] = dloc[s];
            CD[base + s] = cdg;
            QJ[base + s] = expf(fminf(A * (cdg - off), 0.f));
            WS[base + s] = expf(fminf(A * (cd15 - cdg), 0.f)) * dloc[s];
            WSC[base + s] = expf(fminf(A * (ceC - cdg), 0.f)) * dloc[s];
        }
    }
    if (threadIdx.x < 16) {
        float prev = threadIdx.x ? ce[threadIdx.x - 1] : 0.f;
        QC[bh * 16 + threadIdx.x] = expf(fminf(A * (ce[threadIdx.x] - prev), 0.f));
    }
}

// ---------------- Mamba A-mask precompute ----------------
__global__ __launch_bounds__(64) void k_amask(const float* __restrict__ BCF,
                                              const float* __restrict__ CD, const float* __restrict__ DT,
                                              const float* __restrict__ A_log,
                                              unsigned short* __restrict__ AM) {
    const int c = blockIdx.x, bh = blockIdx.y;
    const int b = bh >> 5, h = bh & 31;
    const int lane = threadIdx.x;
    const int l16 = lane & 15, lq = lane >> 4;
    const float A = -expf(A_log[h]);
    const size_t m = (size_t)b * T_ + c * 16 + l16;
    f32x4 Aacc = (f32x4)(0.f);
#pragma unroll
    for (int ks = 0; ks < 4; ks++) {
        bf16x8 cf, bf;
        const float* cr = BCF + m * 256 + 128 + ks * 32 + lq * 8;
        const float* br = BCF + m * 256 + ks * 32 + lq * 8;
#pragma unroll
        for (int i = 0; i < 8; i++) { cf[i] = (__bf16)cr[i]; bf[i] = (__bf16)br[i]; }
        Aacc = __builtin_amdgcn_mfma_f32_16x16x32_bf16(cf, bf, Aacc, 0, 0, 0);
    }
    size_t base = ((size_t)bh * 128 + c) * 256;
    size_t tb = (size_t)bh * 2048 + c * 16;
    float cds = CD[tb + l16];
    float dts = DT[tb + l16];
#pragma unroll
    for (int r = 0; r < 4; r++) {
        int j = lq * 4 + r;
        float av = 0.f;
        if (l16 <= j) {
            float cdj = CD[tb + j];
            av = Aacc[r] * expf(fminf(A * (cdj - cds), 0.f)) * dts;
        }
        AM[base + j * 16 + l16] = f2bfu(av);
    }
}

// ---------------- Mamba carry: coarse-chunk (128 t) state via MFMA ----------------
__global__ __launch_bounds__(256) void k_mcarry(const float* __restrict__ BCF, const unsigned short* __restrict__ XB,
                                                const float* __restrict__ WSC, const float* __restrict__ QC,
                                                unsigned short* __restrict__ MSCC) {
    __shared__ float Bsf[64][128];
    __shared__ unsigned short BWt[128][72];
    __shared__ unsigned short XT[16][72];
    __shared__ float wsl[64];
    const int tid = threadIdx.x;
    const int dq = blockIdx.x, bh = blockIdx.y;
    const int b = bh >> 5, h = bh & 31;
    const int wave = tid >> 6, lane = tid & 63;
    const int l16 = lane & 15, lq = lane >> 4;
    const size_t baseM = (size_t)b * T_;
    f32x4 sreg[2];
    sreg[0] = (f32x4)(0.f); sreg[1] = (f32x4)(0.f);

    for (int cc = 0; cc < 15; ++cc) {
        float qC = QC[bh * 16 + cc];
        sreg[0] *= qC; sreg[1] *= qC;
        for (int sub = 0; sub < 2; ++sub) {
            int t0g = cc * 128 + sub * 64;
            __syncthreads();
            if (tid < 64) wsl[tid] = WSC[(size_t)bh * 2048 + t0g + tid];
#pragma unroll
            for (int i = 0; i < 8; i++) {
                int idx4 = tid + i * 256;
                int t = idx4 >> 5, s4 = (idx4 & 31) * 4;
                *(float4*)&Bsf[t][s4] = *(const float4*)(BCF + (baseM + t0g + t) * 256 + s4);
            }
#pragma unroll
            for (int i = 0; i < 4; i++) {
                int idx = tid + i * 256;
                int t = idx >> 4, d = idx & 15;
                XT[d][t] = XB[(baseM + t0g + t) * DI + h * 64 + dq * 16 + d];
            }
            __syncthreads();
            {
                int sg = tid >> 1;
                int tb = (tid & 1) * 32;
#pragma unroll
                for (int q = 0; q < 8; q++) {
                    int tt = tb + q * 4;
                    ushort4 v;
                    v.x = f2bfu(Bsf[tt + 0][sg] * wsl[tt + 0]);
                    v.y = f2bfu(Bsf[tt + 1][sg] * wsl[tt + 1]);
                    v.z = f2bfu(Bsf[tt + 2][sg] * wsl[tt + 2]);
                    v.w = f2bfu(Bsf[tt + 3][sg] * wsl[tt + 3]);
                    *(ushort4*)&BWt[sg][tt] = v;
                }
            }
            __syncthreads();
#pragma unroll
            for (int st = 0; st < 2; st++) {
#pragma unroll
                for (int ks = 0; ks < 2; ks++) {
                    bf16x8 bwf = *(const bf16x8*)&BWt[wave * 32 + st * 16 + l16][ks * 32 + lq * 8];
                    bf16x8 xtf = *(const bf16x8*)&XT[l16][ks * 32 + lq * 8];
                    sreg[st] = __builtin_amdgcn_mfma_f32_16x16x32_bf16(bwf, xtf, sreg[st], 0, 0, 0);
                }
            }
        }
        size_t dbase = ((size_t)(bh * 16 + cc + 1) * 64 + dq * 16 + l16) * 128;
#pragma unroll
        for (int st = 0; st < 2; st++) {
            ushort4 pk;
            pk.x = f2bfu(sreg[st][0]); pk.y = f2bfu(sreg[st][1]);
            pk.z = f2bfu(sreg[st][2]); pk.w = f2bfu(sreg[st][3]);
            *(ushort4*)(MSCC + dbase + wave * 32 + st * 16 + lq * 4) = pk;
        }
    }
}

// ---------------- Mamba chunked output (MFMA) ----------------
__global__ __launch_bounds__(256) void k_mout(const float* __restrict__ BCF, const unsigned short* __restrict__ XB,
                                              const unsigned short* __restrict__ AM,
                                              const float* __restrict__ QJ, const float* __restrict__ WS,
                                              const float* __restrict__ QLf, const unsigned short* __restrict__ MSCC,
                                              unsigned short* __restrict__ Y) {
    __shared__ unsigned short Sb[64][136];
    __shared__ unsigned short Cs[16][136];
    __shared__ unsigned short BWt[128][24];
    __shared__ unsigned short XT[64][24];
    __shared__ unsigned short Ab[16][24];
    __shared__ float qjl[16], wsl[16], qLl;
    const int tid = threadIdx.x;
    const int cc = blockIdx.x, bh = blockIdx.y;
    const int b = bh >> 5, h = bh & 31;
    const int wave = tid >> 6, lane = tid & 63;
    const int l16 = lane & 15, lq = lane >> 4;
    const int wv0 = wave * 16;
    const int aoff = (lq < 2) ? lq * 8 : 0;
    const size_t baseM = (size_t)b * T_;
    f32x4 sreg[8];
    if (cc == 0) {
#pragma unroll
        for (int kt = 0; kt < 8; kt++) sreg[kt] = (f32x4)(0.f);
        for (int i = tid; i < 64 * 136 / 8; i += 256) ((u32x4*)Sb)[i] = (u32x4)(0u);
    } else {
        size_t sbase = (size_t)(bh * 16 + cc) * 64;
        for (int i = tid; i < 1024; i += 256) {
            int d = i >> 4, s8 = (i & 15) * 8;
            *(u32x4*)&Sb[d][s8] = *(const u32x4*)(MSCC + (sbase + d) * 128 + s8);
        }
#pragma unroll
        for (int kt = 0; kt < 8; kt++) {
            ushort4 w4 = *(const ushort4*)(MSCC + (sbase + wv0 + l16) * 128 + kt * 16 + lq * 4);
            sreg[kt][0] = bfu2f(w4.x); sreg[kt][1] = bfu2f(w4.y);
            sreg[kt][2] = bfu2f(w4.z); sreg[kt][3] = bfu2f(w4.w);
        }
    }

    for (int fc = 0; fc < 8; ++fc) {
        const int c = cc * 8 + fc;
        const size_t m0 = baseM + c * 16;
        __syncthreads();
        if (tid < 16) {
            size_t tb = (size_t)bh * 2048 + c * 16 + tid;
            qjl[tid] = QJ[tb];
            wsl[tid] = WS[tb];
            if (tid == 0) qLl = QLf[bh * 128 + c];
        }
        {
            int j = tid >> 4, s = tid & 15;
            Ab[j][s] = AM[((size_t)bh * 128 + c) * 256 + tid];
        }
#pragma unroll
        for (int i = 0; i < 8; i++) {
            int idx = tid + i * 256;
            int t = idx >> 7, sig = idx & 127;
            Cs[t][sig] = f2bfu(BCF[(m0 + t) * 256 + 128 + sig]);
        }
#pragma unroll
        for (int i = 0; i < 4; i++) {
            int idx = tid + i * 256;
            int t = idx >> 6, d = idx & 63;
            XT[d][t] = XB[(m0 + t) * DI + h * 64 + d];
        }
        __syncthreads();
#pragma unroll
        for (int i = 0; i < 8; i++) {
            int idx = tid + i * 256;
            int t = idx >> 7, sig = idx & 127;
            BWt[sig][t] = f2bfu(BCF[(m0 + t) * 256 + sig] * wsl[t]);
        }
        __syncthreads();
        bf16x8 cf[4];
#pragma unroll
        for (int ks = 0; ks < 4; ks++) cf[ks] = *(const bf16x8*)(&Cs[l16][ks * 32 + lq * 8]);
        f32x4 oacc = (f32x4)(0.f);
#pragma unroll
        for (int ks = 0; ks < 4; ks++) {
            bf16x8 sbf = *(const bf16x8*)(&Sb[wv0 + l16][ks * 32 + lq * 8]);
            oacc = __builtin_amdgcn_mfma_f32_16x16x32_bf16(cf[ks], sbf, oacc, 0, 0, 0);
        }
#pragma unroll
        for (int r = 0; r < 4; r++) oacc[r] *= qjl[lq * 4 + r];
        bf16x8 abf_t = *(const bf16x8*)(&Ab[l16][aoff]);
        bf16x8 xtf_t = *(const bf16x8*)(&XT[wv0 + l16][aoff]);
        bf16x8 abf = (lq < 2) ? abf_t : zero8();
        bf16x8 xtf = (lq < 2) ? xtf_t : zero8();
        oacc = __builtin_amdgcn_mfma_f32_16x16x32_bf16(abf, xtf, oacc, 0, 0, 0);
#pragma unroll
        for (int r = 0; r < 4; r++)
            Y[(m0 + lq * 4 + r) * DI + h * 64 + wv0 + l16] = f2bfu(oacc[r]);
        float qL = qLl;
#pragma unroll
        for (int kt = 0; kt < 8; kt++) {
            sreg[kt] *= qL;
            bf16x8 bwf_t = *(const bf16x8*)(&BWt[kt * 16 + l16][aoff]);
            bf16x8 bwf = (lq < 2) ? bwf_t : zero8();
            sreg[kt] = __builtin_amdgcn_mfma_f32_16x16x32_bf16(bwf, xtf, sreg[kt], 0, 0, 0);
            ushort4 pk;
            pk.x = f2bfu(sreg[kt][0]); pk.y = f2bfu(sreg[kt][1]);
            pk.z = f2bfu(sreg[kt][2]); pk.w = f2bfu(sreg[kt][3]);
            *(ushort4*)(&Sb[wv0 + l16][kt * 16 + lq * 4]) = pk;
        }
    }
}

// ---------------- Mamba post ----------------
__global__ __launch_bounds__(256) void k_mamba_post(unsigned short* __restrict__ y_io,
                                                    const unsigned short* __restrict__ XB,
                                                    const unsigned short* __restrict__ C2B, const float* __restrict__ D_m,
                                                    const float* __restrict__ mnw) {
    __shared__ float red[4];
    int m = blockIdx.x, tid = threadIdx.x;
    int j0 = tid * 8;
    const float Dv = D_m[j0 >> 6];
    ushort4 ya = *(const ushort4*)(y_io + (size_t)m * DI + j0);
    ushort4 yb = *(const ushort4*)(y_io + (size_t)m * DI + j0 + 4);
    ushort4 xa = *(const ushort4*)(XB + (size_t)m * DI + j0);
    ushort4 xb = *(const ushort4*)(XB + (size_t)m * DI + j0 + 4);
    ushort4 za = *(const ushort4*)(C2B + (size_t)m * LD2 + j0);
    ushort4 zb = *(const ushort4*)(C2B + (size_t)m * LD2 + j0 + 4);
    float yv[8] = {bfu2f(ya.x), bfu2f(ya.y), bfu2f(ya.z), bfu2f(ya.w),
                   bfu2f(yb.x), bfu2f(yb.y), bfu2f(yb.z), bfu2f(yb.w)};
    float xv[8] = {bfu2f(xa.x), bfu2f(xa.y), bfu2f(xa.z), bfu2f(xa.w), bfu2f(xb.x), bfu2f(xb.y), bfu2f(xb.z), bfu2f(xb.w)};
    float zv[8] = {bfu2f(za.x), bfu2f(za.y), bfu2f(za.z), bfu2f(za.w), bfu2f(zb.x), bfu2f(zb.y), bfu2f(zb.z), bfu2f(zb.w)};
    float val[8];
    float ss = 0.f;
#pragma unroll
    for (int i = 0; i < 8; i++) {
        float v = (yv[i] + Dv * xv[i]) * siluf(zv[i]);
        val[i] = v;
        ss += v * v;
    }
#pragma unroll
    for (int off = 32; off; off >>= 1) ss += __shfl_xor(ss, off);
    if ((tid & 63) == 0) red[tid >> 6] = ss;
    __syncthreads();
    float scale = rsqrtf((red[0] + red[1] + red[2] + red[3]) * (1.f / 2048.f) + EPS_);
    ushort4 oa, ob;
    oa.x = f2bfu(val[0] * scale * mnw[j0 + 0]); oa.y = f2bfu(val[1] * scale * mnw[j0 + 1]);
    oa.z = f2bfu(val[2] * scale * mnw[j0 + 2]); oa.w = f2bfu(val[3] * scale * mnw[j0 + 3]);
    ob.x = f2bfu(val[4] * scale * mnw[j0 + 4]); ob.y = f2bfu(val[5] * scale * mnw[j0 + 5]);
    ob.z = f2bfu(val[6] * scale * mnw[j0 + 6]); ob.w = f2bfu(val[7] * scale * mnw[j0 + 7]);
    *(ushort4*)(y_io + (size_t)m * DI + j0) = oa;
    *(ushort4*)(y_io + (size_t)m * DI + j0 + 4) = ob;
}

// ---------------- gate + mix + residual + RMS(ffn_ln) ----------------
__global__ __launch_bounds__(256) void k_mix(const float* __restrict__ x, const float* __restrict__ o_r,
                                             const float* __restrict__ o_m, const float* __restrict__ gw,
                                             const float* __restrict__ gb, const float* __restrict__ flnw,
                                             float* __restrict__ x1, unsigned short* __restrict__ nx2) {
    __shared__ float red[4];
    int m = blockIdx.x, tid = threadIdx.x;
    size_t base = (size_t)m * H_ + tid * 4;
    float4 orv = *(const float4*)(o_r + base);
    float4 omv = *(const float4*)(o_m + base);
    float4 xv = *(const float4*)(x + base);
    float4 g1 = *(const float4*)(gw + tid * 4);
    float4 g2 = *(const float4*)(gw + 1024 + tid * 4);
    float ps = orv.x * g1.x + orv.y * g1.y + orv.z * g1.z + orv.w * g1.w
             + omv.x * g2.x + omv.y * g2.y + omv.z * g2.z + omv.w * g2.w;
#pragma unroll
    for (int off = 32; off; off >>= 1) ps += __shfl_xor(ps, off);
    if ((tid & 63) == 0) red[tid >> 6] = ps;
    __syncthreads();
    float g = 1.f / (1.f + expf(-(red[0] + red[1] + red[2] + red[3] + gb[0])));
    float4 xo;
    xo.x = xv.x + g * orv.x + (1.f - g) * omv.x;
    xo.y = xv.y + g * orv.y + (1.f - g) * omv.y;
    xo.z = xv.z + g * orv.z + (1.f - g) * omv.z;
    xo.w = xv.w + g * orv.w + (1.f - g) * omv.w;
    *(float4*)(x1 + base) = xo;
    float ss = xo.x * xo.x + xo.y * xo.y + xo.z * xo.z + xo.w * xo.w;
#pragma unroll
    for (int off = 32; off; off >>= 1) ss += __shfl_xor(ss, off);
    __syncthreads();
    if ((tid & 63) == 0) red[tid >> 6] = ss;
    __syncthreads();
    float scale = rsqrtf((red[0] + red[1] + red[2] + red[3]) * (1.f / 1024.f) + EPS_);
    float4 wv = *(const float4*)(flnw + tid * 4);
    ushort4 o;
    o.x = f2bfu(xo.x * scale * wv.x); o.y = f2bfu(xo.y * scale * wv.y);
    o.z = f2bfu(xo.z * scale * wv.z); o.w = f2bfu(xo.w * scale * wv.w);
    *(ushort4*)(nx2 + base) = o;
}

extern "C" void kernel_launch(void* const* d_in, const int* in_sizes, int n_in,
                              void* d_out, int out_size, void* d_ws, size_t ws_size,
                              hipStream_t stream) {
    const float* x = (const float*)d_in[0];
    const float* ln_w = (const float*)d_in[1];
    const float* r_w = (const float*)d_in[2];
    const float* k_w = (const float*)d_in[3];
    const float* v_w = (const float*)d_in[4];
    const float* g_w = (const float*)d_in[5];
    const float* dw_w = (const float*)d_in[6];
    const float* u = (const float*)d_in[7];
    const float* gn_w = (const float*)d_in[8];
    const float* o_w = (const float*)d_in[9];
    const float* in_proj = (const float*)d_in[10];
    const float* conv_w = (const float*)d_in[11];
    const float* conv_b = (const float*)d_in[12];
    const float* dt_bias = (const float*)d_in[13];
    const float* A_log = (const float*)d_in[14];
    const float* D_m = (const float*)d_in[15];
    const float* m_norm_w = (const float*)d_in[16];
    const float* out_proj = (const float*)d_in[17];
    const float* gate_w = (const float*)d_in[18];
    const float* gate_b = (const float*)d_in[19];
    const float* ffn_ln_w = (const float*)d_in[20];
    const float* ffn_w1 = (const float*)d_in[21];
    const float* ffn_w2 = (const float*)d_in[22];
    (void)in_sizes; (void)n_in;

    const size_t NEEDED = 192675840ull;
    if (ws_size < NEEDED) {
        hipMemsetAsync(d_out, 0, (size_t)out_size * 4, stream);
        return;
    }
    char* ws = (char*)d_ws;
    unsigned short* WT5 = (unsigned short*)(ws + 0);
    unsigned short* INPT = (unsigned short*)(ws + 10485760);
    unsigned short* QLb = (unsigned short*)(ws + 0);
    float* DDb = (float*)(ws + 524288);
    unsigned short* SCC = (unsigned short*)(ws + 1048576);
    unsigned short* MSCC = (unsigned short*)(ws + 1048576);
    unsigned short* F1T = (unsigned short*)(ws + 0);
    unsigned short* F2T = (unsigned short*)(ws + 10485760);
    unsigned short* OWT = (unsigned short*)(ws + 19660800);
    unsigned short* OPT = (unsigned short*)(ws + 21757952);
    unsigned short* NXB = (unsigned short*)(ws + 25952256);
    unsigned short* KDt = NXB;
    unsigned short* RB = (unsigned short*)(ws + 34340864);
    unsigned short* KB = (unsigned short*)(ws + 42729472);
    unsigned short* VB = (unsigned short*)(ws + 51118080);
    unsigned short* GB = (unsigned short*)(ws + 59506688);
    float* WF = (float*)(ws + 67895296);
    char* MTB = ws + 67895296;
    float* DTt = (float*)(MTB + 0);
    float* CDt = (float*)(MTB + 524288);
    float* WSt = (float*)(MTB + 1048576);
    float* WSCt = (float*)(MTB + 1572864);
    float* QJt = (float*)(MTB + 2097152);
    float* QLft = (float*)(MTB + 2621440);
    float* QCt = (float*)(MTB + 2654208);
    unsigned short* AMt = (unsigned short*)(MTB + 2658304);
    float* OM = (float*)(ws + 34340864);
    unsigned short* MIDB = (unsigned short*)(ws + 51118080);
    unsigned short* C2B = (unsigned short*)(ws + 84672512);
    unsigned short* XB = (unsigned short*)(ws + 121372672);
    float* BCF = (float*)(ws + 138149888);
    float* P0 = (float*)(ws + 142344192);
    float* P1 = (float*)(ws + 159121408);
    unsigned short* YB = (unsigned short*)(ws + 175898624);

    dim3 blk(256);
    k_rms1024<<<M_, blk, 0, stream>>>(x, ln_w, NXB);
    k_transpose<<<dim3(32, 32), blk, 0, stream>>>(r_w, WT5 + 0ull * 1048576, 1024, 1024, 1024);
    k_transpose<<<dim3(32, 32), blk, 0, stream>>>(k_w, WT5 + 1ull * 1048576, 1024, 1024, 1024);
    k_transpose<<<dim3(32, 32), blk, 0, stream>>>(v_w, WT5 + 2ull * 1048576, 1024, 1024, 1024);
    k_transpose<<<dim3(32, 32), blk, 0, stream>>>(g_w, WT5 + 3ull * 1048576, 1024, 1024, 1024);
    k_transpose<<<dim3(32, 32), blk, 0, stream>>>(dw_w, WT5 + 4ull * 1048576, 1024, 1024, 1024);
    k_transpose<<<dim3(140, 32), blk, 0, stream>>>(in_proj, INPT, 1024, 4384, 4480);
    k_transpose<<<dim3(32, 32), blk, 0, stream>>>(o_w, OWT, 1024, 1024, 1024);
    k_transpose<<<dim3(32, 64), blk, 0, stream>>>(out_proj, OPT, 2048, 1024, 1024);
    k_gemm_fused<<<dim3(75, 32), blk, 0, stream>>>(NXB, WT5, RB, KB, VB, GB, WF, C2B);
    k_conv<<<dim3(9, M_), blk, 0, stream>>>(C2B, conv_w, conv_b, XB, BCF);
    // rwkv chain
    k_rwkv_prep<<<dim3(128, 8), blk, 0, stream>>>(RB, KB, WF, u, KDt, QLb, DDb);
    // mamba tables (WF region dead after rwkv_prep)
    k_mprep<<<64, blk, 0, stream>>>(C2B, dt_bias, A_log, DTt, CDt, WSt, WSCt, QJt, QLft, QCt);
    k_amask<<<dim3(128, 64), dim3(64), 0, stream>>>(BCF, CDt, DTt, A_log, AMt);
    k_rwkv_carry<<<dim3(64, 8), blk, 0, stream>>>(KB, VB, QLb, SCC);
    k_rwkv_out<<<dim3(4, 16, 16), blk, 0, stream>>>(RB, KB, KDt, VB, QLb, DDb, SCC, P0, P1);
    k_rwkv_post<<<M_, blk, 0, stream>>>(P0, P1, gn_w, GB);
    // mamba chunked chain (MSCC over dead rwkv SCC)
    k_mcarry<<<dim3(4, 64), blk, 0, stream>>>(BCF, XB, WSCt, QCt, MSCC);
    k_mout<<<dim3(16, 64), blk, 0, stream>>>(BCF, XB, AMt, QJt, WSt, QLft, MSCC, YB);
    k_mamba_post<<<M_, blk, 0, stream>>>(YB, XB, C2B, D_m, m_norm_w);
    k_transpose<<<dim3(128, 32), blk, 0, stream>>>(ffn_w1, F1T, 1024, 4096, 4096);
    k_transpose<<<dim3(32, 128), blk, 0, stream>>>(ffn_w2, F2T, 4096, 1024, 1024);
    k_gemm<0><<<dim3(8, 32), blk, 0, stream>>>(GB, OWT, P1, nullptr, 4096, 1024, 1024);
    k_gemm<0><<<dim3(8, 32), blk, 0, stream>>>(YB, OPT, OM, nullptr, 4096, 1024, 2048);
    k_mix<<<M_, blk, 0, stream>>>(x, P1, OM, gate_w, gate_b, ffn_ln_w, P0, NXB);
    k_gemm<4><<<dim3(32, 32), blk, 0, stream>>>(NXB, F1T, MIDB, nullptr, 4096, 4096, 1024);
    k_gemm<5><<<dim3(8, 32), blk, 0, stream>>>(MIDB, F2T, (float*)d_out, P0, 4096, 1024, 4096);
}

// Round 16
// 933.880 us; speedup vs baseline: 1.0798x; 1.0798x over previous
//
#include <hip/hip_runtime.h>
#include <hip/hip_bf16.h>
#include <stdint.h>

#define B_ 2
#define T_ 2048
#define H_ 1024
#define M_ 4096
#define DI 2048
#define DS 128
#define CONVD 2304
#define LD2 4480
#define EPS_ 1e-6f

typedef __bf16 bf16x8 __attribute__((ext_vector_type(8)));
typedef float f32x4 __attribute__((ext_vector_type(4)));
typedef uint32_t u32x4 __attribute__((ext_vector_type(4)));

__device__ __forceinline__ unsigned short f2bfu(float f) {
    union { float f; uint32_t u; } a; a.f = f;
    uint32_t r = a.u + 0x7FFFu + ((a.u >> 16) & 1u);
    return (unsigned short)(r >> 16);
}
__device__ __forceinline__ float bfu2f(unsigned short u) {
    union { uint32_t u; float f; } a; a.u = ((uint32_t)u) << 16; return a.f;
}
__device__ __forceinline__ float siluf(float x) { return x / (1.f + expf(-x)); }
__device__ __forceinline__ bf16x8 zero8() { bf16x8 r{}; return r; }

// ---------------- RMS over 1024 cols -> bf16 ----------------
__global__ __launch_bounds__(256) void k_rms1024(const float* __restrict__ in, const float* __restrict__ w,
                                                 unsigned short* __restrict__ out) {
    __shared__ float red[4];
    int m = blockIdx.x, tid = threadIdx.x;
    size_t base = (size_t)m * H_ + tid * 4;
    float4 v = *(const float4*)(in + base);
    float ss = v.x * v.x + v.y * v.y + v.z * v.z + v.w * v.w;
#pragma unroll
    for (int off = 32; off; off >>= 1) ss += __shfl_xor(ss, off);
    if ((tid & 63) == 0) red[tid >> 6] = ss;
    __syncthreads();
    float scale = rsqrtf((red[0] + red[1] + red[2] + red[3]) * (1.f / 1024.f) + EPS_);
    float4 wv = *(const float4*)(w + tid * 4);
    ushort4 o;
    o.x = f2bfu(v.x * wv.x * scale); o.y = f2bfu(v.y * wv.y * scale);
    o.z = f2bfu(v.z * wv.z * scale); o.w = f2bfu(v.w * wv.w * scale);
    *(ushort4*)(out + base) = o;
}

// ---------------- transpose fp32 [K,N] -> bf16 [NP,K] ----------------
__global__ __launch_bounds__(256) void k_transpose(const float* __restrict__ src, unsigned short* __restrict__ dst,
                                                   int K, int N, int NP) {
    __shared__ float t[32][33];
    int n0 = blockIdx.x * 32, k0 = blockIdx.y * 32;
    int tx = threadIdx.x & 31, ty = threadIdx.x >> 5;
#pragma unroll
    for (int i = ty; i < 32; i += 8) {
        int k = k0 + i, n = n0 + tx;
        t[i][tx] = (n < N) ? src[(size_t)k * N + n] : 0.f;
    }
    __syncthreads();
#pragma unroll
    for (int i = ty; i < 32; i += 8) {
        int n = n0 + i, k = k0 + tx;
        if (n < NP) dst[(size_t)n * K + k] = f2bfu(t[tx][i]);
    }
}

// ---------------- bf16 MFMA GEMM ----------------
template <int EPI>
__global__ __launch_bounds__(256) void k_gemm(const unsigned short* __restrict__ A, const unsigned short* __restrict__ Bt,
                                              void* __restrict__ Cout, const float* __restrict__ aux,
                                              int M, int N, int K) {
    __shared__ alignas(16) unsigned short As[128 * 64];
    __shared__ alignas(16) unsigned short Bs[128 * 64];
    const int tid = threadIdx.x;
    const int m0 = blockIdx.y * 128, n0 = blockIdx.x * 128;
    const int wave = tid >> 6, lane = tid & 63;
    const int wm = (wave >> 1) * 64, wn = (wave & 1) * 64;
    const int fr = lane & 15, fg = lane >> 4;
    const int srow = tid >> 3;
    const int ske = (tid & 7) * 8;

    f32x4 acc[4][4];
#pragma unroll
    for (int m = 0; m < 4; m++)
#pragma unroll
        for (int n = 0; n < 4; n++) acc[m][n] = (f32x4)(0.f);

    const int nk = K >> 6;
    u32x4 ra[4], rb[4];
#pragma unroll
    for (int i = 0; i < 4; i++) {
        ra[i] = *(const u32x4*)(A + (size_t)(m0 + srow + 32 * i) * K + ske);
        rb[i] = *(const u32x4*)(Bt + (size_t)(n0 + srow + 32 * i) * K + ske);
    }
    for (int kt = 0; kt < nk; ++kt) {
        __syncthreads();
#pragma unroll
        for (int i = 0; i < 4; i++) {
            int lin = (tid + 256 * i) * 16;
            int sw = lin ^ (((lin >> 7) & 7) << 4);
            *(u32x4*)((char*)As + sw) = ra[i];
            *(u32x4*)((char*)Bs + sw) = rb[i];
        }
        __syncthreads();
        if (kt + 1 < nk) {
#pragma unroll
            for (int i = 0; i < 4; i++) {
                ra[i] = *(const u32x4*)(A + (size_t)(m0 + srow + 32 * i) * K + (kt + 1) * 64 + ske);
                rb[i] = *(const u32x4*)(Bt + (size_t)(n0 + srow + 32 * i) * K + (kt + 1) * 64 + ske);
            }
        }
#pragma unroll
        for (int ks = 0; ks < 2; ++ks) {
            bf16x8 af[4], bg[4];
#pragma unroll
            for (int m = 0; m < 4; m++) {
                int row = wm + m * 16 + fr;
                int lin = row * 128 + ks * 64 + fg * 16;
                af[m] = *(const bf16x8*)((const char*)As + (lin ^ ((row & 7) << 4)));
            }
#pragma unroll
            for (int n = 0; n < 4; n++) {
                int col = wn + n * 16 + fr;
                int lin = col * 128 + ks * 64 + fg * 16;
                bg[n] = *(const bf16x8*)((const char*)Bs + (lin ^ ((col & 7) << 4)));
            }
#pragma unroll
            for (int m = 0; m < 4; m++)
#pragma unroll
                for (int n = 0; n < 4; n++)
                    acc[m][n] = __builtin_amdgcn_mfma_f32_16x16x32_bf16(af[m], bg[n], acc[m][n], 0, 0, 0);
        }
    }
#pragma unroll
    for (int m = 0; m < 4; m++) {
#pragma unroll
        for (int r = 0; r < 4; r++) {
            size_t row = (size_t)(m0 + wm + m * 16 + fg * 4 + r);
#pragma unroll
            for (int n = 0; n < 4; n++) {
                size_t idx = row * N + n0 + wn + n * 16 + fr;
                float v = acc[m][n][r];
                if constexpr (EPI == 0) ((float*)Cout)[idx] = v;
                else if constexpr (EPI == 4) ((unsigned short*)Cout)[idx] = f2bfu(0.5f * v * (1.f + erff(v * 0.70710678118f)));
                else ((float*)Cout)[idx] = v + aux[idx];
            }
        }
    }
}

// ---------------- fused projection GEMM ----------------
__global__ __launch_bounds__(256) void k_gemm_fused(const unsigned short* __restrict__ A, const unsigned short* __restrict__ Bt,
                                                    unsigned short* __restrict__ RB, unsigned short* __restrict__ KB,
                                                    unsigned short* __restrict__ VB, unsigned short* __restrict__ GB,
                                                    float* __restrict__ WF, unsigned short* __restrict__ C2B) {
    __shared__ alignas(16) unsigned short As[128 * 64];
    __shared__ alignas(16) unsigned short Bs[128 * 64];
    const int tid = threadIdx.x;
    const int m0 = blockIdx.y * 128, n0 = blockIdx.x * 128;
    const int wave = tid >> 6, lane = tid & 63;
    const int wm = (wave >> 1) * 64, wn = (wave & 1) * 64;
    const int fr = lane & 15, fg = lane >> 4;
    const int srow = tid >> 3;
    const int ske = (tid & 7) * 8;
    const int K = 1024;

    f32x4 acc[4][4];
#pragma unroll
    for (int m = 0; m < 4; m++)
#pragma unroll
        for (int n = 0; n < 4; n++) acc[m][n] = (f32x4)(0.f);

    u32x4 ra[4], rb[4];
#pragma unroll
    for (int i = 0; i < 4; i++) {
        ra[i] = *(const u32x4*)(A + (size_t)(m0 + srow + 32 * i) * K + ske);
        rb[i] = *(const u32x4*)(Bt + (size_t)(n0 + srow + 32 * i) * K + ske);
    }
    for (int kt = 0; kt < 16; ++kt) {
        __syncthreads();
#pragma unroll
        for (int i = 0; i < 4; i++) {
            int lin = (tid + 256 * i) * 16;
            int sw = lin ^ (((lin >> 7) & 7) << 4);
            *(u32x4*)((char*)As + sw) = ra[i];
            *(u32x4*)((char*)Bs + sw) = rb[i];
        }
        __syncthreads();
        if (kt + 1 < 16) {
#pragma unroll
            for (int i = 0; i < 4; i++) {
                ra[i] = *(const u32x4*)(A + (size_t)(m0 + srow + 32 * i) * K + (kt + 1) * 64 + ske);
                rb[i] = *(const u32x4*)(Bt + (size_t)(n0 + srow + 32 * i) * K + (kt + 1) * 64 + ske);
            }
        }
#pragma unroll
        for (int ks = 0; ks < 2; ++ks) {
            bf16x8 af[4], bg[4];
#pragma unroll
            for (int m = 0; m < 4; m++) {
                int row = wm + m * 16 + fr;
                int lin = row * 128 + ks * 64 + fg * 16;
                af[m] = *(const bf16x8*)((const char*)As + (lin ^ ((row & 7) << 4)));
            }
#pragma unroll
            for (int n = 0; n < 4; n++) {
                int col = wn + n * 16 + fr;
                int lin = col * 128 + ks * 64 + fg * 16;
                bg[n] = *(const bf16x8*)((const char*)Bs + (lin ^ ((col & 7) << 4)));
            }
#pragma unroll
            for (int m = 0; m < 4; m++)
#pragma unroll
                for (int n = 0; n < 4; n++)
                    acc[m][n] = __builtin_amdgcn_mfma_f32_16x16x32_bf16(af[m], bg[n], acc[m][n], 0, 0, 0);
        }
    }
    const int seg = n0 >> 10;
#pragma unroll
    for (int m = 0; m < 4; m++) {
#pragma unroll
        for (int r = 0; r < 4; r++) {
            size_t row = (size_t)(m0 + wm + m * 16 + fg * 4 + r);
#pragma unroll
            for (int n = 0; n < 4; n++) {
                int gcol = n0 + wn + n * 16 + fr;
                float v = acc[m][n][r];
                if (n0 < 5120) {
                    size_t idx = row * 1024 + (gcol & 1023);
                    if (seg == 0) RB[idx] = f2bfu(v);
                    else if (seg == 1) KB[idx] = f2bfu(v);
                    else if (seg == 2) VB[idx] = f2bfu(v);
                    else if (seg == 3) GB[idx] = f2bfu(siluf(v));
                    else WF[idx] = expf(-expf(v));
                } else {
                    C2B[row * 4480 + (gcol - 5120)] = f2bfu(v);
                }
            }
        }
    }
}

// ---------------- RWKV chunk prep ----------------
__global__ __launch_bounds__(256) void k_rwkv_prep(unsigned short* __restrict__ RB, unsigned short* __restrict__ KB,
                                                   const float* __restrict__ WF, const float* __restrict__ u,
                                                   unsigned short* __restrict__ KDt, unsigned short* __restrict__ QLb,
                                                   float* __restrict__ DDb) {
    __shared__ float red[16][257];
    __shared__ float red2[16][17];
    const int c = blockIdx.x, bh = blockIdx.y;
    const int b = bh >> 2, h = bh & 3;
    const int k = threadIdx.x;
    const size_t m0 = (size_t)b * T_ + c * 16;
    const int hk = h * 256 + k;
    const float uv = u[hk];
    float Q = 1.f;
    float kd[16];
#pragma unroll
    for (int s = 0; s < 16; s++) {
        size_t off = (m0 + s) * H_ + hk;
        float r = bfu2f(RB[off]);
        float kv = bfu2f(KB[off]);
        float w = WF[off];
        RB[off] = f2bfu(r * Q);
        Q = fmaxf(Q * w, 1e-35f);
        float kdv = kv / Q;
        kd[s] = kdv;
        KB[off] = f2bfu(kdv);
        red[s][k] = r * uv * kv;
    }
    QLb[((size_t)(b * 128 + c)) * 1024 + hk] = f2bfu(Q);
    size_t kt0 = (((size_t)(b * 128 + c)) * 1024 + hk) * 16;
#pragma unroll
    for (int s = 0; s < 16; s++) KDt[kt0 + s] = f2bfu(kd[s]);
    __syncthreads();
    {
        int s = threadIdx.x >> 4, part = threadIdx.x & 15;
        float ps = 0.f;
#pragma unroll
        for (int j = 0; j < 16; j++) ps += red[s][part * 16 + j];
        red2[s][part] = ps;
    }
    __syncthreads();
    if (threadIdx.x < 32) {
        int s = threadIdx.x & 15, half = threadIdx.x >> 4;
        float d = 0.f;
#pragma unroll
        for (int j = 0; j < 8; j++) d += red2[s][half * 8 + j];
        DDb[(((size_t)bh * 128 + c) * 2 + half) * 16 + s] = d;
    }
}

// ---------------- RWKV carry ----------------
__global__ __launch_bounds__(256) void k_rwkv_carry(const unsigned short* __restrict__ KD, const unsigned short* __restrict__ VB,
                                                    const unsigned short* __restrict__ QLb, unsigned short* __restrict__ Scc) {
    __shared__ unsigned short kds[16][256];
    __shared__ float lv[16][4];
    const int vg = blockIdx.x, bh = blockIdx.y;
    const int b = bh >> 2, h = bh & 3;
    const int k = threadIdx.x;
    const int hk = h * 256 + k;
    const size_t baseM = (size_t)b * T_;
    float s0 = 0.f, s1 = 0.f, s2 = 0.f, s3 = 0.f;
    for (int c = 0; c < 128; ++c) {
        size_t m0 = baseM + c * 16;
        if ((c & 7) == 0 && c > 0) {
            int cc = c >> 3;
            size_t sb = ((size_t)(bh * 16 + cc) * 256 + vg * 4) * 256 + k;
            Scc[sb] = f2bfu(s0); Scc[sb + 256] = f2bfu(s1);
            Scc[sb + 512] = f2bfu(s2); Scc[sb + 768] = f2bfu(s3);
        }
        __syncthreads();
#pragma unroll
        for (int it = 0; it < 2; ++it) {
            int i = threadIdx.x + it * 256;
            int row = i >> 5, col8 = (i & 31) * 8;
            *(u32x4*)&kds[row][col8] = *(const u32x4*)(KD + (m0 + row) * H_ + h * 256 + col8);
        }
        if (threadIdx.x < 64) {
            int t = threadIdx.x >> 2, j = threadIdx.x & 3;
            lv[t][j] = bfu2f(VB[(m0 + t) * H_ + h * 256 + vg * 4 + j]);
        }
        __syncthreads();
        float a0 = 0.f, a1 = 0.f, a2 = 0.f, a3 = 0.f;
#pragma unroll
        for (int t = 0; t < 16; t++) {
            float kdv = bfu2f(kds[t][k]);
            a0 = fmaf(kdv, lv[t][0], a0);
            a1 = fmaf(kdv, lv[t][1], a1);
            a2 = fmaf(kdv, lv[t][2], a2);
            a3 = fmaf(kdv, lv[t][3], a3);
        }
        float ql = bfu2f(QLb[((size_t)(b * 128 + c)) * 1024 + hk]);
        s0 = (s0 + a0) * ql; s1 = (s1 + a1) * ql;
        s2 = (s2 + a2) * ql; s3 = (s3 + a3) * ql;
    }
}

// ---------------- RWKV chunked output (MFMA) ----------------
__global__ __launch_bounds__(256) void k_rwkv_out(const unsigned short* __restrict__ RT, const unsigned short* __restrict__ KD,
                                                  const unsigned short* __restrict__ KDt, const unsigned short* __restrict__ VB,
                                                  const unsigned short* __restrict__ QLb, const float* __restrict__ DDb,
                                                  const unsigned short* __restrict__ Scc,
                                                  float* __restrict__ P0, float* __restrict__ P1) {
    __shared__ unsigned short Sb[64][136];
    __shared__ unsigned short VT[64][24];
    __shared__ unsigned short Ab[16][24];
    __shared__ float dls[16];
    const int tid = threadIdx.x;
    const int vt = blockIdx.x, cc = blockIdx.y;
    const int bh = blockIdx.z >> 1, kh = blockIdx.z & 1;
    const int b = bh >> 2, h = bh & 3;
    const int wave = tid >> 6, lane = tid & 63;
    const int l16 = lane & 15, lq = lane >> 4;
    const int wv0 = wave * 16;
    const int hk0 = h * 256 + kh * 128;
    const int hv = h * 256 + vt * 64;
    const int aoff = (lq < 2) ? lq * 8 : 0;
    float* __restrict__ OP = kh ? P1 : P0;
    f32x4 sreg[8];
    if (cc == 0) {
#pragma unroll
        for (int kt = 0; kt < 8; kt++) sreg[kt] = (f32x4)(0.f);
        for (int i = tid; i < 64 * 136 / 8; i += 256) ((u32x4*)Sb)[i] = (u32x4)(0u);
    } else {
        size_t sbase = ((size_t)(bh * 16 + cc) * 256 + vt * 64);
        for (int i = tid; i < 1024; i += 256) {
            int v = i >> 4, k8 = (i & 15) * 8;
            *(u32x4*)&Sb[v][k8] = *(const u32x4*)(Scc + (sbase + v) * 256 + kh * 128 + k8);
        }
#pragma unroll
        for (int kt = 0; kt < 8; kt++) {
            ushort4 w4 = *(const ushort4*)(Scc + (sbase + wv0 + l16) * 256 + kh * 128 + kt * 16 + lq * 4);
            sreg[kt][0] = bfu2f(w4.x); sreg[kt][1] = bfu2f(w4.y);
            sreg[kt][2] = bfu2f(w4.z); sreg[kt][3] = bfu2f(w4.w);
        }
    }
    __syncthreads();

    for (int fc = 0; fc < 8; ++fc) {
        const int c = cc * 8 + fc;
        const size_t m0 = (size_t)b * T_ + c * 16;
        const size_t bc = (size_t)(b * 128 + c);
        if (fc > 0) __syncthreads();
        {
            int st = tid >> 4, v4 = (tid & 15) * 4;
            ushort4 v4v = *(const ushort4*)(VB + (m0 + st) * H_ + hv + v4);
            VT[v4 + 0][st] = v4v.x; VT[v4 + 1][st] = v4v.y;
            VT[v4 + 2][st] = v4v.z; VT[v4 + 3][st] = v4v.w;
            if (tid < 16) dls[tid] = DDb[(((size_t)bh * 128 + c) * 2 + kh) * 16 + tid];
        }
        __syncthreads();
        const size_t rowA = (m0 + l16) * H_ + hk0;
        bf16x8 rtf[4];
#pragma unroll
        for (int ks = 0; ks < 4; ks++) rtf[ks] = *(const bf16x8*)(RT + rowA + ks * 32 + lq * 8);
        f32x4 Aacc = (f32x4)(0.f);
#pragma unroll
        for (int ks = 0; ks < 4; ks++) {
            bf16x8 kdf = *(const bf16x8*)(KD + rowA + ks * 32 + lq * 8);
            Aacc = __builtin_amdgcn_mfma_f32_16x16x32_bf16(rtf[ks], kdf, Aacc, 0, 0, 0);
        }
        f32x4 oacc = (f32x4)(0.f);
#pragma unroll
        for (int ks = 0; ks < 4; ks++) {
            bf16x8 sbf = *(const bf16x8*)(&Sb[wv0 + l16][ks * 32 + lq * 8]);
            oacc = __builtin_amdgcn_mfma_f32_16x16x32_bf16(rtf[ks], sbf, oacc, 0, 0, 0);
        }
#pragma unroll
        for (int r = 0; r < 4; r++) {
            int t = lq * 4 + r, s = l16;
            float av = (s < t) ? Aacc[r] : ((s == t) ? dls[t] : 0.f);
            Ab[t][s] = f2bfu(av);
        }
        bf16x8 abf_t = *(const bf16x8*)(&Ab[l16][aoff]);
        bf16x8 vtf_t = *(const bf16x8*)(&VT[wv0 + l16][aoff]);
        bf16x8 abf = (lq < 2) ? abf_t : zero8();
        bf16x8 vtf = (lq < 2) ? vtf_t : zero8();
        oacc = __builtin_amdgcn_mfma_f32_16x16x32_bf16(abf, vtf, oacc, 0, 0, 0);
#pragma unroll
        for (int r = 0; r < 4; r++)
            OP[(m0 + lq * 4 + r) * H_ + hv + wv0 + l16] = oacc[r];
#pragma unroll
        for (int kt = 0; kt < 8; kt++) {
            const unsigned short* kp = KDt + (((bc * 1024) + hk0 + kt * 16 + l16) << 4) + aoff;
            bf16x8 kdtf_t = *(const bf16x8*)kp;
            bf16x8 kdtf = (lq < 2) ? kdtf_t : zero8();
            sreg[kt] = __builtin_amdgcn_mfma_f32_16x16x32_bf16(kdtf, vtf, sreg[kt], 0, 0, 0);
            ushort4 q4 = *(const ushort4*)(QLb + bc * 1024 + hk0 + kt * 16 + lq * 4);
            sreg[kt][0] *= bfu2f(q4.x); sreg[kt][1] *= bfu2f(q4.y);
            sreg[kt][2] *= bfu2f(q4.z); sreg[kt][3] *= bfu2f(q4.w);
            ushort4 pk;
            pk.x = f2bfu(sreg[kt][0]); pk.y = f2bfu(sreg[kt][1]);
            pk.z = f2bfu(sreg[kt][2]); pk.w = f2bfu(sreg[kt][3]);
            *(ushort4*)(&Sb[wv0 + l16][kt * 16 + lq * 4]) = pk;
        }
    }
}

// ---------------- RWKV post ----------------
__global__ __launch_bounds__(256) void k_rwkv_post(const float* __restrict__ P0, const float* __restrict__ P1,
                                                   const float* __restrict__ gn_w, unsigned short* __restrict__ g_io) {
    int m = blockIdx.x, tid = threadIdx.x;
    int wave = tid >> 6, lane = tid & 63;
    size_t base = (size_t)m * H_ + wave * 256 + lane * 4;
    int col = wave * 256 + lane * 4;
    float4 a = *(const float4*)(P0 + base);
    float4 b4 = *(const float4*)(P1 + base);
    float4 v; v.x = a.x + b4.x; v.y = a.y + b4.y; v.z = a.z + b4.z; v.w = a.w + b4.w;
    float ss = v.x * v.x + v.y * v.y + v.z * v.z + v.w * v.w;
#pragma unroll
    for (int off = 32; off; off >>= 1) ss += __shfl_xor(ss, off);
    float scale = rsqrtf(ss * (1.f / 256.f) + EPS_);
    float4 gn = *(const float4*)(gn_w + col);
    ushort4 gb4 = *(const ushort4*)(g_io + base);
    ushort4 out;
    out.x = f2bfu(v.x * scale * gn.x * bfu2f(gb4.x));
    out.y = f2bfu(v.y * scale * gn.y * bfu2f(gb4.y));
    out.z = f2bfu(v.z * scale * gn.z * bfu2f(gb4.z));
    out.w = f2bfu(v.w * scale * gn.w * bfu2f(gb4.w));
    *(ushort4*)(g_io + base) = out;
}

// ---------------- conv ----------------
__global__ __launch_bounds__(256) void k_conv(const unsigned short* __restrict__ C2B, const float* __restrict__ conv_w,
                                              const float* __restrict__ conv_b, unsigned short* __restrict__ XB,
                                              float* __restrict__ BCF) {
    int m = blockIdx.y;
    int c = blockIdx.x * 256 + threadIdx.x;
    int b = m >> 11, t = m & 2047;
    float acc = conv_b[c];
#pragma unroll
    for (int i = 0; i < 4; i++) {
        int tt = t - 3 + i;
        if (tt >= 0) acc = fmaf(bfu2f(C2B[((size_t)(b * T_ + tt)) * LD2 + DI + c]), conv_w[c * 4 + i], acc);
    }
    float r = siluf(acc);
    if (c < DI) XB[(size_t)m * DI + c] = f2bfu(r);
    else BCF[(size_t)m * 256 + (c - DI)] = r;
}

// ---------------- Mamba chunk prep: dt, global cumsum, decay tables ----------------
__global__ __launch_bounds__(256) void k_mprep(const unsigned short* __restrict__ C2B,
                                               const float* __restrict__ dt_bias, const float* __restrict__ A_log,
                                               float* __restrict__ DT, float* __restrict__ CD,
                                               float* __restrict__ WS, float* __restrict__ WSC,
                                               float* __restrict__ QJ, float* __restrict__ QLf,
                                               float* __restrict__ QC) {
    __shared__ float sums[128], offs[128], ce[16];
    const int bh = blockIdx.x;
    const int b = bh >> 5, h = bh & 31;
    const int c = threadIdx.x;
    const float A = -expf(A_log[h]);
    const float dtb = dt_bias[h];
    float dloc[16], cdl[16];
    if (c < 128) {
        float acc = 0.f;
#pragma unroll
        for (int s = 0; s < 16; s++) {
            size_t m = (size_t)b * T_ + c * 16 + s;
            float draw = bfu2f(C2B[m * LD2 + 4352 + h]) + dtb;
            float dt = draw > 20.f ? draw : log1pf(expf(draw));
            acc += dt;
            dloc[s] = dt; cdl[s] = acc;
        }
        sums[c] = acc;
    }
    __syncthreads();
    if (threadIdx.x == 0) {
        float run = 0.f;
        for (int i = 0; i < 128; i++) { offs[i] = run; run += sums[i]; }
    }
    __syncthreads();
    if (threadIdx.x < 16) {
        int last = threadIdx.x * 8 + 7;
        ce[threadIdx.x] = offs[last] + sums[last];
    }
    __syncthreads();
    if (c < 128) {
        float off = offs[c];
        float cd15 = off + cdl[15];
        float ceC = ce[c >> 3];
        QLf[bh * 128 + c] = expf(fminf(A * cdl[15], 0.f));
        size_t base = (size_t)bh * 2048 + c * 16;
#pragma unroll
        for (int s = 0; s < 16; s++) {
            float cdg = off + cdl[s];
            DT[base + s] = dloc[s];
            CD[base + s] = cdg;
            QJ[base + s] = expf(fminf(A * (cdg - off), 0.f));
            WS[base + s] = expf(fminf(A * (cd15 - cdg), 0.f)) * dloc[s];
            WSC[base + s] = expf(fminf(A * (ceC - cdg), 0.f)) * dloc[s];
        }
    }
    if (threadIdx.x < 16) {
        float prev = threadIdx.x ? ce[threadIdx.x - 1] : 0.f;
        QC[bh * 16 + threadIdx.x] = expf(fminf(A * (ce[threadIdx.x] - prev), 0.f));
    }
}

// ---------------- Mamba A-mask precompute ----------------
__global__ __launch_bounds__(64) void k_amask(const float* __restrict__ BCF,
                                              const float* __restrict__ CD, const float* __restrict__ DT,
                                              const float* __restrict__ A_log,
                                              unsigned short* __restrict__ AM) {
    const int c = blockIdx.x, bh = blockIdx.y;
    const int b = bh >> 5, h = bh & 31;
    const int lane = threadIdx.x;
    const int l16 = lane & 15, lq = lane >> 4;
    const float A = -expf(A_log[h]);
    const size_t m = (size_t)b * T_ + c * 16 + l16;
    f32x4 Aacc = (f32x4)(0.f);
#pragma unroll
    for (int ks = 0; ks < 4; ks++) {
        bf16x8 cf, bf;
        const float* cr = BCF + m * 256 + 128 + ks * 32 + lq * 8;
        const float* br = BCF + m * 256 + ks * 32 + lq * 8;
#pragma unroll
        for (int i = 0; i < 8; i++) { cf[i] = (__bf16)cr[i]; bf[i] = (__bf16)br[i]; }
        Aacc = __builtin_amdgcn_mfma_f32_16x16x32_bf16(cf, bf, Aacc, 0, 0, 0);
    }
    size_t base = ((size_t)bh * 128 + c) * 256;
    size_t tb = (size_t)bh * 2048 + c * 16;
    float cds = CD[tb + l16];
    float dts = DT[tb + l16];
#pragma unroll
    for (int r = 0; r < 4; r++) {
        int j = lq * 4 + r;
        float av = 0.f;
        if (l16 <= j) {
            float cdj = CD[tb + j];
            av = Aacc[r] * expf(fminf(A * (cdj - cds), 0.f)) * dts;
        }
        AM[base + j * 16 + l16] = f2bfu(av);
    }
}

// ---------------- Mamba carry: coarse-chunk (128 t) state via MFMA ----------------
__global__ __launch_bounds__(256) void k_mcarry(const float* __restrict__ BCF, const unsigned short* __restrict__ XB,
                                                const float* __restrict__ WSC, const float* __restrict__ QC,
                                                unsigned short* __restrict__ MSCC) {
    __shared__ float Bsf[64][128];
    __shared__ unsigned short BWt[128][72];
    __shared__ unsigned short XT[16][72];
    __shared__ float wsl[64];
    const int tid = threadIdx.x;
    const int dq = blockIdx.x, bh = blockIdx.y;
    const int b = bh >> 5, h = bh & 31;
    const int wave = tid >> 6, lane = tid & 63;
    const int l16 = lane & 15, lq = lane >> 4;
    const size_t baseM = (size_t)b * T_;
    f32x4 sreg[2];
    sreg[0] = (f32x4)(0.f); sreg[1] = (f32x4)(0.f);

    for (int cc = 0; cc < 15; ++cc) {
        float qC = QC[bh * 16 + cc];
        sreg[0] *= qC; sreg[1] *= qC;
        for (int sub = 0; sub < 2; ++sub) {
            int t0g = cc * 128 + sub * 64;
            __syncthreads();
            if (tid < 64) wsl[tid] = WSC[(size_t)bh * 2048 + t0g + tid];
#pragma unroll
            for (int i = 0; i < 8; i++) {
                int idx4 = tid + i * 256;
                int t = idx4 >> 5, s4 = (idx4 & 31) * 4;
                *(float4*)&Bsf[t][s4] = *(const float4*)(BCF + (baseM + t0g + t) * 256 + s4);
            }
#pragma unroll
            for (int i = 0; i < 4; i++) {
                int idx = tid + i * 256;
                int t = idx >> 4, d = idx & 15;
                XT[d][t] = XB[(baseM + t0g + t) * DI + h * 64 + dq * 16 + d];
            }
            __syncthreads();
            {
                int sg = tid >> 1;
                int tb = (tid & 1) * 32;
#pragma unroll
                for (int q = 0; q < 8; q++) {
                    int tt = tb + q * 4;
                    ushort4 v;
                    v.x = f2bfu(Bsf[tt + 0][sg] * wsl[tt + 0]);
                    v.y = f2bfu(Bsf[tt + 1][sg] * wsl[tt + 1]);
                    v.z = f2bfu(Bsf[tt + 2][sg] * wsl[tt + 2]);
                    v.w = f2bfu(Bsf[tt + 3][sg] * wsl[tt + 3]);
                    *(ushort4*)&BWt[sg][tt] = v;
                }
            }
            __syncthreads();
#pragma unroll
            for (int st = 0; st < 2; st++) {
#pragma unroll
                for (int ks = 0; ks < 2; ks++) {
                    bf16x8 bwf = *(const bf16x8*)&BWt[wave * 32 + st * 16 + l16][ks * 32 + lq * 8];
                    bf16x8 xtf = *(const bf16x8*)&XT[l16][ks * 32 + lq * 8];
                    sreg[st] = __builtin_amdgcn_mfma_f32_16x16x32_bf16(bwf, xtf, sreg[st], 0, 0, 0);
                }
            }
        }
        size_t dbase = ((size_t)(bh * 16 + cc + 1) * 64 + dq * 16 + l16) * 128;
#pragma unroll
        for (int st = 0; st < 2; st++) {
            ushort4 pk;
            pk.x = f2bfu(sreg[st][0]); pk.y = f2bfu(sreg[st][1]);
            pk.z = f2bfu(sreg[st][2]); pk.w = f2bfu(sreg[st][3]);
            *(ushort4*)(MSCC + dbase + wave * 32 + st * 16 + lq * 4) = pk;
        }
    }
}

// ---------------- Mamba chunked output (MFMA) ----------------
__global__ __launch_bounds__(256) void k_mout(const float* __restrict__ BCF, const unsigned short* __restrict__ XB,
                                              const unsigned short* __restrict__ AM,
                                              const float* __restrict__ QJ, const float* __restrict__ WS,
                                              const float* __restrict__ QLf, const unsigned short* __restrict__ MSCC,
                                              unsigned short* __restrict__ Y) {
    __shared__ unsigned short Sb[64][136];
    __shared__ unsigned short Cs[16][136];
    __shared__ unsigned short BWt[128][24];
    __shared__ unsigned short XT[64][24];
    __shared__ unsigned short Ab[16][24];
    __shared__ float qjl[16], wsl[16], qLl;
    const int tid = threadIdx.x;
    const int cc = blockIdx.x, bh = blockIdx.y;
    const int b = bh >> 5, h = bh & 31;
    const int wave = tid >> 6, lane = tid & 63;
    const int l16 = lane & 15, lq = lane >> 4;
    const int wv0 = wave * 16;
    const int aoff = (lq < 2) ? lq * 8 : 0;
    const size_t baseM = (size_t)b * T_;
    f32x4 sreg[8];
    if (cc == 0) {
#pragma unroll
        for (int kt = 0; kt < 8; kt++) sreg[kt] = (f32x4)(0.f);
        for (int i = tid; i < 64 * 136 / 8; i += 256) ((u32x4*)Sb)[i] = (u32x4)(0u);
    } else {
        size_t sbase = (size_t)(bh * 16 + cc) * 64;
        for (int i = tid; i < 1024; i += 256) {
            int d = i >> 4, s8 = (i & 15) * 8;
            *(u32x4*)&Sb[d][s8] = *(const u32x4*)(MSCC + (sbase + d) * 128 + s8);
        }
#pragma unroll
        for (int kt = 0; kt < 8; kt++) {
            ushort4 w4 = *(const ushort4*)(MSCC + (sbase + wv0 + l16) * 128 + kt * 16 + lq * 4);
            sreg[kt][0] = bfu2f(w4.x); sreg[kt][1] = bfu2f(w4.y);
            sreg[kt][2] = bfu2f(w4.z); sreg[kt][3] = bfu2f(w4.w);
        }
    }

    for (int fc = 0; fc < 8; ++fc) {
        const int c = cc * 8 + fc;
        const size_t m0 = baseM + c * 16;
        __syncthreads();
        if (tid < 16) {
            size_t tb = (size_t)bh * 2048 + c * 16 + tid;
            qjl[tid] = QJ[tb];
            wsl[tid] = WS[tb];
            if (tid == 0) qLl = QLf[bh * 128 + c];
        }
        {
            int j = tid >> 4, s = tid & 15;
            Ab[j][s] = AM[((size_t)bh * 128 + c) * 256 + tid];
        }
#pragma unroll
        for (int i = 0; i < 8; i++) {
            int idx = tid + i * 256;
            int t = idx >> 7, sig = idx & 127;
            Cs[t][sig] = f2bfu(BCF[(m0 + t) * 256 + 128 + sig]);
        }
#pragma unroll
        for (int i = 0; i < 4; i++) {
            int idx = tid + i * 256;
            int t = idx >> 6, d = idx & 63;
            XT[d][t] = XB[(m0 + t) * DI + h * 64 + d];
        }
        __syncthreads();
#pragma unroll
        for (int i = 0; i < 8; i++) {
            int idx = tid + i * 256;
            int t = idx >> 7, sig = idx & 127;
            BWt[sig][t] = f2bfu(BCF[(m0 + t) * 256 + sig] * wsl[t]);
        }
        __syncthreads();
        bf16x8 cf[4];
#pragma unroll
        for (int ks = 0; ks < 4; ks++) cf[ks] = *(const bf16x8*)(&Cs[l16][ks * 32 + lq * 8]);
        f32x4 oacc = (f32x4)(0.f);
#pragma unroll
        for (int ks = 0; ks < 4; ks++) {
            bf16x8 sbf = *(const bf16x8*)(&Sb[wv0 + l16][ks * 32 + lq * 8]);
            oacc = __builtin_amdgcn_mfma_f32_16x16x32_bf16(cf[ks], sbf, oacc, 0, 0, 0);
        }
#pragma unroll
        for (int r = 0; r < 4; r++) oacc[r] *= qjl[lq * 4 + r];
        bf16x8 abf_t = *(const bf16x8*)(&Ab[l16][aoff]);
        bf16x8 xtf_t = *(const bf16x8*)(&XT[wv0 + l16][aoff]);
        bf16x8 abf = (lq < 2) ? abf_t : zero8();
        bf16x8 xtf = (lq < 2) ? xtf_t : zero8();
        oacc = __builtin_amdgcn_mfma_f32_16x16x32_bf16(abf, xtf, oacc, 0, 0, 0);
#pragma unroll
        for (int r = 0; r < 4; r++)
            Y[(m0 + lq * 4 + r) * DI + h * 64 + wv0 + l16] = f2bfu(oacc[r]);
        float qL = qLl;
#pragma unroll
        for (int kt = 0; kt < 8; kt++) {
            sreg[kt] *= qL;
            bf16x8 bwf_t = *(const bf16x8*)(&BWt[kt * 16 + l16][aoff]);
            bf16x8 bwf = (lq < 2) ? bwf_t : zero8();
            sreg[kt] = __builtin_amdgcn_mfma_f32_16x16x32_bf16(bwf, xtf, sreg[kt], 0, 0, 0);
            ushort4 pk;
            pk.x = f2bfu(sreg[kt][0]); pk.y = f2bfu(sreg[kt][1]);
            pk.z = f2bfu(sreg[kt][2]); pk.w = f2bfu(sreg[kt][3]);
            *(ushort4*)(&Sb[wv0 + l16][kt * 16 + lq * 4]) = pk;
        }
    }
}

// ---------------- Mamba post ----------------
__global__ __launch_bounds__(256) void k_mamba_post(unsigned short* __restrict__ y_io,
                                                    const unsigned short* __restrict__ XB,
                                                    const unsigned short* __restrict__ C2B, const float* __restrict__ D_m,
                                                    const float* __restrict__ mnw) {
    __shared__ float red[4];
    int m = blockIdx.x, tid = threadIdx.x;
    int j0 = tid * 8;
    const float Dv = D_m[j0 >> 6];
    ushort4 ya = *(const ushort4*)(y_io + (size_t)m * DI + j0);
    ushort4 yb = *(const ushort4*)(y_io + (size_t)m * DI + j0 + 4);
    ushort4 xa = *(const ushort4*)(XB + (size_t)m * DI + j0);
    ushort4 xb = *(const ushort4*)(XB + (size_t)m * DI + j0 + 4);
    ushort4 za = *(const ushort4*)(C2B + (size_t)m * LD2 + j0);
    ushort4 zb = *(const ushort4*)(C2B + (size_t)m * LD2 + j0 + 4);
    float yv[8] = {bfu2f(ya.x), bfu2f(ya.y), bfu2f(ya.z), bfu2f(ya.w),
                   bfu2f(yb.x), bfu2f(yb.y), bfu2f(yb.z), bfu2f(yb.w)};
    float xv[8] = {bfu2f(xa.x), bfu2f(xa.y), bfu2f(xa.z), bfu2f(xa.w), bfu2f(xb.x), bfu2f(xb.y), bfu2f(xb.z), bfu2f(xb.w)};
    float zv[8] = {bfu2f(za.x), bfu2f(za.y), bfu2f(za.z), bfu2f(za.w), bfu2f(zb.x), bfu2f(zb.y), bfu2f(zb.z), bfu2f(zb.w)};
    float val[8];
    float ss = 0.f;
#pragma unroll
    for (int i = 0; i < 8; i++) {
        float v = (yv[i] + Dv * xv[i]) * siluf(zv[i]);
        val[i] = v;
        ss += v * v;
    }
#pragma unroll
    for (int off = 32; off; off >>= 1) ss += __shfl_xor(ss, off);
    if ((tid & 63) == 0) red[tid >> 6] = ss;
    __syncthreads();
    float scale = rsqrtf((red[0] + red[1] + red[2] + red[3]) * (1.f / 2048.f) + EPS_);
    ushort4 oa, ob;
    oa.x = f2bfu(val[0] * scale * mnw[j0 + 0]); oa.y = f2bfu(val[1] * scale * mnw[j0 + 1]);
    oa.z = f2bfu(val[2] * scale * mnw[j0 + 2]); oa.w = f2bfu(val[3] * scale * mnw[j0 + 3]);
    ob.x = f2bfu(val[4] * scale * mnw[j0 + 4]); ob.y = f2bfu(val[5] * scale * mnw[j0 + 5]);
    ob.z = f2bfu(val[6] * scale * mnw[j0 + 6]); ob.w = f2bfu(val[7] * scale * mnw[j0 + 7]);
    *(ushort4*)(y_io + (size_t)m * DI + j0) = oa;
    *(ushort4*)(y_io + (size_t)m * DI + j0 + 4) = ob;
}

// ---------------- gate + mix + residual + RMS(ffn_ln) ----------------
__global__ __launch_bounds__(256) void k_mix(const float* __restrict__ x, const float* __restrict__ o_r,
                                             const float* __restrict__ o_m, const float* __restrict__ gw,
                                             const float* __restrict__ gb, const float* __restrict__ flnw,
                                             float* __restrict__ x1, unsigned short* __restrict__ nx2) {
    __shared__ float red[4];
    int m = blockIdx.x, tid = threadIdx.x;
    size_t base = (size_t)m * H_ + tid * 4;
    float4 orv = *(const float4*)(o_r + base);
    float4 omv = *(const float4*)(o_m + base);
    float4 xv = *(const float4*)(x + base);
    float4 g1 = *(const float4*)(gw + tid * 4);
    float4 g2 = *(const float4*)(gw + 1024 + tid * 4);
    float ps = orv.x * g1.x + orv.y * g1.y + orv.z * g1.z + orv.w * g1.w
             + omv.x * g2.x + omv.y * g2.y + omv.z * g2.z + omv.w * g2.w;
#pragma unroll
    for (int off = 32; off; off >>= 1) ps += __shfl_xor(ps, off);
    if ((tid & 63) == 0) red[tid >> 6] = ps;
    __syncthreads();
    float g = 1.f / (1.f + expf(-(red[0] + red[1] + red[2] + red[3] + gb[0])));
    float4 xo;
    xo.x = xv.x + g * orv.x + (1.f - g) * omv.x;
    xo.y = xv.y + g * orv.y + (1.f - g) * omv.y;
    xo.z = xv.z + g * orv.z + (1.f - g) * omv.z;
    xo.w = xv.w + g * orv.w + (1.f - g) * omv.w;
    *(float4*)(x1 + base) = xo;
    float ss = xo.x * xo.x + xo.y * xo.y + xo.z * xo.z + xo.w * xo.w;
#pragma unroll
    for (int off = 32; off; off >>= 1) ss += __shfl_xor(ss, off);
    __syncthreads();
    if ((tid & 63) == 0) red[tid >> 6] = ss;
    __syncthreads();
    float scale = rsqrtf((red[0] + red[1] + red[2] + red[3]) * (1.f / 1024.f) + EPS_);
    float4 wv = *(const float4*)(flnw + tid * 4);
    ushort4 o;
    o.x = f2bfu(xo.x * scale * wv.x); o.y = f2bfu(xo.y * scale * wv.y);
    o.z = f2bfu(xo.z * scale * wv.z); o.w = f2bfu(xo.w * scale * wv.w);
    *(ushort4*)(nx2 + base) = o;
}

extern "C" void kernel_launch(void* const* d_in, const int* in_sizes, int n_in,
                              void* d_out, int out_size, void* d_ws, size_t ws_size,
                              hipStream_t stream) {
    const float* x = (const float*)d_in[0];
    const float* ln_w = (const float*)d_in[1];
    const float* r_w = (const float*)d_in[2];
    const float* k_w = (const float*)d_in[3];
    const float* v_w = (const float*)d_in[4];
    const float* g_w = (const float*)d_in[5];
    const float* dw_w = (const float*)d_in[6];
    const float* u = (const float*)d_in[7];
    const float* gn_w = (const float*)d_in[8];
    const float* o_w = (const float*)d_in[9];
    const float* in_proj = (const float*)d_in[10];
    const float* conv_w = (const float*)d_in[11];
    const float* conv_b = (const float*)d_in[12];
    const float* dt_bias = (const float*)d_in[13];
    const float* A_log = (const float*)d_in[14];
    const float* D_m = (const float*)d_in[15];
    const float* m_norm_w = (const float*)d_in[16];
    const float* out_proj = (const float*)d_in[17];
    const float* gate_w = (const float*)d_in[18];
    const float* gate_b = (const float*)d_in[19];
    const float* ffn_ln_w = (const float*)d_in[20];
    const float* ffn_w1 = (const float*)d_in[21];
    const float* ffn_w2 = (const float*)d_in[22];
    (void)in_sizes; (void)n_in;

    const size_t NEEDED = 192675840ull;
    if (ws_size < NEEDED) {
        hipMemsetAsync(d_out, 0, (size_t)out_size * 4, stream);
        return;
    }
    char* ws = (char*)d_ws;
    unsigned short* WT5 = (unsigned short*)(ws + 0);
    unsigned short* INPT = (unsigned short*)(ws + 10485760);
    unsigned short* QLb = (unsigned short*)(ws + 0);
    float* DDb = (float*)(ws + 524288);
    unsigned short* SCC = (unsigned short*)(ws + 1048576);
    unsigned short* MSCC = (unsigned short*)(ws + 1048576);
    unsigned short* F1T = (unsigned short*)(ws + 0);
    unsigned short* F2T = (unsigned short*)(ws + 10485760);
    unsigned short* OWT = (unsigned short*)(ws + 19660800);
    unsigned short* OPT = (unsigned short*)(ws + 21757952);
    unsigned short* NXB = (unsigned short*)(ws + 25952256);
    unsigned short* KDt = NXB;
    unsigned short* RB = (unsigned short*)(ws + 34340864);
    unsigned short* KB = (unsigned short*)(ws + 42729472);
    unsigned short* VB = (unsigned short*)(ws + 51118080);
    unsigned short* GB = (unsigned short*)(ws + 59506688);
    float* WF = (float*)(ws + 67895296);
    char* MTB = ws + 67895296;
    float* DTt = (float*)(MTB + 0);
    float* CDt = (float*)(MTB + 524288);
    float* WSt = (float*)(MTB + 1048576);
    float* WSCt = (float*)(MTB + 1572864);
    float* QJt = (float*)(MTB + 2097152);
    float* QLft = (float*)(MTB + 2621440);
    float* QCt = (float*)(MTB + 2654208);
    unsigned short* AMt = (unsigned short*)(MTB + 2658304);
    float* OM = (float*)(ws + 34340864);
    unsigned short* MIDB = (unsigned short*)(ws + 51118080);
    unsigned short* C2B = (unsigned short*)(ws + 84672512);
    unsigned short* XB = (unsigned short*)(ws + 121372672);
    float* BCF = (float*)(ws + 138149888);
    float* P0 = (float*)(ws + 142344192);
    float* P1 = (float*)(ws + 159121408);
    unsigned short* YB = (unsigned short*)(ws + 175898624);

    dim3 blk(256);
    k_rms1024<<<M_, blk, 0, stream>>>(x, ln_w, NXB);
    k_transpose<<<dim3(32, 32), blk, 0, stream>>>(r_w, WT5 + 0ull * 1048576, 1024, 1024, 1024);
    k_transpose<<<dim3(32, 32), blk, 0, stream>>>(k_w, WT5 + 1ull * 1048576, 1024, 1024, 1024);
    k_transpose<<<dim3(32, 32), blk, 0, stream>>>(v_w, WT5 + 2ull * 1048576, 1024, 1024, 1024);
    k_transpose<<<dim3(32, 32), blk, 0, stream>>>(g_w, WT5 + 3ull * 1048576, 1024, 1024, 1024);
    k_transpose<<<dim3(32, 32), blk, 0, stream>>>(dw_w, WT5 + 4ull * 1048576, 1024, 1024, 1024);
    k_transpose<<<dim3(140, 32), blk, 0, stream>>>(in_proj, INPT, 1024, 4384, 4480);
    k_transpose<<<dim3(32, 32), blk, 0, stream>>>(o_w, OWT, 1024, 1024, 1024);
    k_transpose<<<dim3(32, 64), blk, 0, stream>>>(out_proj, OPT, 2048, 1024, 1024);
    k_gemm_fused<<<dim3(75, 32), blk, 0, stream>>>(NXB, WT5, RB, KB, VB, GB, WF, C2B);
    k_conv<<<dim3(9, M_), blk, 0, stream>>>(C2B, conv_w, conv_b, XB, BCF);
    // rwkv chain
    k_rwkv_prep<<<dim3(128, 8), blk, 0, stream>>>(RB, KB, WF, u, KDt, QLb, DDb);
    // mamba tables (WF region dead after rwkv_prep)
    k_mprep<<<64, blk, 0, stream>>>(C2B, dt_bias, A_log, DTt, CDt, WSt, WSCt, QJt, QLft, QCt);
    k_amask<<<dim3(128, 64), dim3(64), 0, stream>>>(BCF, CDt, DTt, A_log, AMt);
    k_rwkv_carry<<<dim3(64, 8), blk, 0, stream>>>(KB, VB, QLb, SCC);
    k_rwkv_out<<<dim3(4, 16, 16), blk, 0, stream>>>(RB, KB, KDt, VB, QLb, DDb, SCC, P0, P1);
    k_rwkv_post<<<M_, blk, 0, stream>>>(P0, P1, gn_w, GB);
    // mamba chunked chain (MSCC over dead rwkv SCC)
    k_mcarry<<<dim3(4, 64), blk, 0, stream>>>(BCF, XB, WSCt, QCt, MSCC);
    k_mout<<<dim3(16, 64), blk, 0, stream>>>(BCF, XB, AMt, QJt, WSt, QLft, MSCC, YB);
    k_mamba_post<<<M_, blk, 0, stream>>>(YB, XB, C2B, D_m, m_norm_w);
    k_transpose<<<dim3(128, 32), blk, 0, stream>>>(ffn_w1, F1T, 1024, 4096, 4096);
    k_transpose<<<dim3(32, 128), blk, 0, stream>>>(ffn_w2, F2T, 4096, 1024, 1024);
    k_gemm<0><<<dim3(8, 32), blk, 0, stream>>>(GB, OWT, P1, nullptr, 4096, 1024, 1024);
    k_gemm<0><<<dim3(8, 32), blk, 0, stream>>>(YB, OPT, OM, nullptr, 4096, 1024, 2048);
    k_mix<<<M_, blk, 0, stream>>>(x, P1, OM, gate_w, gate_b, ffn_ln_w, P0, NXB);
    k_gemm<4><<<dim3(32, 32), blk, 0, stream>>>(NXB, F1T, MIDB, nullptr, 4096, 4096, 1024);
    k_gemm<5><<<dim3(8, 32), blk, 0, stream>>>(MIDB, F2T, (float*)d_out, P0, 4096, 1024, 4096);
}

// Round 17
// 908.787 us; speedup vs baseline: 1.1096x; 1.0276x over previous
//
#include <hip/hip_runtime.h>
#include <hip/hip_bf16.h>
#include <stdint.h>

#define B_ 2
#define T_ 2048
#define H_ 1024
#define M_ 4096
#define DI 2048
#define DS 128
#define CONVD 2304
#define LD2 4480
#define EPS_ 1e-6f

typedef __bf16 bf16x8 __attribute__((ext_vector_type(8)));
typedef float f32x4 __attribute__((ext_vector_type(4)));
typedef uint32_t u32x4 __attribute__((ext_vector_type(4)));

__device__ __forceinline__ unsigned short f2bfu(float f) {
    union { float f; uint32_t u; } a; a.f = f;
    uint32_t r = a.u + 0x7FFFu + ((a.u >> 16) & 1u);
    return (unsigned short)(r >> 16);
}
__device__ __forceinline__ float bfu2f(unsigned short u) {
    union { uint32_t u; float f; } a; a.u = ((uint32_t)u) << 16; return a.f;
}
__device__ __forceinline__ float siluf(float x) { return x / (1.f + expf(-x)); }
__device__ __forceinline__ bf16x8 zero8() { bf16x8 r{}; return r; }

// ---------------- RMS over 1024 cols -> bf16 ----------------
__global__ __launch_bounds__(256) void k_rms1024(const float* __restrict__ in, const float* __restrict__ w,
                                                 unsigned short* __restrict__ out) {
    __shared__ float red[4];
    int m = blockIdx.x, tid = threadIdx.x;
    size_t base = (size_t)m * H_ + tid * 4;
    float4 v = *(const float4*)(in + base);
    float ss = v.x * v.x + v.y * v.y + v.z * v.z + v.w * v.w;
#pragma unroll
    for (int off = 32; off; off >>= 1) ss += __shfl_xor(ss, off);
    if ((tid & 63) == 0) red[tid >> 6] = ss;
    __syncthreads();
    float scale = rsqrtf((red[0] + red[1] + red[2] + red[3]) * (1.f / 1024.f) + EPS_);
    float4 wv = *(const float4*)(w + tid * 4);
    ushort4 o;
    o.x = f2bfu(v.x * wv.x * scale); o.y = f2bfu(v.y * wv.y * scale);
    o.z = f2bfu(v.z * wv.z * scale); o.w = f2bfu(v.w * wv.w * scale);
    *(ushort4*)(out + base) = o;
}

// ---------------- transpose fp32 [K,N] -> bf16 [NP,K] ----------------
__global__ __launch_bounds__(256) void k_transpose(const float* __restrict__ src, unsigned short* __restrict__ dst,
                                                   int K, int N, int NP) {
    __shared__ float t[32][33];
    int n0 = blockIdx.x * 32, k0 = blockIdx.y * 32;
    int tx = threadIdx.x & 31, ty = threadIdx.x >> 5;
#pragma unroll
    for (int i = ty; i < 32; i += 8) {
        int k = k0 + i, n = n0 + tx;
        t[i][tx] = (n < N) ? src[(size_t)k * N + n] : 0.f;
    }
    __syncthreads();
#pragma unroll
    for (int i = ty; i < 32; i += 8) {
        int n = n0 + i, k = k0 + tx;
        if (n < NP) dst[(size_t)n * K + k] = f2bfu(t[tx][i]);
    }
}

// ---------------- fused 6x square transpose (1024x1024 fp32 -> bf16) ----------------
__global__ __launch_bounds__(256) void k_transpose6(const float* __restrict__ s0, const float* __restrict__ s1,
                                                    const float* __restrict__ s2, const float* __restrict__ s3,
                                                    const float* __restrict__ s4, const float* __restrict__ s5,
                                                    unsigned short* __restrict__ wt5, unsigned short* __restrict__ owt) {
    __shared__ float t[32][33];
    int z = blockIdx.z;
    const float* src = (z == 0) ? s0 : (z == 1) ? s1 : (z == 2) ? s2 : (z == 3) ? s3 : (z == 4) ? s4 : s5;
    unsigned short* dst = (z < 5) ? (wt5 + (size_t)z * 1048576) : owt;
    int n0 = blockIdx.x * 32, k0 = blockIdx.y * 32;
    int tx = threadIdx.x & 31, ty = threadIdx.x >> 5;
#pragma unroll
    for (int i = ty; i < 32; i += 8) {
        t[i][tx] = src[(size_t)(k0 + i) * 1024 + n0 + tx];
    }
    __syncthreads();
#pragma unroll
    for (int i = ty; i < 32; i += 8) {
        dst[(size_t)(n0 + i) * 1024 + k0 + tx] = f2bfu(t[tx][i]);
    }
}

// ---------------- bf16 MFMA GEMM ----------------
template <int EPI>
__global__ __launch_bounds__(256) void k_gemm(const unsigned short* __restrict__ A, const unsigned short* __restrict__ Bt,
                                              void* __restrict__ Cout, const float* __restrict__ aux,
                                              int M, int N, int K) {
    __shared__ alignas(16) unsigned short As[128 * 64];
    __shared__ alignas(16) unsigned short Bs[128 * 64];
    const int tid = threadIdx.x;
    const int m0 = blockIdx.y * 128, n0 = blockIdx.x * 128;
    const int wave = tid >> 6, lane = tid & 63;
    const int wm = (wave >> 1) * 64, wn = (wave & 1) * 64;
    const int fr = lane & 15, fg = lane >> 4;
    const int srow = tid >> 3;
    const int ske = (tid & 7) * 8;

    f32x4 acc[4][4];
#pragma unroll
    for (int m = 0; m < 4; m++)
#pragma unroll
        for (int n = 0; n < 4; n++) acc[m][n] = (f32x4)(0.f);

    const int nk = K >> 6;
    u32x4 ra[4], rb[4];
#pragma unroll
    for (int i = 0; i < 4; i++) {
        ra[i] = *(const u32x4*)(A + (size_t)(m0 + srow + 32 * i) * K + ske);
        rb[i] = *(const u32x4*)(Bt + (size_t)(n0 + srow + 32 * i) * K + ske);
    }
    for (int kt = 0; kt < nk; ++kt) {
        __syncthreads();
#pragma unroll
        for (int i = 0; i < 4; i++) {
            int lin = (tid + 256 * i) * 16;
            int sw = lin ^ (((lin >> 7) & 7) << 4);
            *(u32x4*)((char*)As + sw) = ra[i];
            *(u32x4*)((char*)Bs + sw) = rb[i];
        }
        __syncthreads();
        if (kt + 1 < nk) {
#pragma unroll
            for (int i = 0; i < 4; i++) {
                ra[i] = *(const u32x4*)(A + (size_t)(m0 + srow + 32 * i) * K + (kt + 1) * 64 + ske);
                rb[i] = *(const u32x4*)(Bt + (size_t)(n0 + srow + 32 * i) * K + (kt + 1) * 64 + ske);
            }
        }
#pragma unroll
        for (int ks = 0; ks < 2; ++ks) {
            bf16x8 af[4], bg[4];
#pragma unroll
            for (int m = 0; m < 4; m++) {
                int row = wm + m * 16 + fr;
                int lin = row * 128 + ks * 64 + fg * 16;
                af[m] = *(const bf16x8*)((const char*)As + (lin ^ ((row & 7) << 4)));
            }
#pragma unroll
            for (int n = 0; n < 4; n++) {
                int col = wn + n * 16 + fr;
                int lin = col * 128 + ks * 64 + fg * 16;
                bg[n] = *(const bf16x8*)((const char*)Bs + (lin ^ ((col & 7) << 4)));
            }
#pragma unroll
            for (int m = 0; m < 4; m++)
#pragma unroll
                for (int n = 0; n < 4; n++)
                    acc[m][n] = __builtin_amdgcn_mfma_f32_16x16x32_bf16(af[m], bg[n], acc[m][n], 0, 0, 0);
        }
    }
#pragma unroll
    for (int m = 0; m < 4; m++) {
#pragma unroll
        for (int r = 0; r < 4; r++) {
            size_t row = (size_t)(m0 + wm + m * 16 + fg * 4 + r);
#pragma unroll
            for (int n = 0; n < 4; n++) {
                size_t idx = row * N + n0 + wn + n * 16 + fr;
                float v = acc[m][n][r];
                if constexpr (EPI == 0) ((float*)Cout)[idx] = v;
                else if constexpr (EPI == 4) ((unsigned short*)Cout)[idx] = f2bfu(0.5f * v * (1.f + erff(v * 0.70710678118f)));
                else ((float*)Cout)[idx] = v + aux[idx];
            }
        }
    }
}

// ---------------- paired skinny GEMMs: z=0: A0xB0->C0 (K0), z=1: A1xB1->C1 (K1); N=1024 ------
__global__ __launch_bounds__(256) void k_gemm_pair(const unsigned short* __restrict__ A0, const unsigned short* __restrict__ B0,
                                                   float* __restrict__ C0, int K0,
                                                   const unsigned short* __restrict__ A1, const unsigned short* __restrict__ B1,
                                                   float* __restrict__ C1, int K1) {
    __shared__ alignas(16) unsigned short As[128 * 64];
    __shared__ alignas(16) unsigned short Bs[128 * 64];
    const int tid = threadIdx.x;
    const int z = blockIdx.z;
    const unsigned short* __restrict__ A = z ? A1 : A0;
    const unsigned short* __restrict__ Bt = z ? B1 : B0;
    float* __restrict__ C = z ? C1 : C0;
    const int K = z ? K1 : K0;
    const int N = 1024;
    const int m0 = blockIdx.y * 128, n0 = blockIdx.x * 128;
    const int wave = tid >> 6, lane = tid & 63;
    const int wm = (wave >> 1) * 64, wn = (wave & 1) * 64;
    const int fr = lane & 15, fg = lane >> 4;
    const int srow = tid >> 3;
    const int ske = (tid & 7) * 8;

    f32x4 acc[4][4];
#pragma unroll
    for (int m = 0; m < 4; m++)
#pragma unroll
        for (int n = 0; n < 4; n++) acc[m][n] = (f32x4)(0.f);

    const int nk = K >> 6;
    u32x4 ra[4], rb[4];
#pragma unroll
    for (int i = 0; i < 4; i++) {
        ra[i] = *(const u32x4*)(A + (size_t)(m0 + srow + 32 * i) * K + ske);
        rb[i] = *(const u32x4*)(Bt + (size_t)(n0 + srow + 32 * i) * K + ske);
    }
    for (int kt = 0; kt < nk; ++kt) {
        __syncthreads();
#pragma unroll
        for (int i = 0; i < 4; i++) {
            int lin = (tid + 256 * i) * 16;
            int sw = lin ^ (((lin >> 7) & 7) << 4);
            *(u32x4*)((char*)As + sw) = ra[i];
            *(u32x4*)((char*)Bs + sw) = rb[i];
        }
        __syncthreads();
        if (kt + 1 < nk) {
#pragma unroll
            for (int i = 0; i < 4; i++) {
                ra[i] = *(const u32x4*)(A + (size_t)(m0 + srow + 32 * i) * K + (kt + 1) * 64 + ske);
                rb[i] = *(const u32x4*)(Bt + (size_t)(n0 + srow + 32 * i) * K + (kt + 1) * 64 + ske);
            }
        }
#pragma unroll
        for (int ks = 0; ks < 2; ++ks) {
            bf16x8 af[4], bg[4];
#pragma unroll
            for (int m = 0; m < 4; m++) {
                int row = wm + m * 16 + fr;
                int lin = row * 128 + ks * 64 + fg * 16;
                af[m] = *(const bf16x8*)((const char*)As + (lin ^ ((row & 7) << 4)));
            }
#pragma unroll
            for (int n = 0; n < 4; n++) {
                int col = wn + n * 16 + fr;
                int lin = col * 128 + ks * 64 + fg * 16;
                bg[n] = *(const bf16x8*)((const char*)Bs + (lin ^ ((col & 7) << 4)));
            }
#pragma unroll
            for (int m = 0; m < 4; m++)
#pragma unroll
                for (int n = 0; n < 4; n++)
                    acc[m][n] = __builtin_amdgcn_mfma_f32_16x16x32_bf16(af[m], bg[n], acc[m][n], 0, 0, 0);
        }
    }
#pragma unroll
    for (int m = 0; m < 4; m++) {
#pragma unroll
        for (int r = 0; r < 4; r++) {
            size_t row = (size_t)(m0 + wm + m * 16 + fg * 4 + r);
#pragma unroll
            for (int n = 0; n < 4; n++) {
                size_t idx = row * N + n0 + wn + n * 16 + fr;
                C[idx] = acc[m][n][r];
            }
        }
    }
}

// ---------------- fused projection GEMM ----------------
__global__ __launch_bounds__(256) void k_gemm_fused(const unsigned short* __restrict__ A, const unsigned short* __restrict__ Bt,
                                                    unsigned short* __restrict__ RB, unsigned short* __restrict__ KB,
                                                    unsigned short* __restrict__ VB, unsigned short* __restrict__ GB,
                                                    float* __restrict__ WF, unsigned short* __restrict__ C2B) {
    __shared__ alignas(16) unsigned short As[128 * 64];
    __shared__ alignas(16) unsigned short Bs[128 * 64];
    const int tid = threadIdx.x;
    const int m0 = blockIdx.y * 128, n0 = blockIdx.x * 128;
    const int wave = tid >> 6, lane = tid & 63;
    const int wm = (wave >> 1) * 64, wn = (wave & 1) * 64;
    const int fr = lane & 15, fg = lane >> 4;
    const int srow = tid >> 3;
    const int ske = (tid & 7) * 8;
    const int K = 1024;

    f32x4 acc[4][4];
#pragma unroll
    for (int m = 0; m < 4; m++)
#pragma unroll
        for (int n = 0; n < 4; n++) acc[m][n] = (f32x4)(0.f);

    u32x4 ra[4], rb[4];
#pragma unroll
    for (int i = 0; i < 4; i++) {
        ra[i] = *(const u32x4*)(A + (size_t)(m0 + srow + 32 * i) * K + ske);
        rb[i] = *(const u32x4*)(Bt + (size_t)(n0 + srow + 32 * i) * K + ske);
    }
    for (int kt = 0; kt < 16; ++kt) {
        __syncthreads();
#pragma unroll
        for (int i = 0; i < 4; i++) {
            int lin = (tid + 256 * i) * 16;
            int sw = lin ^ (((lin >> 7) & 7) << 4);
            *(u32x4*)((char*)As + sw) = ra[i];
            *(u32x4*)((char*)Bs + sw) = rb[i];
        }
        __syncthreads();
        if (kt + 1 < 16) {
#pragma unroll
            for (int i = 0; i < 4; i++) {
                ra[i] = *(const u32x4*)(A + (size_t)(m0 + srow + 32 * i) * K + (kt + 1) * 64 + ske);
                rb[i] = *(const u32x4*)(Bt + (size_t)(n0 + srow + 32 * i) * K + (kt + 1) * 64 + ske);
            }
        }
#pragma unroll
        for (int ks = 0; ks < 2; ++ks) {
            bf16x8 af[4], bg[4];
#pragma unroll
            for (int m = 0; m < 4; m++) {
                int row = wm + m * 16 + fr;
                int lin = row * 128 + ks * 64 + fg * 16;
                af[m] = *(const bf16x8*)((const char*)As + (lin ^ ((row & 7) << 4)));
            }
#pragma unroll
            for (int n = 0; n < 4; n++) {
                int col = wn + n * 16 + fr;
                int lin = col * 128 + ks * 64 + fg * 16;
                bg[n] = *(const bf16x8*)((const char*)Bs + (lin ^ ((col & 7) << 4)));
            }
#pragma unroll
            for (int m = 0; m < 4; m++)
#pragma unroll
                for (int n = 0; n < 4; n++)
                    acc[m][n] = __builtin_amdgcn_mfma_f32_16x16x32_bf16(af[m], bg[n], acc[m][n], 0, 0, 0);
        }
    }
    const int seg = n0 >> 10;
#pragma unroll
    for (int m = 0; m < 4; m++) {
#pragma unroll
        for (int r = 0; r < 4; r++) {
            size_t row = (size_t)(m0 + wm + m * 16 + fg * 4 + r);
#pragma unroll
            for (int n = 0; n < 4; n++) {
                int gcol = n0 + wn + n * 16 + fr;
                float v = acc[m][n][r];
                if (n0 < 5120) {
                    size_t idx = row * 1024 + (gcol & 1023);
                    if (seg == 0) RB[idx] = f2bfu(v);
                    else if (seg == 1) KB[idx] = f2bfu(v);
                    else if (seg == 2) VB[idx] = f2bfu(v);
                    else if (seg == 3) GB[idx] = f2bfu(siluf(v));
                    else WF[idx] = expf(-expf(v));
                } else {
                    C2B[row * 4480 + (gcol - 5120)] = f2bfu(v);
                }
            }
        }
    }
}

// ---------------- RWKV chunk prep ----------------
__global__ __launch_bounds__(256) void k_rwkv_prep(unsigned short* __restrict__ RB, unsigned short* __restrict__ KB,
                                                   const float* __restrict__ WF, const float* __restrict__ u,
                                                   unsigned short* __restrict__ KDt, unsigned short* __restrict__ QLb,
                                                   float* __restrict__ DDb) {
    __shared__ float red[16][257];
    __shared__ float red2[16][17];
    const int c = blockIdx.x, bh = blockIdx.y;
    const int b = bh >> 2, h = bh & 3;
    const int k = threadIdx.x;
    const size_t m0 = (size_t)b * T_ + c * 16;
    const int hk = h * 256 + k;
    const float uv = u[hk];
    float Q = 1.f;
    float kd[16];
#pragma unroll
    for (int s = 0; s < 16; s++) {
        size_t off = (m0 + s) * H_ + hk;
        float r = bfu2f(RB[off]);
        float kv = bfu2f(KB[off]);
        float w = WF[off];
        RB[off] = f2bfu(r * Q);
        Q = fmaxf(Q * w, 1e-35f);
        float kdv = kv / Q;
        kd[s] = kdv;
        KB[off] = f2bfu(kdv);
        red[s][k] = r * uv * kv;
    }
    QLb[((size_t)(b * 128 + c)) * 1024 + hk] = f2bfu(Q);
    size_t kt0 = (((size_t)(b * 128 + c)) * 1024 + hk) * 16;
#pragma unroll
    for (int s = 0; s < 16; s++) KDt[kt0 + s] = f2bfu(kd[s]);
    __syncthreads();
    {
        int s = threadIdx.x >> 4, part = threadIdx.x & 15;
        float ps = 0.f;
#pragma unroll
        for (int j = 0; j < 16; j++) ps += red[s][part * 16 + j];
        red2[s][part] = ps;
    }
    __syncthreads();
    if (threadIdx.x < 32) {
        int s = threadIdx.x & 15, half = threadIdx.x >> 4;
        float d = 0.f;
#pragma unroll
        for (int j = 0; j < 8; j++) d += red2[s][half * 8 + j];
        DDb[(((size_t)bh * 128 + c) * 2 + half) * 16 + s] = d;
    }
}

// ---------------- RWKV carry ----------------
__global__ __launch_bounds__(256) void k_rwkv_carry(const unsigned short* __restrict__ KD, const unsigned short* __restrict__ VB,
                                                    const unsigned short* __restrict__ QLb, unsigned short* __restrict__ Scc) {
    __shared__ unsigned short kds[16][256];
    __shared__ float lv[16][4];
    const int vg = blockIdx.x, bh = blockIdx.y;
    const int b = bh >> 2, h = bh & 3;
    const int k = threadIdx.x;
    const int hk = h * 256 + k;
    const size_t baseM = (size_t)b * T_;
    float s0 = 0.f, s1 = 0.f, s2 = 0.f, s3 = 0.f;
    for (int c = 0; c < 128; ++c) {
        size_t m0 = baseM + c * 16;
        if ((c & 7) == 0 && c > 0) {
            int cc = c >> 3;
            size_t sb = ((size_t)(bh * 16 + cc) * 256 + vg * 4) * 256 + k;
            Scc[sb] = f2bfu(s0); Scc[sb + 256] = f2bfu(s1);
            Scc[sb + 512] = f2bfu(s2); Scc[sb + 768] = f2bfu(s3);
        }
        __syncthreads();
#pragma unroll
        for (int it = 0; it < 2; ++it) {
            int i = threadIdx.x + it * 256;
            int row = i >> 5, col8 = (i & 31) * 8;
            *(u32x4*)&kds[row][col8] = *(const u32x4*)(KD + (m0 + row) * H_ + h * 256 + col8);
        }
        if (threadIdx.x < 64) {
            int t = threadIdx.x >> 2, j = threadIdx.x & 3;
            lv[t][j] = bfu2f(VB[(m0 + t) * H_ + h * 256 + vg * 4 + j]);
        }
        __syncthreads();
        float a0 = 0.f, a1 = 0.f, a2 = 0.f, a3 = 0.f;
#pragma unroll
        for (int t = 0; t < 16; t++) {
            float kdv = bfu2f(kds[t][k]);
            a0 = fmaf(kdv, lv[t][0], a0);
            a1 = fmaf(kdv, lv[t][1], a1);
            a2 = fmaf(kdv, lv[t][2], a2);
            a3 = fmaf(kdv, lv[t][3], a3);
        }
        float ql = bfu2f(QLb[((size_t)(b * 128 + c)) * 1024 + hk]);
        s0 = (s0 + a0) * ql; s1 = (s1 + a1) * ql;
        s2 = (s2 + a2) * ql; s3 = (s3 + a3) * ql;
    }
}

// ---------------- RWKV chunked output (MFMA) ----------------
__global__ __launch_bounds__(256) void k_rwkv_out(const unsigned short* __restrict__ RT, const unsigned short* __restrict__ KD,
                                                  const unsigned short* __restrict__ KDt, const unsigned short* __restrict__ VB,
                                                  const unsigned short* __restrict__ QLb, const float* __restrict__ DDb,
                                                  const unsigned short* __restrict__ Scc,
                                                  float* __restrict__ P0, float* __restrict__ P1) {
    __shared__ unsigned short Sb[64][136];
    __shared__ unsigned short VT[64][24];
    __shared__ unsigned short Ab[16][24];
    __shared__ float dls[16];
    const int tid = threadIdx.x;
    const int vt = blockIdx.x, cc = blockIdx.y;
    const int bh = blockIdx.z >> 1, kh = blockIdx.z & 1;
    const int b = bh >> 2, h = bh & 3;
    const int wave = tid >> 6, lane = tid & 63;
    const int l16 = lane & 15, lq = lane >> 4;
    const int wv0 = wave * 16;
    const int hk0 = h * 256 + kh * 128;
    const int hv = h * 256 + vt * 64;
    const int aoff = (lq < 2) ? lq * 8 : 0;
    float* __restrict__ OP = kh ? P1 : P0;
    f32x4 sreg[8];
    if (cc == 0) {
#pragma unroll
        for (int kt = 0; kt < 8; kt++) sreg[kt] = (f32x4)(0.f);
        for (int i = tid; i < 64 * 136 / 8; i += 256) ((u32x4*)Sb)[i] = (u32x4)(0u);
    } else {
        size_t sbase = ((size_t)(bh * 16 + cc) * 256 + vt * 64);
        for (int i = tid; i < 1024; i += 256) {
            int v = i >> 4, k8 = (i & 15) * 8;
            *(u32x4*)&Sb[v][k8] = *(const u32x4*)(Scc + (sbase + v) * 256 + kh * 128 + k8);
        }
#pragma unroll
        for (int kt = 0; kt < 8; kt++) {
            ushort4 w4 = *(const ushort4*)(Scc + (sbase + wv0 + l16) * 256 + kh * 128 + kt * 16 + lq * 4);
            sreg[kt][0] = bfu2f(w4.x); sreg[kt][1] = bfu2f(w4.y);
            sreg[kt][2] = bfu2f(w4.z); sreg[kt][3] = bfu2f(w4.w);
        }
    }
    __syncthreads();

    for (int fc = 0; fc < 8; ++fc) {
        const int c = cc * 8 + fc;
        const size_t m0 = (size_t)b * T_ + c * 16;
        const size_t bc = (size_t)(b * 128 + c);
        if (fc > 0) __syncthreads();
        {
            int st = tid >> 4, v4 = (tid & 15) * 4;
            ushort4 v4v = *(const ushort4*)(VB + (m0 + st) * H_ + hv + v4);
            VT[v4 + 0][st] = v4v.x; VT[v4 + 1][st] = v4v.y;
            VT[v4 + 2][st] = v4v.z; VT[v4 + 3][st] = v4v.w;
            if (tid < 16) dls[tid] = DDb[(((size_t)bh * 128 + c) * 2 + kh) * 16 + tid];
        }
        __syncthreads();
        const size_t rowA = (m0 + l16) * H_ + hk0;
        bf16x8 rtf[4];
#pragma unroll
        for (int ks = 0; ks < 4; ks++) rtf[ks] = *(const bf16x8*)(RT + rowA + ks * 32 + lq * 8);
        f32x4 Aacc = (f32x4)(0.f);
#pragma unroll
        for (int ks = 0; ks < 4; ks++) {
            bf16x8 kdf = *(const bf16x8*)(KD + rowA + ks * 32 + lq * 8);
            Aacc = __builtin_amdgcn_mfma_f32_16x16x32_bf16(rtf[ks], kdf, Aacc, 0, 0, 0);
        }
        f32x4 oacc = (f32x4)(0.f);
#pragma unroll
        for (int ks = 0; ks < 4; ks++) {
            bf16x8 sbf = *(const bf16x8*)(&Sb[wv0 + l16][ks * 32 + lq * 8]);
            oacc = __builtin_amdgcn_mfma_f32_16x16x32_bf16(rtf[ks], sbf, oacc, 0, 0, 0);
        }
#pragma unroll
        for (int r = 0; r < 4; r++) {
            int t = lq * 4 + r, s = l16;
            float av = (s < t) ? Aacc[r] : ((s == t) ? dls[t] : 0.f);
            Ab[t][s] = f2bfu(av);
        }
        bf16x8 abf_t = *(const bf16x8*)(&Ab[l16][aoff]);
        bf16x8 vtf_t = *(const bf16x8*)(&VT[wv0 + l16][aoff]);
        bf16x8 abf = (lq < 2) ? abf_t : zero8();
        bf16x8 vtf = (lq < 2) ? vtf_t : zero8();
        oacc = __builtin_amdgcn_mfma_f32_16x16x32_bf16(abf, vtf, oacc, 0, 0, 0);
#pragma unroll
        for (int r = 0; r < 4; r++)
            OP[(m0 + lq * 4 + r) * H_ + hv + wv0 + l16] = oacc[r];
#pragma unroll
        for (int kt = 0; kt < 8; kt++) {
            const unsigned short* kp = KDt + (((bc * 1024) + hk0 + kt * 16 + l16) << 4) + aoff;
            bf16x8 kdtf_t = *(const bf16x8*)kp;
            bf16x8 kdtf = (lq < 2) ? kdtf_t : zero8();
            sreg[kt] = __builtin_amdgcn_mfma_f32_16x16x32_bf16(kdtf, vtf, sreg[kt], 0, 0, 0);
            ushort4 q4 = *(const ushort4*)(QLb + bc * 1024 + hk0 + kt * 16 + lq * 4);
            sreg[kt][0] *= bfu2f(q4.x); sreg[kt][1] *= bfu2f(q4.y);
            sreg[kt][2] *= bfu2f(q4.z); sreg[kt][3] *= bfu2f(q4.w);
            ushort4 pk;
            pk.x = f2bfu(sreg[kt][0]); pk.y = f2bfu(sreg[kt][1]);
            pk.z = f2bfu(sreg[kt][2]); pk.w = f2bfu(sreg[kt][3]);
            *(ushort4*)(&Sb[wv0 + l16][kt * 16 + lq * 4]) = pk;
        }
    }
}

// ---------------- RWKV post ----------------
__global__ __launch_bounds__(256) void k_rwkv_post(const float* __restrict__ P0, const float* __restrict__ P1,
                                                   const float* __restrict__ gn_w, unsigned short* __restrict__ g_io) {
    int m = blockIdx.x, tid = threadIdx.x;
    int wave = tid >> 6, lane = tid & 63;
    size_t base = (size_t)m * H_ + wave * 256 + lane * 4;
    int col = wave * 256 + lane * 4;
    float4 a = *(const float4*)(P0 + base);
    float4 b4 = *(const float4*)(P1 + base);
    float4 v; v.x = a.x + b4.x; v.y = a.y + b4.y; v.z = a.z + b4.z; v.w = a.w + b4.w;
    float ss = v.x * v.x + v.y * v.y + v.z * v.z + v.w * v.w;
#pragma unroll
    for (int off = 32; off; off >>= 1) ss += __shfl_xor(ss, off);
    float scale = rsqrtf(ss * (1.f / 256.f) + EPS_);
    float4 gn = *(const float4*)(gn_w + col);
    ushort4 gb4 = *(const ushort4*)(g_io + base);
    ushort4 out;
    out.x = f2bfu(v.x * scale * gn.x * bfu2f(gb4.x));
    out.y = f2bfu(v.y * scale * gn.y * bfu2f(gb4.y));
    out.z = f2bfu(v.z * scale * gn.z * bfu2f(gb4.z));
    out.w = f2bfu(v.w * scale * gn.w * bfu2f(gb4.w));
    *(ushort4*)(g_io + base) = out;
}

// ---------------- conv ----------------
__global__ __launch_bounds__(256) void k_conv(const unsigned short* __restrict__ C2B, const float* __restrict__ conv_w,
                                              const float* __restrict__ conv_b, unsigned short* __restrict__ XB,
                                              float* __restrict__ BCF) {
    int m = blockIdx.y;
    int c = blockIdx.x * 256 + threadIdx.x;
    int b = m >> 11, t = m & 2047;
    float acc = conv_b[c];
#pragma unroll
    for (int i = 0; i < 4; i++) {
        int tt = t - 3 + i;
        if (tt >= 0) acc = fmaf(bfu2f(C2B[((size_t)(b * T_ + tt)) * LD2 + DI + c]), conv_w[c * 4 + i], acc);
    }
    float r = siluf(acc);
    if (c < DI) XB[(size_t)m * DI + c] = f2bfu(r);
    else BCF[(size_t)m * 256 + (c - DI)] = r;
}

// ---------------- Mamba chunk prep: dt, global cumsum, decay tables ----------------
__global__ __launch_bounds__(256) void k_mprep(const unsigned short* __restrict__ C2B,
                                               const float* __restrict__ dt_bias, const float* __restrict__ A_log,
                                               float* __restrict__ DT, float* __restrict__ CD,
                                               float* __restrict__ WS, float* __restrict__ WSC,
                                               float* __restrict__ QJ, float* __restrict__ QLf,
                                               float* __restrict__ QC) {
    __shared__ float sums[128], offs[128], ce[16];
    const int bh = blockIdx.x;
    const int b = bh >> 5, h = bh & 31;
    const int c = threadIdx.x;
    const float A = -expf(A_log[h]);
    const float dtb = dt_bias[h];
    float dloc[16], cdl[16];
    if (c < 128) {
        float acc = 0.f;
#pragma unroll
        for (int s = 0; s < 16; s++) {
            size_t m = (size_t)b * T_ + c * 16 + s;
            float draw = bfu2f(C2B[m * LD2 + 4352 + h]) + dtb;
            float dt = draw > 20.f ? draw : log1pf(expf(draw));
            acc += dt;
            dloc[s] = dt; cdl[s] = acc;
        }
        sums[c] = acc;
    }
    __syncthreads();
    if (threadIdx.x == 0) {
        float run = 0.f;
        for (int i = 0; i < 128; i++) { offs[i] = run; run += sums[i]; }
    }
    __syncthreads();
    if (threadIdx.x < 16) {
        int last = threadIdx.x * 8 + 7;
        ce[threadIdx.x] = offs[last] + sums[last];
    }
    __syncthreads();
    if (c < 128) {
        float off = offs[c];
        float cd15 = off + cdl[15];
        float ceC = ce[c >> 3];
        QLf[bh * 128 + c] = expf(fminf(A * cdl[15], 0.f));
        size_t base = (size_t)bh * 2048 + c * 16;
#pragma unroll
        for (int s = 0; s < 16; s++) {
            float cdg = off + cdl[s];
            DT[base + s] = dloc[s];
            CD[base + s] = cdg;
            QJ[base + s] = expf(fminf(A * (cdg - off), 0.f));
            WS[base + s] = expf(fminf(A * (cd15 - cdg), 0.f)) * dloc[s];
            WSC[base + s] = expf(fminf(A * (ceC - cdg), 0.f)) * dloc[s];
        }
    }
    if (threadIdx.x < 16) {
        float prev = threadIdx.x ? ce[threadIdx.x - 1] : 0.f;
        QC[bh * 16 + threadIdx.x] = expf(fminf(A * (ce[threadIdx.x] - prev), 0.f));
    }
}

// ---------------- Mamba A-mask precompute ----------------
__global__ __launch_bounds__(64) void k_amask(const float* __restrict__ BCF,
                                              const float* __restrict__ CD, const float* __restrict__ DT,
                                              const float* __restrict__ A_log,
                                              unsigned short* __restrict__ AM) {
    const int c = blockIdx.x, bh = blockIdx.y;
    const int b = bh >> 5, h = bh & 31;
    const int lane = threadIdx.x;
    const int l16 = lane & 15, lq = lane >> 4;
    const float A = -expf(A_log[h]);
    const size_t m = (size_t)b * T_ + c * 16 + l16;
    f32x4 Aacc = (f32x4)(0.f);
#pragma unroll
    for (int ks = 0; ks < 4; ks++) {
        bf16x8 cf, bf;
        const float* cr = BCF + m * 256 + 128 + ks * 32 + lq * 8;
        const float* br = BCF + m * 256 + ks * 32 + lq * 8;
#pragma unroll
        for (int i = 0; i < 8; i++) { cf[i] = (__bf16)cr[i]; bf[i] = (__bf16)br[i]; }
        Aacc = __builtin_amdgcn_mfma_f32_16x16x32_bf16(cf, bf, Aacc, 0, 0, 0);
    }
    size_t base = ((size_t)bh * 128 + c) * 256;
    size_t tb = (size_t)bh * 2048 + c * 16;
    float cds = CD[tb + l16];
    float dts = DT[tb + l16];
#pragma unroll
    for (int r = 0; r < 4; r++) {
        int j = lq * 4 + r;
        float av = 0.f;
        if (l16 <= j) {
            float cdj = CD[tb + j];
            av = Aacc[r] * expf(fminf(A * (cdj - cds), 0.f)) * dts;
        }
        AM[base + j * 16 + l16] = f2bfu(av);
    }
}

// ---------------- Mamba carry: coarse-chunk (128 t) state via MFMA ----------------
__global__ __launch_bounds__(256) void k_mcarry(const float* __restrict__ BCF, const unsigned short* __restrict__ XB,
                                                const float* __restrict__ WSC, const float* __restrict__ QC,
                                                unsigned short* __restrict__ MSCC) {
    __shared__ float Bsf[64][128];
    __shared__ unsigned short BWt[128][72];
    __shared__ unsigned short XT[16][72];
    __shared__ float wsl[64];
    const int tid = threadIdx.x;
    const int dq = blockIdx.x, bh = blockIdx.y;
    const int b = bh >> 5, h = bh & 31;
    const int wave = tid >> 6, lane = tid & 63;
    const int l16 = lane & 15, lq = lane >> 4;
    const size_t baseM = (size_t)b * T_;
    f32x4 sreg[2];
    sreg[0] = (f32x4)(0.f); sreg[1] = (f32x4)(0.f);

    for (int cc = 0; cc < 15; ++cc) {
        float qC = QC[bh * 16 + cc];
        sreg[0] *= qC; sreg[1] *= qC;
        for (int sub = 0; sub < 2; ++sub) {
            int t0g = cc * 128 + sub * 64;
            __syncthreads();
            if (tid < 64) wsl[tid] = WSC[(size_t)bh * 2048 + t0g + tid];
#pragma unroll
            for (int i = 0; i < 8; i++) {
                int idx4 = tid + i * 256;
                int t = idx4 >> 5, s4 = (idx4 & 31) * 4;
                *(float4*)&Bsf[t][s4] = *(const float4*)(BCF + (baseM + t0g + t) * 256 + s4);
            }
#pragma unroll
            for (int i = 0; i < 4; i++) {
                int idx = tid + i * 256;
                int t = idx >> 4, d = idx & 15;
                XT[d][t] = XB[(baseM + t0g + t) * DI + h * 64 + dq * 16 + d];
            }
            __syncthreads();
            {
                int sg = tid >> 1;
                int tb = (tid & 1) * 32;
#pragma unroll
                for (int q = 0; q < 8; q++) {
                    int tt = tb + q * 4;
                    ushort4 v;
                    v.x = f2bfu(Bsf[tt + 0][sg] * wsl[tt + 0]);
                    v.y = f2bfu(Bsf[tt + 1][sg] * wsl[tt + 1]);
                    v.z = f2bfu(Bsf[tt + 2][sg] * wsl[tt + 2]);
                    v.w = f2bfu(Bsf[tt + 3][sg] * wsl[tt + 3]);
                    *(ushort4*)&BWt[sg][tt] = v;
                }
            }
            __syncthreads();
#pragma unroll
            for (int st = 0; st < 2; st++) {
#pragma unroll
                for (int ks = 0; ks < 2; ks++) {
                    bf16x8 bwf = *(const bf16x8*)&BWt[wave * 32 + st * 16 + l16][ks * 32 + lq * 8];
                    bf16x8 xtf = *(const bf16x8*)&XT[l16][ks * 32 + lq * 8];
                    sreg[st] = __builtin_amdgcn_mfma_f32_16x16x32_bf16(bwf, xtf, sreg[st], 0, 0, 0);
                }
            }
        }
        size_t dbase = ((size_t)(bh * 16 + cc + 1) * 64 + dq * 16 + l16) * 128;
#pragma unroll
        for (int st = 0; st < 2; st++) {
            ushort4 pk;
            pk.x = f2bfu(sreg[st][0]); pk.y = f2bfu(sreg[st][1]);
            pk.z = f2bfu(sreg[st][2]); pk.w = f2bfu(sreg[st][3]);
            *(ushort4*)(MSCC + dbase + wave * 32 + st * 16 + lq * 4) = pk;
        }
    }
}

// ---------------- Mamba chunked output (MFMA) ----------------
__global__ __launch_bounds__(256) void k_mout(const float* __restrict__ BCF, const unsigned short* __restrict__ XB,
                                              const unsigned short* __restrict__ AM,
                                              const float* __restrict__ QJ, const float* __restrict__ WS,
                                              const float* __restrict__ QLf, const unsigned short* __restrict__ MSCC,
                                              unsigned short* __restrict__ Y) {
    __shared__ unsigned short Sb[64][136];
    __shared__ unsigned short Cs[16][136];
    __shared__ unsigned short BWt[128][24];
    __shared__ unsigned short XT[64][24];
    __shared__ unsigned short Ab[16][24];
    __shared__ float qjl[16], wsl[16], qLl;
    const int tid = threadIdx.x;
    const int cc = blockIdx.x, bh = blockIdx.y;
    const int b = bh >> 5, h = bh & 31;
    const int wave = tid >> 6, lane = tid & 63;
    const int l16 = lane & 15, lq = lane >> 4;
    const int wv0 = wave * 16;
    const int aoff = (lq < 2) ? lq * 8 : 0;
    const size_t baseM = (size_t)b * T_;
    f32x4 sreg[8];
    if (cc == 0) {
#pragma unroll
        for (int kt = 0; kt < 8; kt++) sreg[kt] = (f32x4)(0.f);
        for (int i = tid; i < 64 * 136 / 8; i += 256) ((u32x4*)Sb)[i] = (u32x4)(0u);
    } else {
        size_t sbase = (size_t)(bh * 16 + cc) * 64;
        for (int i = tid; i < 1024; i += 256) {
            int d = i >> 4, s8 = (i & 15) * 8;
            *(u32x4*)&Sb[d][s8] = *(const u32x4*)(MSCC + (sbase + d) * 128 + s8);
        }
#pragma unroll
        for (int kt = 0; kt < 8; kt++) {
            ushort4 w4 = *(const ushort4*)(MSCC + (sbase + wv0 + l16) * 128 + kt * 16 + lq * 4);
            sreg[kt][0] = bfu2f(w4.x); sreg[kt][1] = bfu2f(w4.y);
            sreg[kt][2] = bfu2f(w4.z); sreg[kt][3] = bfu2f(w4.w);
        }
    }

    for (int fc = 0; fc < 8; ++fc) {
        const int c = cc * 8 + fc;
        const size_t m0 = baseM + c * 16;
        __syncthreads();
        if (tid < 16) {
            size_t tb = (size_t)bh * 2048 + c * 16 + tid;
            qjl[tid] = QJ[tb];
            wsl[tid] = WS[tb];
            if (tid == 0) qLl = QLf[bh * 128 + c];
        }
        {
            int j = tid >> 4, s = tid & 15;
            Ab[j][s] = AM[((size_t)bh * 128 + c) * 256 + tid];
        }
#pragma unroll
        for (int i = 0; i < 8; i++) {
            int idx = tid + i * 256;
            int t = idx >> 7, sig = idx & 127;
            Cs[t][sig] = f2bfu(BCF[(m0 + t) * 256 + 128 + sig]);
        }
#pragma unroll
        for (int i = 0; i < 4; i++) {
            int idx = tid + i * 256;
            int t = idx >> 6, d = idx & 63;
            XT[d][t] = XB[(m0 + t) * DI + h * 64 + d];
        }
        __syncthreads();
#pragma unroll
        for (int i = 0; i < 8; i++) {
            int idx = tid + i * 256;
            int t = idx >> 7, sig = idx & 127;
            BWt[sig][t] = f2bfu(BCF[(m0 + t) * 256 + sig] * wsl[t]);
        }
        __syncthreads();
        bf16x8 cf[4];
#pragma unroll
        for (int ks = 0; ks < 4; ks++) cf[ks] = *(const bf16x8*)(&Cs[l16][ks * 32 + lq * 8]);
        f32x4 oacc = (f32x4)(0.f);
#pragma unroll
        for (int ks = 0; ks < 4; ks++) {
            bf16x8 sbf = *(const bf16x8*)(&Sb[wv0 + l16][ks * 32 + lq * 8]);
            oacc = __builtin_amdgcn_mfma_f32_16x16x32_bf16(cf[ks], sbf, oacc, 0, 0, 0);
        }
#pragma unroll
        for (int r = 0; r < 4; r++) oacc[r] *= qjl[lq * 4 + r];
        bf16x8 abf_t = *(const bf16x8*)(&Ab[l16][aoff]);
        bf16x8 xtf_t = *(const bf16x8*)(&XT[wv0 + l16][aoff]);
        bf16x8 abf = (lq < 2) ? abf_t : zero8();
        bf16x8 xtf = (lq < 2) ? xtf_t : zero8();
        oacc = __builtin_amdgcn_mfma_f32_16x16x32_bf16(abf, xtf, oacc, 0, 0, 0);
#pragma unroll
        for (int r = 0; r < 4; r++)
            Y[(m0 + lq * 4 + r) * DI + h * 64 + wv0 + l16] = f2bfu(oacc[r]);
        float qL = qLl;
#pragma unroll
        for (int kt = 0; kt < 8; kt++) {
            sreg[kt] *= qL;
            bf16x8 bwf_t = *(const bf16x8*)(&BWt[kt * 16 + l16][aoff]);
            bf16x8 bwf = (lq < 2) ? bwf_t : zero8();
            sreg[kt] = __builtin_amdgcn_mfma_f32_16x16x32_bf16(bwf, xtf, sreg[kt], 0, 0, 0);
            ushort4 pk;
            pk.x = f2bfu(sreg[kt][0]); pk.y = f2bfu(sreg[kt][1]);
            pk.z = f2bfu(sreg[kt][2]); pk.w = f2bfu(sreg[kt][3]);
            *(ushort4*)(&Sb[wv0 + l16][kt * 16 + lq * 4]) = pk;
        }
    }
}

// ---------------- Mamba post ----------------
__global__ __launch_bounds__(256) void k_mamba_post(unsigned short* __restrict__ y_io,
                                                    const unsigned short* __restrict__ XB,
                                                    const unsigned short* __restrict__ C2B, const float* __restrict__ D_m,
                                                    const float* __restrict__ mnw) {
    __shared__ float red[4];
    int m = blockIdx.x, tid = threadIdx.x;
    int j0 = tid * 8;
    const float Dv = D_m[j0 >> 6];
    ushort4 ya = *(const ushort4*)(y_io + (size_t)m * DI + j0);
    ushort4 yb = *(const ushort4*)(y_io + (size_t)m * DI + j0 + 4);
    ushort4 xa = *(const ushort4*)(XB + (size_t)m * DI + j0);
    ushort4 xb = *(const ushort4*)(XB + (size_t)m * DI + j0 + 4);
    ushort4 za = *(const ushort4*)(C2B + (size_t)m * LD2 + j0);
    ushort4 zb = *(const ushort4*)(C2B + (size_t)m * LD2 + j0 + 4);
    float yv[8] = {bfu2f(ya.x), bfu2f(ya.y), bfu2f(ya.z), bfu2f(ya.w),
                   bfu2f(yb.x), bfu2f(yb.y), bfu2f(yb.z), bfu2f(yb.w)};
    float xv[8] = {bfu2f(xa.x), bfu2f(xa.y), bfu2f(xa.z), bfu2f(xa.w), bfu2f(xb.x), bfu2f(xb.y), bfu2f(xb.z), bfu2f(xb.w)};
    float zv[8] = {bfu2f(za.x), bfu2f(za.y), bfu2f(za.z), bfu2f(za.w), bfu2f(zb.x), bfu2f(zb.y), bfu2f(zb.z), bfu2f(zb.w)};
    float val[8];
    float ss = 0.f;
#pragma unroll
    for (int i = 0; i < 8; i++) {
        float v = (yv[i] + Dv * xv[i]) * siluf(zv[i]);
        val[i] = v;
        ss += v * v;
    }
#pragma unroll
    for (int off = 32; off; off >>= 1) ss += __shfl_xor(ss, off);
    if ((tid & 63) == 0) red[tid >> 6] = ss;
    __syncthreads();
    float scale = rsqrtf((red[0] + red[1] + red[2] + red[3]) * (1.f / 2048.f) + EPS_);
    ushort4 oa, ob;
    oa.x = f2bfu(val[0] * scale * mnw[j0 + 0]); oa.y = f2bfu(val[1] * scale * mnw[j0 + 1]);
    oa.z = f2bfu(val[2] * scale * mnw[j0 + 2]); oa.w = f2bfu(val[3] * scale * mnw[j0 + 3]);
    ob.x = f2bfu(val[4] * scale * mnw[j0 + 4]); ob.y = f2bfu(val[5] * scale * mnw[j0 + 5]);
    ob.z = f2bfu(val[6] * scale * mnw[j0 + 6]); ob.w = f2bfu(val[7] * scale * mnw[j0 + 7]);
    *(ushort4*)(y_io + (size_t)m * DI + j0) = oa;
    *(ushort4*)(y_io + (size_t)m * DI + j0 + 4) = ob;
}

// ---------------- gate + mix + residual + RMS(ffn_ln) ----------------
__global__ __launch_bounds__(256) void k_mix(const float* __restrict__ x, const float* __restrict__ o_r,
                                             const float* __restrict__ o_m, const float* __restrict__ gw,
                                             const float* __restrict__ gb, const float* __restrict__ flnw,
                                             float* __restrict__ x1, unsigned short* __restrict__ nx2) {
    __shared__ float red[4];
    int m = blockIdx.x, tid = threadIdx.x;
    size_t base = (size_t)m * H_ + tid * 4;
    float4 orv = *(const float4*)(o_r + base);
    float4 omv = *(const float4*)(o_m + base);
    float4 xv = *(const float4*)(x + base);
    float4 g1 = *(const float4*)(gw + tid * 4);
    float4 g2 = *(const float4*)(gw + 1024 + tid * 4);
    float ps = orv.x * g1.x + orv.y * g1.y + orv.z * g1.z + orv.w * g1.w
             + omv.x * g2.x + omv.y * g2.y + omv.z * g2.z + omv.w * g2.w;
#pragma unroll
    for (int off = 32; off; off >>= 1) ps += __shfl_xor(ps, off);
    if ((tid & 63) == 0) red[tid >> 6] = ps;
    __syncthreads();
    float g = 1.f / (1.f + expf(-(red[0] + red[1] + red[2] + red[3] + gb[0])));
    float4 xo;
    xo.x = xv.x + g * orv.x + (1.f - g) * omv.x;
    xo.y = xv.y + g * orv.y + (1.f - g) * omv.y;
    xo.z = xv.z + g * orv.z + (1.f - g) * omv.z;
    xo.w = xv.w + g * orv.w + (1.f - g) * omv.w;
    *(float4*)(x1 + base) = xo;
    float ss = xo.x * xo.x + xo.y * xo.y + xo.z * xo.z + xo.w * xo.w;
#pragma unroll
    for (int off = 32; off; off >>= 1) ss += __shfl_xor(ss, off);
    __syncthreads();
    if ((tid & 63) == 0) red[tid >> 6] = ss;
    __syncthreads();
    float scale = rsqrtf((red[0] + red[1] + red[2] + red[3]) * (1.f / 1024.f) + EPS_);
    float4 wv = *(const float4*)(flnw + tid * 4);
    ushort4 o;
    o.x = f2bfu(xo.x * scale * wv.x); o.y = f2bfu(xo.y * scale * wv.y);
    o.z = f2bfu(xo.z * scale * wv.z); o.w = f2bfu(xo.w * scale * wv.w);
    *(ushort4*)(nx2 + base) = o;
}

extern "C" void kernel_launch(void* const* d_in, const int* in_sizes, int n_in,
                              void* d_out, int out_size, void* d_ws, size_t ws_size,
                              hipStream_t stream) {
    const float* x = (const float*)d_in[0];
    const float* ln_w = (const float*)d_in[1];
    const float* r_w = (const float*)d_in[2];
    const float* k_w = (const float*)d_in[3];
    const float* v_w = (const float*)d_in[4];
    const float* g_w = (const float*)d_in[5];
    const float* dw_w = (const float*)d_in[6];
    const float* u = (const float*)d_in[7];
    const float* gn_w = (const float*)d_in[8];
    const float* o_w = (const float*)d_in[9];
    const float* in_proj = (const float*)d_in[10];
    const float* conv_w = (const float*)d_in[11];
    const float* conv_b = (const float*)d_in[12];
    const float* dt_bias = (const float*)d_in[13];
    const float* A_log = (const float*)d_in[14];
    const float* D_m = (const float*)d_in[15];
    const float* m_norm_w = (const float*)d_in[16];
    const float* out_proj = (const float*)d_in[17];
    const float* gate_w = (const float*)d_in[18];
    const float* gate_b = (const float*)d_in[19];
    const float* ffn_ln_w = (const float*)d_in[20];
    const float* ffn_w1 = (const float*)d_in[21];
    const float* ffn_w2 = (const float*)d_in[22];
    (void)in_sizes; (void)n_in;

    const size_t NEEDED = 192675840ull;
    if (ws_size < NEEDED) {
        hipMemsetAsync(d_out, 0, (size_t)out_size * 4, stream);
        return;
    }
    char* ws = (char*)d_ws;
    unsigned short* WT5 = (unsigned short*)(ws + 0);
    unsigned short* INPT = (unsigned short*)(ws + 10485760);
    unsigned short* QLb = (unsigned short*)(ws + 0);
    float* DDb = (float*)(ws + 524288);
    unsigned short* SCC = (unsigned short*)(ws + 1048576);
    unsigned short* MSCC = (unsigned short*)(ws + 1048576);
    unsigned short* F1T = (unsigned short*)(ws + 0);
    unsigned short* F2T = (unsigned short*)(ws + 10485760);
    unsigned short* OWT = (unsigned short*)(ws + 19660800);
    unsigned short* OPT = (unsigned short*)(ws + 21757952);
    unsigned short* NXB = (unsigned short*)(ws + 25952256);
    unsigned short* KDt = NXB;
    unsigned short* RB = (unsigned short*)(ws + 34340864);
    unsigned short* KB = (unsigned short*)(ws + 42729472);
    unsigned short* VB = (unsigned short*)(ws + 51118080);
    unsigned short* GB = (unsigned short*)(ws + 59506688);
    float* WF = (float*)(ws + 67895296);
    char* MTB = ws + 67895296;
    float* DTt = (float*)(MTB + 0);
    float* CDt = (float*)(MTB + 524288);
    float* WSt = (float*)(MTB + 1048576);
    float* WSCt = (float*)(MTB + 1572864);
    float* QJt = (float*)(MTB + 2097152);
    float* QLft = (float*)(MTB + 2621440);
    float* QCt = (float*)(MTB + 2654208);
    unsigned short* AMt = (unsigned short*)(MTB + 2658304);
    float* OM = (float*)(ws + 34340864);
    unsigned short* MIDB = (unsigned short*)(ws + 51118080);
    unsigned short* C2B = (unsigned short*)(ws + 84672512);
    unsigned short* XB = (unsigned short*)(ws + 121372672);
    float* BCF = (float*)(ws + 138149888);
    float* P0 = (float*)(ws + 142344192);
    float* P1 = (float*)(ws + 159121408);
    unsigned short* YB = (unsigned short*)(ws + 175898624);

    dim3 blk(256);
    k_rms1024<<<M_, blk, 0, stream>>>(x, ln_w, NXB);
    // fused 6x 1024x1024 transposes: r,k,v,g,dw -> WT5 ; o_w -> OWT
    k_transpose6<<<dim3(32, 32, 6), blk, 0, stream>>>(r_w, k_w, v_w, g_w, dw_w, o_w, WT5, OWT);
    k_transpose<<<dim3(140, 32), blk, 0, stream>>>(in_proj, INPT, 1024, 4384, 4480);
    k_transpose<<<dim3(32, 64), blk, 0, stream>>>(out_proj, OPT, 2048, 1024, 1024);
    k_gemm_fused<<<dim3(75, 32), blk, 0, stream>>>(NXB, WT5, RB, KB, VB, GB, WF, C2B);
    k_conv<<<dim3(9, M_), blk, 0, stream>>>(C2B, conv_w, conv_b, XB, BCF);
    // rwkv chain
    k_rwkv_prep<<<dim3(128, 8), blk, 0, stream>>>(RB, KB, WF, u, KDt, QLb, DDb);
    // mamba tables (WF region dead after rwkv_prep)
    k_mprep<<<64, blk, 0, stream>>>(C2B, dt_bias, A_log, DTt, CDt, WSt, WSCt, QJt, QLft, QCt);
    k_amask<<<dim3(128, 64), dim3(64), 0, stream>>>(BCF, CDt, DTt, A_log, AMt);
    k_rwkv_carry<<<dim3(64, 8), blk, 0, stream>>>(KB, VB, QLb, SCC);
    k_rwkv_out<<<dim3(4, 16, 16), blk, 0, stream>>>(RB, KB, KDt, VB, QLb, DDb, SCC, P0, P1);
    k_rwkv_post<<<M_, blk, 0, stream>>>(P0, P1, gn_w, GB);
    // mamba chunked chain (MSCC over dead rwkv SCC)
    k_mcarry<<<dim3(4, 64), blk, 0, stream>>>(BCF, XB, WSCt, QCt, MSCC);
    k_mout<<<dim3(16, 64), blk, 0, stream>>>(BCF, XB, AMt, QJt, WSt, QLft, MSCC, YB);
    k_mamba_post<<<M_, blk, 0, stream>>>(YB, XB, C2B, D_m, m_norm_w);
    k_transpose<<<dim3(128, 32), blk, 0, stream>>>(ffn_w1, F1T, 1024, 4096, 4096);
    k_transpose<<<dim3(32, 128), blk, 0, stream>>>(ffn_w2, F2T, 4096, 1024, 1024);
    // paired skinny GEMMs: z=0 o_w (GBxOWT->P1, K=1024), z=1 out_proj (YBxOPT->OM, K=2048)
    k_gemm_pair<<<dim3(8, 32, 2), blk, 0, stream>>>(GB, OWT, P1, 1024, YB, OPT, OM, 2048);
    k_mix<<<M_, blk, 0, stream>>>(x, P1, OM, gate_w, gate_b, ffn_ln_w, P0, NXB);
    k_gemm<4><<<dim3(32, 32), blk, 0, stream>>>(NXB, F1T, MIDB, nullptr, 4096, 4096, 1024);
    k_gemm<5><<<dim3(8, 32), blk, 0, stream>>>(MIDB, F2T, (float*)d_out, P0, 4096, 1024, 4096);
}

// Round 18
// 861.867 us; speedup vs baseline: 1.1700x; 1.0544x over previous
//
#include <hip/hip_runtime.h>
#include <hip/hip_bf16.h>
#include <stdint.h>

#define B_ 2
#define T_ 2048
#define H_ 1024
#define M_ 4096
#define DI 2048
#define DS 128
#define CONVD 2304
#define LD2 4480
#define EPS_ 1e-6f

typedef __bf16 bf16x8 __attribute__((ext_vector_type(8)));
typedef float f32x4 __attribute__((ext_vector_type(4)));
typedef uint32_t u32x4 __attribute__((ext_vector_type(4)));

__device__ __forceinline__ unsigned short f2bfu(float f) {
    union { float f; uint32_t u; } a; a.f = f;
    uint32_t r = a.u + 0x7FFFu + ((a.u >> 16) & 1u);
    return (unsigned short)(r >> 16);
}
__device__ __forceinline__ float bfu2f(unsigned short u) {
    union { uint32_t u; float f; } a; a.u = ((uint32_t)u) << 16; return a.f;
}
__device__ __forceinline__ float siluf(float x) { return x / (1.f + expf(-x)); }
__device__ __forceinline__ bf16x8 zero8() { bf16x8 r{}; return r; }

// ---------------- RMS over 1024 cols -> bf16 ----------------
__global__ __launch_bounds__(256) void k_rms1024(const float* __restrict__ in, const float* __restrict__ w,
                                                 unsigned short* __restrict__ out) {
    __shared__ float red[4];
    int m = blockIdx.x, tid = threadIdx.x;
    size_t base = (size_t)m * H_ + tid * 4;
    float4 v = *(const float4*)(in + base);
    float ss = v.x * v.x + v.y * v.y + v.z * v.z + v.w * v.w;
#pragma unroll
    for (int off = 32; off; off >>= 1) ss += __shfl_xor(ss, off);
    if ((tid & 63) == 0) red[tid >> 6] = ss;
    __syncthreads();
    float scale = rsqrtf((red[0] + red[1] + red[2] + red[3]) * (1.f / 1024.f) + EPS_);
    float4 wv = *(const float4*)(w + tid * 4);
    ushort4 o;
    o.x = f2bfu(v.x * wv.x * scale); o.y = f2bfu(v.y * wv.y * scale);
    o.z = f2bfu(v.z * wv.z * scale); o.w = f2bfu(v.w * wv.w * scale);
    *(ushort4*)(out + base) = o;
}

// ---------------- transpose fp32 [K,N] -> bf16 [NP,K] ----------------
__global__ __launch_bounds__(256) void k_transpose(const float* __restrict__ src, unsigned short* __restrict__ dst,
                                                   int K, int N, int NP) {
    __shared__ float t[32][33];
    int n0 = blockIdx.x * 32, k0 = blockIdx.y * 32;
    int tx = threadIdx.x & 31, ty = threadIdx.x >> 5;
#pragma unroll
    for (int i = ty; i < 32; i += 8) {
        int k = k0 + i, n = n0 + tx;
        t[i][tx] = (n < N) ? src[(size_t)k * N + n] : 0.f;
    }
    __syncthreads();
#pragma unroll
    for (int i = ty; i < 32; i += 8) {
        int n = n0 + i, k = k0 + tx;
        if (n < NP) dst[(size_t)n * K + k] = f2bfu(t[tx][i]);
    }
}

// ---------------- fused 6x square transpose (1024x1024 fp32 -> bf16) ----------------
__global__ __launch_bounds__(256) void k_transpose6(const float* __restrict__ s0, const float* __restrict__ s1,
                                                    const float* __restrict__ s2, const float* __restrict__ s3,
                                                    const float* __restrict__ s4, const float* __restrict__ s5,
                                                    unsigned short* __restrict__ wt5, unsigned short* __restrict__ owt) {
    __shared__ float t[32][33];
    int z = blockIdx.z;
    const float* src = (z == 0) ? s0 : (z == 1) ? s1 : (z == 2) ? s2 : (z == 3) ? s3 : (z == 4) ? s4 : s5;
    unsigned short* dst = (z < 5) ? (wt5 + (size_t)z * 1048576) : owt;
    int n0 = blockIdx.x * 32, k0 = blockIdx.y * 32;
    int tx = threadIdx.x & 31, ty = threadIdx.x >> 5;
#pragma unroll
    for (int i = ty; i < 32; i += 8) {
        t[i][tx] = src[(size_t)(k0 + i) * 1024 + n0 + tx];
    }
    __syncthreads();
#pragma unroll
    for (int i = ty; i < 32; i += 8) {
        dst[(size_t)(n0 + i) * 1024 + k0 + tx] = f2bfu(t[tx][i]);
    }
}

// ---------------- bf16 MFMA GEMM ----------------
template <int EPI>
__global__ __launch_bounds__(256) void k_gemm(const unsigned short* __restrict__ A, const unsigned short* __restrict__ Bt,
                                              void* __restrict__ Cout, const float* __restrict__ aux,
                                              int M, int N, int K) {
    __shared__ alignas(16) unsigned short As[128 * 64];
    __shared__ alignas(16) unsigned short Bs[128 * 64];
    const int tid = threadIdx.x;
    const int m0 = blockIdx.y * 128, n0 = blockIdx.x * 128;
    const int wave = tid >> 6, lane = tid & 63;
    const int wm = (wave >> 1) * 64, wn = (wave & 1) * 64;
    const int fr = lane & 15, fg = lane >> 4;
    const int srow = tid >> 3;
    const int ske = (tid & 7) * 8;

    f32x4 acc[4][4];
#pragma unroll
    for (int m = 0; m < 4; m++)
#pragma unroll
        for (int n = 0; n < 4; n++) acc[m][n] = (f32x4)(0.f);

    const int nk = K >> 6;
    u32x4 ra[4], rb[4];
#pragma unroll
    for (int i = 0; i < 4; i++) {
        ra[i] = *(const u32x4*)(A + (size_t)(m0 + srow + 32 * i) * K + ske);
        rb[i] = *(const u32x4*)(Bt + (size_t)(n0 + srow + 32 * i) * K + ske);
    }
    for (int kt = 0; kt < nk; ++kt) {
        __syncthreads();
#pragma unroll
        for (int i = 0; i < 4; i++) {
            int lin = (tid + 256 * i) * 16;
            int sw = lin ^ (((lin >> 7) & 7) << 4);
            *(u32x4*)((char*)As + sw) = ra[i];
            *(u32x4*)((char*)Bs + sw) = rb[i];
        }
        __syncthreads();
        if (kt + 1 < nk) {
#pragma unroll
            for (int i = 0; i < 4; i++) {
                ra[i] = *(const u32x4*)(A + (size_t)(m0 + srow + 32 * i) * K + (kt + 1) * 64 + ske);
                rb[i] = *(const u32x4*)(Bt + (size_t)(n0 + srow + 32 * i) * K + (kt + 1) * 64 + ske);
            }
        }
#pragma unroll
        for (int ks = 0; ks < 2; ++ks) {
            bf16x8 af[4], bg[4];
#pragma unroll
            for (int m = 0; m < 4; m++) {
                int row = wm + m * 16 + fr;
                int lin = row * 128 + ks * 64 + fg * 16;
                af[m] = *(const bf16x8*)((const char*)As + (lin ^ ((row & 7) << 4)));
            }
#pragma unroll
            for (int n = 0; n < 4; n++) {
                int col = wn + n * 16 + fr;
                int lin = col * 128 + ks * 64 + fg * 16;
                bg[n] = *(const bf16x8*)((const char*)Bs + (lin ^ ((col & 7) << 4)));
            }
#pragma unroll
            for (int m = 0; m < 4; m++)
#pragma unroll
                for (int n = 0; n < 4; n++)
                    acc[m][n] = __builtin_amdgcn_mfma_f32_16x16x32_bf16(af[m], bg[n], acc[m][n], 0, 0, 0);
        }
    }
#pragma unroll
    for (int m = 0; m < 4; m++) {
#pragma unroll
        for (int r = 0; r < 4; r++) {
            size_t row = (size_t)(m0 + wm + m * 16 + fg * 4 + r);
#pragma unroll
            for (int n = 0; n < 4; n++) {
                size_t idx = row * N + n0 + wn + n * 16 + fr;
                float v = acc[m][n][r];
                if constexpr (EPI == 0) ((float*)Cout)[idx] = v;
                else if constexpr (EPI == 4) ((unsigned short*)Cout)[idx] = f2bfu(0.5f * v * (1.f + erff(v * 0.70710678118f)));
                else ((float*)Cout)[idx] = v + aux[idx];
            }
        }
    }
}

// ---------------- paired skinny GEMMs: z=0: A0xB0->C0 (K0), z=1: A1xB1->C1 (K1); N=1024 ------
__global__ __launch_bounds__(256) void k_gemm_pair(const unsigned short* __restrict__ A0, const unsigned short* __restrict__ B0,
                                                   float* __restrict__ C0, int K0,
                                                   const unsigned short* __restrict__ A1, const unsigned short* __restrict__ B1,
                                                   float* __restrict__ C1, int K1) {
    __shared__ alignas(16) unsigned short As[128 * 64];
    __shared__ alignas(16) unsigned short Bs[128 * 64];
    const int tid = threadIdx.x;
    const int z = blockIdx.z;
    const unsigned short* __restrict__ A = z ? A1 : A0;
    const unsigned short* __restrict__ Bt = z ? B1 : B0;
    float* __restrict__ C = z ? C1 : C0;
    const int K = z ? K1 : K0;
    const int N = 1024;
    const int m0 = blockIdx.y * 128, n0 = blockIdx.x * 128;
    const int wave = tid >> 6, lane = tid & 63;
    const int wm = (wave >> 1) * 64, wn = (wave & 1) * 64;
    const int fr = lane & 15, fg = lane >> 4;
    const int srow = tid >> 3;
    const int ske = (tid & 7) * 8;

    f32x4 acc[4][4];
#pragma unroll
    for (int m = 0; m < 4; m++)
#pragma unroll
        for (int n = 0; n < 4; n++) acc[m][n] = (f32x4)(0.f);

    const int nk = K >> 6;
    u32x4 ra[4], rb[4];
#pragma unroll
    for (int i = 0; i < 4; i++) {
        ra[i] = *(const u32x4*)(A + (size_t)(m0 + srow + 32 * i) * K + ske);
        rb[i] = *(const u32x4*)(Bt + (size_t)(n0 + srow + 32 * i) * K + ske);
    }
    for (int kt = 0; kt < nk; ++kt) {
        __syncthreads();
#pragma unroll
        for (int i = 0; i < 4; i++) {
            int lin = (tid + 256 * i) * 16;
            int sw = lin ^ (((lin >> 7) & 7) << 4);
            *(u32x4*)((char*)As + sw) = ra[i];
            *(u32x4*)((char*)Bs + sw) = rb[i];
        }
        __syncthreads();
        if (kt + 1 < nk) {
#pragma unroll
            for (int i = 0; i < 4; i++) {
                ra[i] = *(const u32x4*)(A + (size_t)(m0 + srow + 32 * i) * K + (kt + 1) * 64 + ske);
                rb[i] = *(const u32x4*)(Bt + (size_t)(n0 + srow + 32 * i) * K + (kt + 1) * 64 + ske);
            }
        }
#pragma unroll
        for (int ks = 0; ks < 2; ++ks) {
            bf16x8 af[4], bg[4];
#pragma unroll
            for (int m = 0; m < 4; m++) {
                int row = wm + m * 16 + fr;
                int lin = row * 128 + ks * 64 + fg * 16;
                af[m] = *(const bf16x8*)((const char*)As + (lin ^ ((row & 7) << 4)));
            }
#pragma unroll
            for (int n = 0; n < 4; n++) {
                int col = wn + n * 16 + fr;
                int lin = col * 128 + ks * 64 + fg * 16;
                bg[n] = *(const bf16x8*)((const char*)Bs + (lin ^ ((col & 7) << 4)));
            }
#pragma unroll
            for (int m = 0; m < 4; m++)
#pragma unroll
                for (int n = 0; n < 4; n++)
                    acc[m][n] = __builtin_amdgcn_mfma_f32_16x16x32_bf16(af[m], bg[n], acc[m][n], 0, 0, 0);
        }
    }
#pragma unroll
    for (int m = 0; m < 4; m++) {
#pragma unroll
        for (int r = 0; r < 4; r++) {
            size_t row = (size_t)(m0 + wm + m * 16 + fg * 4 + r);
#pragma unroll
            for (int n = 0; n < 4; n++) {
                size_t idx = row * N + n0 + wn + n * 16 + fr;
                C[idx] = acc[m][n][r];
            }
        }
    }
}

// ---------------- fused projection GEMM ----------------
__global__ __launch_bounds__(256) void k_gemm_fused(const unsigned short* __restrict__ A, const unsigned short* __restrict__ Bt,
                                                    unsigned short* __restrict__ RB, unsigned short* __restrict__ KB,
                                                    unsigned short* __restrict__ VB, unsigned short* __restrict__ GB,
                                                    float* __restrict__ WF, unsigned short* __restrict__ C2B) {
    __shared__ alignas(16) unsigned short As[128 * 64];
    __shared__ alignas(16) unsigned short Bs[128 * 64];
    const int tid = threadIdx.x;
    const int m0 = blockIdx.y * 128, n0 = blockIdx.x * 128;
    const int wave = tid >> 6, lane = tid & 63;
    const int wm = (wave >> 1) * 64, wn = (wave & 1) * 64;
    const int fr = lane & 15, fg = lane >> 4;
    const int srow = tid >> 3;
    const int ske = (tid & 7) * 8;
    const int K = 1024;

    f32x4 acc[4][4];
#pragma unroll
    for (int m = 0; m < 4; m++)
#pragma unroll
        for (int n = 0; n < 4; n++) acc[m][n] = (f32x4)(0.f);

    u32x4 ra[4], rb[4];
#pragma unroll
    for (int i = 0; i < 4; i++) {
        ra[i] = *(const u32x4*)(A + (size_t)(m0 + srow + 32 * i) * K + ske);
        rb[i] = *(const u32x4*)(Bt + (size_t)(n0 + srow + 32 * i) * K + ske);
    }
    for (int kt = 0; kt < 16; ++kt) {
        __syncthreads();
#pragma unroll
        for (int i = 0; i < 4; i++) {
            int lin = (tid + 256 * i) * 16;
            int sw = lin ^ (((lin >> 7) & 7) << 4);
            *(u32x4*)((char*)As + sw) = ra[i];
            *(u32x4*)((char*)Bs + sw) = rb[i];
        }
        __syncthreads();
        if (kt + 1 < 16) {
#pragma unroll
            for (int i = 0; i < 4; i++) {
                ra[i] = *(const u32x4*)(A + (size_t)(m0 + srow + 32 * i) * K + (kt + 1) * 64 + ske);
                rb[i] = *(const u32x4*)(Bt + (size_t)(n0 + srow + 32 * i) * K + (kt + 1) * 64 + ske);
            }
        }
#pragma unroll
        for (int ks = 0; ks < 2; ++ks) {
            bf16x8 af[4], bg[4];
#pragma unroll
            for (int m = 0; m < 4; m++) {
                int row = wm + m * 16 + fr;
                int lin = row * 128 + ks * 64 + fg * 16;
                af[m] = *(const bf16x8*)((const char*)As + (lin ^ ((row & 7) << 4)));
            }
#pragma unroll
            for (int n = 0; n < 4; n++) {
                int col = wn + n * 16 + fr;
                int lin = col * 128 + ks * 64 + fg * 16;
                bg[n] = *(const bf16x8*)((const char*)Bs + (lin ^ ((col & 7) << 4)));
            }
#pragma unroll
            for (int m = 0; m < 4; m++)
#pragma unroll
                for (int n = 0; n < 4; n++)
                    acc[m][n] = __builtin_amdgcn_mfma_f32_16x16x32_bf16(af[m], bg[n], acc[m][n], 0, 0, 0);
        }
    }
    const int seg = n0 >> 10;
#pragma unroll
    for (int m = 0; m < 4; m++) {
#pragma unroll
        for (int r = 0; r < 4; r++) {
            size_t row = (size_t)(m0 + wm + m * 16 + fg * 4 + r);
#pragma unroll
            for (int n = 0; n < 4; n++) {
                int gcol = n0 + wn + n * 16 + fr;
                float v = acc[m][n][r];
                if (n0 < 5120) {
                    size_t idx = row * 1024 + (gcol & 1023);
                    if (seg == 0) RB[idx] = f2bfu(v);
                    else if (seg == 1) KB[idx] = f2bfu(v);
                    else if (seg == 2) VB[idx] = f2bfu(v);
                    else if (seg == 3) GB[idx] = f2bfu(siluf(v));
                    else WF[idx] = expf(-expf(v));
                } else {
                    C2B[row * 4480 + (gcol - 5120)] = f2bfu(v);
                }
            }
        }
    }
}

// ---------------- RWKV chunk prep ----------------
__global__ __launch_bounds__(256) void k_rwkv_prep(unsigned short* __restrict__ RB, unsigned short* __restrict__ KB,
                                                   const float* __restrict__ WF, const float* __restrict__ u,
                                                   unsigned short* __restrict__ KDt, unsigned short* __restrict__ QLb,
                                                   float* __restrict__ DDb) {
    __shared__ float red[16][257];
    __shared__ float red2[16][17];
    const int c = blockIdx.x, bh = blockIdx.y;
    const int b = bh >> 2, h = bh & 3;
    const int k = threadIdx.x;
    const size_t m0 = (size_t)b * T_ + c * 16;
    const int hk = h * 256 + k;
    const float uv = u[hk];
    float Q = 1.f;
    float kd[16];
#pragma unroll
    for (int s = 0; s < 16; s++) {
        size_t off = (m0 + s) * H_ + hk;
        float r = bfu2f(RB[off]);
        float kv = bfu2f(KB[off]);
        float w = WF[off];
        RB[off] = f2bfu(r * Q);
        Q = fmaxf(Q * w, 1e-35f);
        float kdv = kv / Q;
        kd[s] = kdv;
        KB[off] = f2bfu(kdv);
        red[s][k] = r * uv * kv;
    }
    QLb[((size_t)(b * 128 + c)) * 1024 + hk] = f2bfu(Q);
    size_t kt0 = (((size_t)(b * 128 + c)) * 1024 + hk) * 16;
#pragma unroll
    for (int s = 0; s < 16; s++) KDt[kt0 + s] = f2bfu(kd[s]);
    __syncthreads();
    {
        int s = threadIdx.x >> 4, part = threadIdx.x & 15;
        float ps = 0.f;
#pragma unroll
        for (int j = 0; j < 16; j++) ps += red[s][part * 16 + j];
        red2[s][part] = ps;
    }
    __syncthreads();
    if (threadIdx.x < 32) {
        int s = threadIdx.x & 15, half = threadIdx.x >> 4;
        float d = 0.f;
#pragma unroll
        for (int j = 0; j < 8; j++) d += red2[s][half * 8 + j];
        DDb[(((size_t)bh * 128 + c) * 2 + half) * 16 + s] = d;
    }
}

// ---------------- merged carries: z<512 rwkv carry, z>=512 mamba carry ----------------
__global__ __launch_bounds__(256) void k_carry2(const unsigned short* __restrict__ KD, const unsigned short* __restrict__ VB,
                                                const unsigned short* __restrict__ QLb, unsigned short* __restrict__ Scc,
                                                const float* __restrict__ BCF, const unsigned short* __restrict__ XB,
                                                const float* __restrict__ WSC, const float* __restrict__ QC,
                                                unsigned short* __restrict__ MSCC) {
    __shared__ alignas(16) float smem[13440];   // 53,760 B union
    const int tid = threadIdx.x;
    if (blockIdx.x < 512) {
        // -------- rwkv carry: kds [16][256] ushort @0, lv [16][4] f32 @8192B --------
        unsigned short* kds = (unsigned short*)smem;
        float* lv = smem + 2048;
        const int vg = blockIdx.x & 63, bh = blockIdx.x >> 6;
        const int b = bh >> 2, h = bh & 3;
        const int k = tid;
        const int hk = h * 256 + k;
        const size_t baseM = (size_t)b * T_;
        float s0 = 0.f, s1 = 0.f, s2 = 0.f, s3 = 0.f;
        for (int c = 0; c < 128; ++c) {
            size_t m0 = baseM + c * 16;
            if ((c & 7) == 0 && c > 0) {
                int cc = c >> 3;
                size_t sb = ((size_t)(bh * 16 + cc) * 256 + vg * 4) * 256 + k;
                Scc[sb] = f2bfu(s0); Scc[sb + 256] = f2bfu(s1);
                Scc[sb + 512] = f2bfu(s2); Scc[sb + 768] = f2bfu(s3);
            }
            __syncthreads();
#pragma unroll
            for (int it = 0; it < 2; ++it) {
                int i = tid + it * 256;
                int row = i >> 5, col8 = (i & 31) * 8;
                *(u32x4*)(kds + row * 256 + col8) = *(const u32x4*)(KD + (m0 + row) * H_ + h * 256 + col8);
            }
            if (tid < 64) {
                int t = tid >> 2, j = tid & 3;
                lv[t * 4 + j] = bfu2f(VB[(m0 + t) * H_ + h * 256 + vg * 4 + j]);
            }
            __syncthreads();
            float a0 = 0.f, a1 = 0.f, a2 = 0.f, a3 = 0.f;
#pragma unroll
            for (int t = 0; t < 16; t++) {
                float kdv = bfu2f(kds[t * 256 + k]);
                a0 = fmaf(kdv, lv[t * 4 + 0], a0);
                a1 = fmaf(kdv, lv[t * 4 + 1], a1);
                a2 = fmaf(kdv, lv[t * 4 + 2], a2);
                a3 = fmaf(kdv, lv[t * 4 + 3], a3);
            }
            float ql = bfu2f(QLb[((size_t)(b * 128 + c)) * 1024 + hk]);
            s0 = (s0 + a0) * ql; s1 = (s1 + a1) * ql;
            s2 = (s2 + a2) * ql; s3 = (s3 + a3) * ql;
        }
    } else {
        // -------- mamba carry: Bsf [64][128] f32 @0, BWt [128][72] u16 @32768B,
        //          XT [16][72] u16 @51200B, wsl [64] f32 @53504B --------
        float* Bsf = smem;
        unsigned short* BWt = (unsigned short*)((char*)smem + 32768);
        unsigned short* XT = (unsigned short*)((char*)smem + 51200);
        float* wsl = (float*)((char*)smem + 53504);
        int zz = blockIdx.x - 512;
        const int dq = zz & 3, bh = zz >> 2;
        const int b = bh >> 5, h = bh & 31;
        const int wave = tid >> 6, lane = tid & 63;
        const int l16 = lane & 15, lq = lane >> 4;
        const size_t baseM = (size_t)b * T_;
        f32x4 sreg[2];
        sreg[0] = (f32x4)(0.f); sreg[1] = (f32x4)(0.f);

        for (int cc = 0; cc < 15; ++cc) {
            float qC = QC[bh * 16 + cc];
            sreg[0] *= qC; sreg[1] *= qC;
            for (int sub = 0; sub < 2; ++sub) {
                int t0g = cc * 128 + sub * 64;
                __syncthreads();
                if (tid < 64) wsl[tid] = WSC[(size_t)bh * 2048 + t0g + tid];
#pragma unroll
                for (int i = 0; i < 8; i++) {
                    int idx4 = tid + i * 256;
                    int t = idx4 >> 5, s4 = (idx4 & 31) * 4;
                    *(float4*)(Bsf + t * 128 + s4) = *(const float4*)(BCF + (baseM + t0g + t) * 256 + s4);
                }
#pragma unroll
                for (int i = 0; i < 4; i++) {
                    int idx = tid + i * 256;
                    int t = idx >> 4, d = idx & 15;
                    XT[d * 72 + t] = XB[(baseM + t0g + t) * DI + h * 64 + dq * 16 + d];
                }
                __syncthreads();
                {
                    int sg = tid >> 1;
                    int tb = (tid & 1) * 32;
#pragma unroll
                    for (int q = 0; q < 8; q++) {
                        int tt = tb + q * 4;
                        ushort4 v;
                        v.x = f2bfu(Bsf[(tt + 0) * 128 + sg] * wsl[tt + 0]);
                        v.y = f2bfu(Bsf[(tt + 1) * 128 + sg] * wsl[tt + 1]);
                        v.z = f2bfu(Bsf[(tt + 2) * 128 + sg] * wsl[tt + 2]);
                        v.w = f2bfu(Bsf[(tt + 3) * 128 + sg] * wsl[tt + 3]);
                        *(ushort4*)(BWt + sg * 72 + tt) = v;
                    }
                }
                __syncthreads();
#pragma unroll
                for (int st = 0; st < 2; st++) {
#pragma unroll
                    for (int ks = 0; ks < 2; ks++) {
                        bf16x8 bwf = *(const bf16x8*)(BWt + (wave * 32 + st * 16 + l16) * 72 + ks * 32 + lq * 8);
                        bf16x8 xtf = *(const bf16x8*)(XT + l16 * 72 + ks * 32 + lq * 8);
                        sreg[st] = __builtin_amdgcn_mfma_f32_16x16x32_bf16(bwf, xtf, sreg[st], 0, 0, 0);
                    }
                }
            }
            size_t dbase = ((size_t)(bh * 16 + cc + 1) * 64 + dq * 16 + l16) * 128;
#pragma unroll
            for (int st = 0; st < 2; st++) {
                ushort4 pk;
                pk.x = f2bfu(sreg[st][0]); pk.y = f2bfu(sreg[st][1]);
                pk.z = f2bfu(sreg[st][2]); pk.w = f2bfu(sreg[st][3]);
                *(ushort4*)(MSCC + dbase + wave * 32 + st * 16 + lq * 4) = pk;
            }
        }
    }
}

// ---------------- RWKV chunked output (MFMA) ----------------
__global__ __launch_bounds__(256) void k_rwkv_out(const unsigned short* __restrict__ RT, const unsigned short* __restrict__ KD,
                                                  const unsigned short* __restrict__ KDt, const unsigned short* __restrict__ VB,
                                                  const unsigned short* __restrict__ QLb, const float* __restrict__ DDb,
                                                  const unsigned short* __restrict__ Scc,
                                                  float* __restrict__ P0, float* __restrict__ P1) {
    __shared__ unsigned short Sb[64][136];
    __shared__ unsigned short VT[64][24];
    __shared__ unsigned short Ab[16][24];
    __shared__ float dls[16];
    const int tid = threadIdx.x;
    const int vt = blockIdx.x, cc = blockIdx.y;
    const int bh = blockIdx.z >> 1, kh = blockIdx.z & 1;
    const int b = bh >> 2, h = bh & 3;
    const int wave = tid >> 6, lane = tid & 63;
    const int l16 = lane & 15, lq = lane >> 4;
    const int wv0 = wave * 16;
    const int hk0 = h * 256 + kh * 128;
    const int hv = h * 256 + vt * 64;
    const int aoff = (lq < 2) ? lq * 8 : 0;
    float* __restrict__ OP = kh ? P1 : P0;
    f32x4 sreg[8];
    if (cc == 0) {
#pragma unroll
        for (int kt = 0; kt < 8; kt++) sreg[kt] = (f32x4)(0.f);
        for (int i = tid; i < 64 * 136 / 8; i += 256) ((u32x4*)Sb)[i] = (u32x4)(0u);
    } else {
        size_t sbase = ((size_t)(bh * 16 + cc) * 256 + vt * 64);
        for (int i = tid; i < 1024; i += 256) {
            int v = i >> 4, k8 = (i & 15) * 8;
            *(u32x4*)&Sb[v][k8] = *(const u32x4*)(Scc + (sbase + v) * 256 + kh * 128 + k8);
        }
#pragma unroll
        for (int kt = 0; kt < 8; kt++) {
            ushort4 w4 = *(const ushort4*)(Scc + (sbase + wv0 + l16) * 256 + kh * 128 + kt * 16 + lq * 4);
            sreg[kt][0] = bfu2f(w4.x); sreg[kt][1] = bfu2f(w4.y);
            sreg[kt][2] = bfu2f(w4.z); sreg[kt][3] = bfu2f(w4.w);
        }
    }
    __syncthreads();

    for (int fc = 0; fc < 8; ++fc) {
        const int c = cc * 8 + fc;
        const size_t m0 = (size_t)b * T_ + c * 16;
        const size_t bc = (size_t)(b * 128 + c);
        if (fc > 0) __syncthreads();
        {
            int st = tid >> 4, v4 = (tid & 15) * 4;
            ushort4 v4v = *(const ushort4*)(VB + (m0 + st) * H_ + hv + v4);
            VT[v4 + 0][st] = v4v.x; VT[v4 + 1][st] = v4v.y;
            VT[v4 + 2][st] = v4v.z; VT[v4 + 3][st] = v4v.w;
            if (tid < 16) dls[tid] = DDb[(((size_t)bh * 128 + c) * 2 + kh) * 16 + tid];
        }
        __syncthreads();
        const size_t rowA = (m0 + l16) * H_ + hk0;
        bf16x8 rtf[4];
#pragma unroll
        for (int ks = 0; ks < 4; ks++) rtf[ks] = *(const bf16x8*)(RT + rowA + ks * 32 + lq * 8);
        f32x4 Aacc = (f32x4)(0.f);
#pragma unroll
        for (int ks = 0; ks < 4; ks++) {
            bf16x8 kdf = *(const bf16x8*)(KD + rowA + ks * 32 + lq * 8);
            Aacc = __builtin_amdgcn_mfma_f32_16x16x32_bf16(rtf[ks], kdf, Aacc, 0, 0, 0);
        }
        f32x4 oacc = (f32x4)(0.f);
#pragma unroll
        for (int ks = 0; ks < 4; ks++) {
            bf16x8 sbf = *(const bf16x8*)(&Sb[wv0 + l16][ks * 32 + lq * 8]);
            oacc = __builtin_amdgcn_mfma_f32_16x16x32_bf16(rtf[ks], sbf, oacc, 0, 0, 0);
        }
#pragma unroll
        for (int r = 0; r < 4; r++) {
            int t = lq * 4 + r, s = l16;
            float av = (s < t) ? Aacc[r] : ((s == t) ? dls[t] : 0.f);
            Ab[t][s] = f2bfu(av);
        }
        bf16x8 abf_t = *(const bf16x8*)(&Ab[l16][aoff]);
        bf16x8 vtf_t = *(const bf16x8*)(&VT[wv0 + l16][aoff]);
        bf16x8 abf = (lq < 2) ? abf_t : zero8();
        bf16x8 vtf = (lq < 2) ? vtf_t : zero8();
        oacc = __builtin_amdgcn_mfma_f32_16x16x32_bf16(abf, vtf, oacc, 0, 0, 0);
#pragma unroll
        for (int r = 0; r < 4; r++)
            OP[(m0 + lq * 4 + r) * H_ + hv + wv0 + l16] = oacc[r];
#pragma unroll
        for (int kt = 0; kt < 8; kt++) {
            const unsigned short* kp = KDt + (((bc * 1024) + hk0 + kt * 16 + l16) << 4) + aoff;
            bf16x8 kdtf_t = *(const bf16x8*)kp;
            bf16x8 kdtf = (lq < 2) ? kdtf_t : zero8();
            sreg[kt] = __builtin_amdgcn_mfma_f32_16x16x32_bf16(kdtf, vtf, sreg[kt], 0, 0, 0);
            ushort4 q4 = *(const ushort4*)(QLb + bc * 1024 + hk0 + kt * 16 + lq * 4);
            sreg[kt][0] *= bfu2f(q4.x); sreg[kt][1] *= bfu2f(q4.y);
            sreg[kt][2] *= bfu2f(q4.z); sreg[kt][3] *= bfu2f(q4.w);
            ushort4 pk;
            pk.x = f2bfu(sreg[kt][0]); pk.y = f2bfu(sreg[kt][1]);
            pk.z = f2bfu(sreg[kt][2]); pk.w = f2bfu(sreg[kt][3]);
            *(ushort4*)(&Sb[wv0 + l16][kt * 16 + lq * 4]) = pk;
        }
    }
}

// ---------------- conv ----------------
__global__ __launch_bounds__(256) void k_conv(const unsigned short* __restrict__ C2B, const float* __restrict__ conv_w,
                                              const float* __restrict__ conv_b, unsigned short* __restrict__ XB,
                                              float* __restrict__ BCF) {
    int m = blockIdx.y;
    int c = blockIdx.x * 256 + threadIdx.x;
    int b = m >> 11, t = m & 2047;
    float acc = conv_b[c];
#pragma unroll
    for (int i = 0; i < 4; i++) {
        int tt = t - 3 + i;
        if (tt >= 0) acc = fmaf(bfu2f(C2B[((size_t)(b * T_ + tt)) * LD2 + DI + c]), conv_w[c * 4 + i], acc);
    }
    float r = siluf(acc);
    if (c < DI) XB[(size_t)m * DI + c] = f2bfu(r);
    else BCF[(size_t)m * 256 + (c - DI)] = r;
}

// ---------------- Mamba chunk prep ----------------
__global__ __launch_bounds__(256) void k_mprep(const unsigned short* __restrict__ C2B,
                                               const float* __restrict__ dt_bias, const float* __restrict__ A_log,
                                               float* __restrict__ DT, float* __restrict__ CD,
                                               float* __restrict__ WS, float* __restrict__ WSC,
                                               float* __restrict__ QJ, float* __restrict__ QLf,
                                               float* __restrict__ QC) {
    __shared__ float sums[128], offs[128], ce[16];
    const int bh = blockIdx.x;
    const int b = bh >> 5, h = bh & 31;
    const int c = threadIdx.x;
    const float A = -expf(A_log[h]);
    const float dtb = dt_bias[h];
    float dloc[16], cdl[16];
    if (c < 128) {
        float acc = 0.f;
#pragma unroll
        for (int s = 0; s < 16; s++) {
            size_t m = (size_t)b * T_ + c * 16 + s;
            float draw = bfu2f(C2B[m * LD2 + 4352 + h]) + dtb;
            float dt = draw > 20.f ? draw : log1pf(expf(draw));
            acc += dt;
            dloc[s] = dt; cdl[s] = acc;
        }
        sums[c] = acc;
    }
    __syncthreads();
    if (threadIdx.x == 0) {
        float run = 0.f;
        for (int i = 0; i < 128; i++) { offs[i] = run; run += sums[i]; }
    }
    __syncthreads();
    if (threadIdx.x < 16) {
        int last = threadIdx.x * 8 + 7;
        ce[threadIdx.x] = offs[last] + sums[last];
    }
    __syncthreads();
    if (c < 128) {
        float off = offs[c];
        float cd15 = off + cdl[15];
        float ceC = ce[c >> 3];
        QLf[bh * 128 + c] = expf(fminf(A * cdl[15], 0.f));
        size_t base = (size_t)bh * 2048 + c * 16;
#pragma unroll
        for (int s = 0; s < 16; s++) {
            float cdg = off + cdl[s];
            DT[base + s] = dloc[s];
            CD[base + s] = cdg;
            QJ[base + s] = expf(fminf(A * (cdg - off), 0.f));
            WS[base + s] = expf(fminf(A * (cd15 - cdg), 0.f)) * dloc[s];
            WSC[base + s] = expf(fminf(A * (ceC - cdg), 0.f)) * dloc[s];
        }
    }
    if (threadIdx.x < 16) {
        float prev = threadIdx.x ? ce[threadIdx.x - 1] : 0.f;
        QC[bh * 16 + threadIdx.x] = expf(fminf(A * (ce[threadIdx.x] - prev), 0.f));
    }
}

// ---------------- Mamba A-mask precompute ----------------
__global__ __launch_bounds__(64) void k_amask(const float* __restrict__ BCF,
                                              const float* __restrict__ CD, const float* __restrict__ DT,
                                              const float* __restrict__ A_log,
                                              unsigned short* __restrict__ AM) {
    const int c = blockIdx.x, bh = blockIdx.y;
    const int b = bh >> 5, h = bh & 31;
    const int lane = threadIdx.x;
    const int l16 = lane & 15, lq = lane >> 4;
    const float A = -expf(A_log[h]);
    const size_t m = (size_t)b * T_ + c * 16 + l16;
    f32x4 Aacc = (f32x4)(0.f);
#pragma unroll
    for (int ks = 0; ks < 4; ks++) {
        bf16x8 cf, bf;
        const float* cr = BCF + m * 256 + 128 + ks * 32 + lq * 8;
        const float* br = BCF + m * 256 + ks * 32 + lq * 8;
#pragma unroll
        for (int i = 0; i < 8; i++) { cf[i] = (__bf16)cr[i]; bf[i] = (__bf16)br[i]; }
        Aacc = __builtin_amdgcn_mfma_f32_16x16x32_bf16(cf, bf, Aacc, 0, 0, 0);
    }
    size_t base = ((size_t)bh * 128 + c) * 256;
    size_t tb = (size_t)bh * 2048 + c * 16;
    float cds = CD[tb + l16];
    float dts = DT[tb + l16];
#pragma unroll
    for (int r = 0; r < 4; r++) {
        int j = lq * 4 + r;
        float av = 0.f;
        if (l16 <= j) {
            float cdj = CD[tb + j];
            av = Aacc[r] * expf(fminf(A * (cdj - cds), 0.f)) * dts;
        }
        AM[base + j * 16 + l16] = f2bfu(av);
    }
}

// ---------------- Mamba chunked output (MFMA) ----------------
__global__ __launch_bounds__(256) void k_mout(const float* __restrict__ BCF, const unsigned short* __restrict__ XB,
                                              const unsigned short* __restrict__ AM,
                                              const float* __restrict__ QJ, const float* __restrict__ WS,
                                              const float* __restrict__ QLf, const unsigned short* __restrict__ MSCC,
                                              unsigned short* __restrict__ Y) {
    __shared__ unsigned short Sb[64][136];
    __shared__ unsigned short Cs[16][136];
    __shared__ unsigned short BWt[128][24];
    __shared__ unsigned short XT[64][24];
    __shared__ unsigned short Ab[16][24];
    __shared__ float qjl[16], wsl[16], qLl;
    const int tid = threadIdx.x;
    const int cc = blockIdx.x, bh = blockIdx.y;
    const int b = bh >> 5, h = bh & 31;
    const int wave = tid >> 6, lane = tid & 63;
    const int l16 = lane & 15, lq = lane >> 4;
    const int wv0 = wave * 16;
    const int aoff = (lq < 2) ? lq * 8 : 0;
    const size_t baseM = (size_t)b * T_;
    f32x4 sreg[8];
    if (cc == 0) {
#pragma unroll
        for (int kt = 0; kt < 8; kt++) sreg[kt] = (f32x4)(0.f);
        for (int i = tid; i < 64 * 136 / 8; i += 256) ((u32x4*)Sb)[i] = (u32x4)(0u);
    } else {
        size_t sbase = (size_t)(bh * 16 + cc) * 64;
        for (int i = tid; i < 1024; i += 256) {
            int d = i >> 4, s8 = (i & 15) * 8;
            *(u32x4*)&Sb[d][s8] = *(const u32x4*)(MSCC + (sbase + d) * 128 + s8);
        }
#pragma unroll
        for (int kt = 0; kt < 8; kt++) {
            ushort4 w4 = *(const ushort4*)(MSCC + (sbase + wv0 + l16) * 128 + kt * 16 + lq * 4);
            sreg[kt][0] = bfu2f(w4.x); sreg[kt][1] = bfu2f(w4.y);
            sreg[kt][2] = bfu2f(w4.z); sreg[kt][3] = bfu2f(w4.w);
        }
    }

    for (int fc = 0; fc < 8; ++fc) {
        const int c = cc * 8 + fc;
        const size_t m0 = baseM + c * 16;
        __syncthreads();
        if (tid < 16) {
            size_t tb = (size_t)bh * 2048 + c * 16 + tid;
            qjl[tid] = QJ[tb];
            wsl[tid] = WS[tb];
            if (tid == 0) qLl = QLf[bh * 128 + c];
        }
        {
            int j = tid >> 4, s = tid & 15;
            Ab[j][s] = AM[((size_t)bh * 128 + c) * 256 + tid];
        }
#pragma unroll
        for (int i = 0; i < 8; i++) {
            int idx = tid + i * 256;
            int t = idx >> 7, sig = idx & 127;
            Cs[t][sig] = f2bfu(BCF[(m0 + t) * 256 + 128 + sig]);
        }
#pragma unroll
        for (int i = 0; i < 4; i++) {
            int idx = tid + i * 256;
            int t = idx >> 6, d = idx & 63;
            XT[d][t] = XB[(m0 + t) * DI + h * 64 + d];
        }
        __syncthreads();
#pragma unroll
        for (int i = 0; i < 8; i++) {
            int idx = tid + i * 256;
            int t = idx >> 7, sig = idx & 127;
            BWt[sig][t] = f2bfu(BCF[(m0 + t) * 256 + sig] * wsl[t]);
        }
        __syncthreads();
        bf16x8 cf[4];
#pragma unroll
        for (int ks = 0; ks < 4; ks++) cf[ks] = *(const bf16x8*)(&Cs[l16][ks * 32 + lq * 8]);
        f32x4 oacc = (f32x4)(0.f);
#pragma unroll
        for (int ks = 0; ks < 4; ks++) {
            bf16x8 sbf = *(const bf16x8*)(&Sb[wv0 + l16][ks * 32 + lq * 8]);
            oacc = __builtin_amdgcn_mfma_f32_16x16x32_bf16(cf[ks], sbf, oacc, 0, 0, 0);
        }
#pragma unroll
        for (int r = 0; r < 4; r++) oacc[r] *= qjl[lq * 4 + r];
        bf16x8 abf_t = *(const bf16x8*)(&Ab[l16][aoff]);
        bf16x8 xtf_t = *(const bf16x8*)(&XT[wv0 + l16][aoff]);
        bf16x8 abf = (lq < 2) ? abf_t : zero8();
        bf16x8 xtf = (lq < 2) ? xtf_t : zero8();
        oacc = __builtin_amdgcn_mfma_f32_16x16x32_bf16(abf, xtf, oacc, 0, 0, 0);
#pragma unroll
        for (int r = 0; r < 4; r++)
            Y[(m0 + lq * 4 + r) * DI + h * 64 + wv0 + l16] = f2bfu(oacc[r]);
        float qL = qLl;
#pragma unroll
        for (int kt = 0; kt < 8; kt++) {
            sreg[kt] *= qL;
            bf16x8 bwf_t = *(const bf16x8*)(&BWt[kt * 16 + l16][aoff]);
            bf16x8 bwf = (lq < 2) ? bwf_t : zero8();
            sreg[kt] = __builtin_amdgcn_mfma_f32_16x16x32_bf16(bwf, xtf, sreg[kt], 0, 0, 0);
            ushort4 pk;
            pk.x = f2bfu(sreg[kt][0]); pk.y = f2bfu(sreg[kt][1]);
            pk.z = f2bfu(sreg[kt][2]); pk.w = f2bfu(sreg[kt][3]);
            *(ushort4*)(&Sb[wv0 + l16][kt * 16 + lq * 4]) = pk;
        }
    }
}

// ---------------- merged posts: z<4096 rwkv post, z>=4096 mamba post ----------------
__global__ __launch_bounds__(256) void k_post2(const float* __restrict__ P0, const float* __restrict__ P1,
                                               const float* __restrict__ gn_w, unsigned short* __restrict__ g_io,
                                               unsigned short* __restrict__ y_io, const unsigned short* __restrict__ XB,
                                               const unsigned short* __restrict__ C2B, const float* __restrict__ D_m,
                                               const float* __restrict__ mnw) {
    __shared__ float red[4];
    const int tid = threadIdx.x;
    if (blockIdx.x < 4096) {
        int m = blockIdx.x;
        int wave = tid >> 6, lane = tid & 63;
        size_t base = (size_t)m * H_ + wave * 256 + lane * 4;
        int col = wave * 256 + lane * 4;
        float4 a = *(const float4*)(P0 + base);
        float4 b4 = *(const float4*)(P1 + base);
        float4 v; v.x = a.x + b4.x; v.y = a.y + b4.y; v.z = a.z + b4.z; v.w = a.w + b4.w;
        float ss = v.x * v.x + v.y * v.y + v.z * v.z + v.w * v.w;
#pragma unroll
        for (int off = 32; off; off >>= 1) ss += __shfl_xor(ss, off);
        float scale = rsqrtf(ss * (1.f / 256.f) + EPS_);
        float4 gn = *(const float4*)(gn_w + col);
        ushort4 gb4 = *(const ushort4*)(g_io + base);
        ushort4 out;
        out.x = f2bfu(v.x * scale * gn.x * bfu2f(gb4.x));
        out.y = f2bfu(v.y * scale * gn.y * bfu2f(gb4.y));
        out.z = f2bfu(v.z * scale * gn.z * bfu2f(gb4.z));
        out.w = f2bfu(v.w * scale * gn.w * bfu2f(gb4.w));
        *(ushort4*)(g_io + base) = out;
    } else {
        int m = blockIdx.x - 4096;
        int j0 = tid * 8;
        const float Dv = D_m[j0 >> 6];
        ushort4 ya = *(const ushort4*)(y_io + (size_t)m * DI + j0);
        ushort4 yb = *(const ushort4*)(y_io + (size_t)m * DI + j0 + 4);
        ushort4 xa = *(const ushort4*)(XB + (size_t)m * DI + j0);
        ushort4 xb = *(const ushort4*)(XB + (size_t)m * DI + j0 + 4);
        ushort4 za = *(const ushort4*)(C2B + (size_t)m * LD2 + j0);
        ushort4 zb = *(const ushort4*)(C2B + (size_t)m * LD2 + j0 + 4);
        float yv[8] = {bfu2f(ya.x), bfu2f(ya.y), bfu2f(ya.z), bfu2f(ya.w),
                       bfu2f(yb.x), bfu2f(yb.y), bfu2f(yb.z), bfu2f(yb.w)};
        float xv[8] = {bfu2f(xa.x), bfu2f(xa.y), bfu2f(xa.z), bfu2f(xa.w), bfu2f(xb.x), bfu2f(xb.y), bfu2f(xb.z), bfu2f(xb.w)};
        float zv[8] = {bfu2f(za.x), bfu2f(za.y), bfu2f(za.z), bfu2f(za.w), bfu2f(zb.x), bfu2f(zb.y), bfu2f(zb.z), bfu2f(zb.w)};
        float val[8];
        float ss = 0.f;
#pragma unroll
        for (int i = 0; i < 8; i++) {
            float v = (yv[i] + Dv * xv[i]) * siluf(zv[i]);
            val[i] = v;
            ss += v * v;
        }
#pragma unroll
        for (int off = 32; off; off >>= 1) ss += __shfl_xor(ss, off);
        if ((tid & 63) == 0) red[tid >> 6] = ss;
        __syncthreads();
        float scale = rsqrtf((red[0] + red[1] + red[2] + red[3]) * (1.f / 2048.f) + EPS_);
        ushort4 oa, ob;
        oa.x = f2bfu(val[0] * scale * mnw[j0 + 0]); oa.y = f2bfu(val[1] * scale * mnw[j0 + 1]);
        oa.z = f2bfu(val[2] * scale * mnw[j0 + 2]); oa.w = f2bfu(val[3] * scale * mnw[j0 + 3]);
        ob.x = f2bfu(val[4] * scale * mnw[j0 + 4]); ob.y = f2bfu(val[5] * scale * mnw[j0 + 5]);
        ob.z = f2bfu(val[6] * scale * mnw[j0 + 6]); ob.w = f2bfu(val[7] * scale * mnw[j0 + 7]);
        *(ushort4*)(y_io + (size_t)m * DI + j0) = oa;
        *(ushort4*)(y_io + (size_t)m * DI + j0 + 4) = ob;
    }
}

// ---------------- gate + mix + residual + RMS(ffn_ln) ----------------
__global__ __launch_bounds__(256) void k_mix(const float* __restrict__ x, const float* __restrict__ o_r,
                                             const float* __restrict__ o_m, const float* __restrict__ gw,
                                             const float* __restrict__ gb, const float* __restrict__ flnw,
                                             float* __restrict__ x1, unsigned short* __restrict__ nx2) {
    __shared__ float red[4];
    int m = blockIdx.x, tid = threadIdx.x;
    size_t base = (size_t)m * H_ + tid * 4;
    float4 orv = *(const float4*)(o_r + base);
    float4 omv = *(const float4*)(o_m + base);
    float4 xv = *(const float4*)(x + base);
    float4 g1 = *(const float4*)(gw + tid * 4);
    float4 g2 = *(const float4*)(gw + 1024 + tid * 4);
    float ps = orv.x * g1.x + orv.y * g1.y + orv.z * g1.z + orv.w * g1.w
             + omv.x * g2.x + omv.y * g2.y + omv.z * g2.z + omv.w * g2.w;
#pragma unroll
    for (int off = 32; off; off >>= 1) ps += __shfl_xor(ps, off);
    if ((tid & 63) == 0) red[tid >> 6] = ps;
    __syncthreads();
    float g = 1.f / (1.f + expf(-(red[0] + red[1] + red[2] + red[3] + gb[0])));
    float4 xo;
    xo.x = xv.x + g * orv.x + (1.f - g) * omv.x;
    xo.y = xv.y + g * orv.y + (1.f - g) * omv.y;
    xo.z = xv.z + g * orv.z + (1.f - g) * omv.z;
    xo.w = xv.w + g * orv.w + (1.f - g) * omv.w;
    *(float4*)(x1 + base) = xo;
    float ss = xo.x * xo.x + xo.y * xo.y + xo.z * xo.z + xo.w * xo.w;
#pragma unroll
    for (int off = 32; off; off >>= 1) ss += __shfl_xor(ss, off);
    __syncthreads();
    if ((tid & 63) == 0) red[tid >> 6] = ss;
    __syncthreads();
    float scale = rsqrtf((red[0] + red[1] + red[2] + red[3]) * (1.f / 1024.f) + EPS_);
    float4 wv = *(const float4*)(flnw + tid * 4);
    ushort4 o;
    o.x = f2bfu(xo.x * scale * wv.x); o.y = f2bfu(xo.y * scale * wv.y);
    o.z = f2bfu(xo.z * scale * wv.z); o.w = f2bfu(xo.w * scale * wv.w);
    *(ushort4*)(nx2 + base) = o;
}

extern "C" void kernel_launch(void* const* d_in, const int* in_sizes, int n_in,
                              void* d_out, int out_size, void* d_ws, size_t ws_size,
                              hipStream_t stream) {
    const float* x = (const float*)d_in[0];
    const float* ln_w = (const float*)d_in[1];
    const float* r_w = (const float*)d_in[2];
    const float* k_w = (const float*)d_in[3];
    const float* v_w = (const float*)d_in[4];
    const float* g_w = (const float*)d_in[5];
    const float* dw_w = (const float*)d_in[6];
    const float* u = (const float*)d_in[7];
    const float* gn_w = (const float*)d_in[8];
    const float* o_w = (const float*)d_in[9];
    const float* in_proj = (const float*)d_in[10];
    const float* conv_w = (const float*)d_in[11];
    const float* conv_b = (const float*)d_in[12];
    const float* dt_bias = (const float*)d_in[13];
    const float* A_log = (const float*)d_in[14];
    const float* D_m = (const float*)d_in[15];
    const float* m_norm_w = (const float*)d_in[16];
    const float* out_proj = (const float*)d_in[17];
    const float* gate_w = (const float*)d_in[18];
    const float* gate_b = (const float*)d_in[19];
    const float* ffn_ln_w = (const float*)d_in[20];
    const float* ffn_w1 = (const float*)d_in[21];
    const float* ffn_w2 = (const float*)d_in[22];
    (void)in_sizes; (void)n_in;

    const size_t NEEDED = 192675840ull;
    if (ws_size < NEEDED) {
        hipMemsetAsync(d_out, 0, (size_t)out_size * 4, stream);
        return;
    }
    char* ws = (char*)d_ws;
    unsigned short* WT5 = (unsigned short*)(ws + 0);
    unsigned short* INPT = (unsigned short*)(ws + 10485760);
    unsigned short* QLb = (unsigned short*)(ws + 0);
    float* DDb = (float*)(ws + 524288);
    unsigned short* SCC = (unsigned short*)(ws + 1048576);
    unsigned short* F1T = (unsigned short*)(ws + 0);
    unsigned short* F2T = (unsigned short*)(ws + 10485760);
    unsigned short* OWT = (unsigned short*)(ws + 19660800);
    unsigned short* OPT = (unsigned short*)(ws + 21757952);
    unsigned short* NXB = (unsigned short*)(ws + 25952256);
    unsigned short* KDt = NXB;
    unsigned short* RB = (unsigned short*)(ws + 34340864);
    unsigned short* KB = (unsigned short*)(ws + 42729472);
    unsigned short* VB = (unsigned short*)(ws + 51118080);
    unsigned short* GB = (unsigned short*)(ws + 59506688);
    float* WF = (float*)(ws + 67895296);
    char* MTB = ws + 67895296;
    float* DTt = (float*)(MTB + 0);
    float* CDt = (float*)(MTB + 524288);
    float* WSt = (float*)(MTB + 1048576);
    float* WSCt = (float*)(MTB + 1572864);
    float* QJt = (float*)(MTB + 2097152);
    float* QLft = (float*)(MTB + 2621440);
    float* QCt = (float*)(MTB + 2654208);
    unsigned short* AMt = (unsigned short*)(MTB + 2658304);
    float* OM = (float*)(ws + 34340864);
    unsigned short* MIDB = (unsigned short*)(ws + 51118080);
    unsigned short* C2B = (unsigned short*)(ws + 84672512);
    unsigned short* XB = (unsigned short*)(ws + 121372672);
    float* BCF = (float*)(ws + 138149888);
    float* P0 = (float*)(ws + 142344192);
    float* P1 = (float*)(ws + 159121408);
    unsigned short* MSCC = (unsigned short*)(ws + 142344192);   // over P0 (dead until rwkv_out)
    unsigned short* YB = (unsigned short*)(ws + 175898624);

    dim3 blk(256);
    k_rms1024<<<M_, blk, 0, stream>>>(x, ln_w, NXB);
    k_transpose6<<<dim3(32, 32, 6), blk, 0, stream>>>(r_w, k_w, v_w, g_w, dw_w, o_w, WT5, OWT);
    k_transpose<<<dim3(140, 32), blk, 0, stream>>>(in_proj, INPT, 1024, 4384, 4480);
    k_transpose<<<dim3(32, 64), blk, 0, stream>>>(out_proj, OPT, 2048, 1024, 1024);
    k_gemm_fused<<<dim3(75, 32), blk, 0, stream>>>(NXB, WT5, RB, KB, VB, GB, WF, C2B);
    k_conv<<<dim3(9, M_), blk, 0, stream>>>(C2B, conv_w, conv_b, XB, BCF);
    // rwkv prep then mamba tables (WF region dead after rwkv_prep)
    k_rwkv_prep<<<dim3(128, 8), blk, 0, stream>>>(RB, KB, WF, u, KDt, QLb, DDb);
    k_mprep<<<64, blk, 0, stream>>>(C2B, dt_bias, A_log, DTt, CDt, WSt, WSCt, QJt, QLft, QCt);
    k_amask<<<dim3(128, 64), dim3(64), 0, stream>>>(BCF, CDt, DTt, A_log, AMt);
    // merged carries: rwkv (SCC) + mamba (MSCC over P0 region)
    k_carry2<<<768, blk, 0, stream>>>(KB, VB, QLb, SCC, BCF, XB, WSCt, QCt, MSCC);
    // mamba out BEFORE rwkv_out (rwkv_out overwrites P0 = MSCC)
    k_mout<<<dim3(16, 64), blk, 0, stream>>>(BCF, XB, AMt, QJt, WSt, QLft, MSCC, YB);
    k_rwkv_out<<<dim3(4, 16, 16), blk, 0, stream>>>(RB, KB, KDt, VB, QLb, DDb, SCC, P0, P1);
    // merged posts
    k_post2<<<8192, blk, 0, stream>>>(P0, P1, gn_w, GB, YB, XB, C2B, D_m, m_norm_w);
    // FFN weight transposes (QLb/SCC dead)
    k_transpose<<<dim3(128, 32), blk, 0, stream>>>(ffn_w1, F1T, 1024, 4096, 4096);
    k_transpose<<<dim3(32, 128), blk, 0, stream>>>(ffn_w2, F2T, 4096, 1024, 1024);
    // paired skinny GEMMs
    k_gemm_pair<<<dim3(8, 32, 2), blk, 0, stream>>>(GB, OWT, P1, 1024, YB, OPT, OM, 2048);
    k_mix<<<M_, blk, 0, stream>>>(x, P1, OM, gate_w, gate_b, ffn_ln_w, P0, NXB);
    k_gemm<4><<<dim3(32, 32), blk, 0, stream>>>(NXB, F1T, MIDB, nullptr, 4096, 4096, 1024);
    k_gemm<5><<<dim3(8, 32), blk, 0, stream>>>(MIDB, F2T, (float*)d_out, P0, 4096, 1024, 4096);
}